// Round 1
// baseline (438.585 us; speedup 1.0000x reference)
//
#include <hip/hip_runtime.h>

#define BN_EPS 1e-5f

// Bucket-sort parameters: NPB nodes per bucket (pow2), PB placement blocks.
#define NPB 512
#define NPB_SHIFT 9
#define PB 512
#define MAXB 256
// BN-stat accumulator slices (atomic-depth reduction)
#define NSLICE 16

typedef __attribute__((ext_vector_type(8))) short short8;
typedef __attribute__((ext_vector_type(4))) float floatx4;
typedef __attribute__((ext_vector_type(2))) float floatx2;

__device__ __forceinline__ unsigned short f2bf(float f) {
    unsigned u = __float_as_uint(f);
    unsigned r = u + 0x7FFFu + ((u >> 16) & 1u);   // round-to-nearest-even
    return (unsigned short)(r >> 16);
}
__device__ __forceinline__ float blo(unsigned v) { return __uint_as_float(v << 16); }
__device__ __forceinline__ float bhi(unsigned v) { return __uint_as_float(v & 0xffff0000u); }

// pack 8 fp32 -> 8 fp8 e4m3 (2 dwords); byte k of output = value k
__device__ __forceinline__ uint2 pk8_fp8(const float4 v0, const float4 v1) {
    int lo = 0, hi = 0;
    lo = __builtin_amdgcn_cvt_pk_fp8_f32(v0.x, v0.y, lo, false);
    lo = __builtin_amdgcn_cvt_pk_fp8_f32(v0.z, v0.w, lo, true);
    hi = __builtin_amdgcn_cvt_pk_fp8_f32(v1.x, v1.y, hi, false);
    hi = __builtin_amdgcn_cvt_pk_fp8_f32(v1.z, v1.w, hi, true);
    return make_uint2((unsigned)lo, (unsigned)hi);
}

// ------- W pre-transpose + stats/cw zeroing (runs first, saves dispatches) ----
__global__ __launch_bounds__(256) void wconv(
    const float* __restrict__ W0, const float* __restrict__ W1,
    unsigned short* __restrict__ wt0, unsigned short* __restrict__ wt1,
    float* __restrict__ stats, float* __restrict__ cw, int N)
{
    const int idx = blockIdx.x * 256 + threadIdx.x;   // < 16384
    const int n = idx >> 7, k = idx & 127;
    wt0[idx] = f2bf(W0[k * 128 + n]);
    wt1[idx] = f2bf(W1[k * 128 + n]);
    if (blockIdx.x < 9) {   // zero 9216 floats (4 sliced stat arrays + svec)
        const int o = idx * 4;
        *(float4*)&stats[o] = make_float4(0.f, 0.f, 0.f, 0.f);
    }
    for (int z = idx; z < N; z += 64 * 256) cw[z] = 0.f;
}

// ------- layer-0 GEMM: C[M x 128] = A_fp32 @ W, C in fp8 e4m3 -------
__global__ __launch_bounds__(256) void gemm0(
    const float* __restrict__ A, const unsigned short* __restrict__ Wt,
    uint2* __restrict__ C, int M)
{
    __shared__ char lds[53248];
    unsigned short* Al = (unsigned short*)lds;            // [64][136] bf16
    unsigned short* Wl = (unsigned short*)(lds + 17408);  // [128][136] bf16
    float* Cl = (float*)lds;                              // [64][132] f32 (reuse)

    const int tid = threadIdx.x;
    const int r0 = blockIdx.x * 64;

#pragma unroll
    for (int i = 0; i < 16; ++i) {
        const int idx = i * 256 + tid;          // ushort4 units
        const int n = idx >> 5, q = idx & 31;
        const ushort4 v = ((const ushort4*)Wt)[idx];
        *(ushort4*)&Wl[n * 136 + q * 4] = v;
    }
#pragma unroll
    for (int i = 0; i < 8; ++i) {
        const int row = i * 8 + (tid >> 5), q = tid & 31;
        const int gr = r0 + row;
        float4 v = (gr < M) ? ((const float4*)A)[(size_t)gr * 32 + q]
                            : make_float4(0.f, 0.f, 0.f, 0.f);
        ushort4 o;
        o.x = f2bf(v.x); o.y = f2bf(v.y); o.z = f2bf(v.z); o.w = f2bf(v.w);
        *(ushort4*)&Al[row * 136 + q * 4] = o;
    }
    __syncthreads();

    const int wave = tid >> 6, lane = tid & 63;
    const int lrow = lane & 15, quad = lane >> 4;
    const int n0 = wave * 32;

    floatx4 acc[4][2];
#pragma unroll
    for (int mt = 0; mt < 4; ++mt)
#pragma unroll
        for (int t = 0; t < 2; ++t)
#pragma unroll
            for (int j = 0; j < 4; ++j) acc[mt][t][j] = 0.f;

#pragma unroll
    for (int c = 0; c < 4; ++c) {
        const int k0 = c * 32;
        const short8 b0 = *(const short8*)&Wl[(n0 + lrow) * 136 + k0 + quad * 8];
        const short8 b1 = *(const short8*)&Wl[(n0 + 16 + lrow) * 136 + k0 + quad * 8];
#pragma unroll
        for (int mt = 0; mt < 4; ++mt) {
            const short8 a = *(const short8*)&Al[(mt * 16 + lrow) * 136 + k0 + quad * 8];
            acc[mt][0] = __builtin_amdgcn_mfma_f32_16x16x32_bf16(a, b0, acc[mt][0], 0, 0, 0);
            acc[mt][1] = __builtin_amdgcn_mfma_f32_16x16x32_bf16(a, b1, acc[mt][1], 0, 0, 0);
        }
    }
    __syncthreads();

#pragma unroll
    for (int mt = 0; mt < 4; ++mt)
#pragma unroll
        for (int t = 0; t < 2; ++t)
#pragma unroll
            for (int j = 0; j < 4; ++j)
                Cl[(mt * 16 + quad * 4 + j) * 132 + n0 + t * 16 + lrow] = acc[mt][t][j];
    __syncthreads();

#pragma unroll
    for (int i = 0; i < 4; ++i) {
        const int row = i * 16 + (tid >> 4);
        const int c0 = (tid & 15) * 8;
        const int gr = r0 + row;
        if (gr < M) {
            const float4 v0 = *(float4*)&Cl[row * 132 + c0];
            const float4 v1 = *(float4*)&Cl[row * 132 + c0 + 4];
            C[(size_t)gr * 16 + (c0 >> 3)] = pk8_fp8(v0, v1);
        }
    }
}

// ------- layer-1 GEMM: C = relu(BN(A_bf16)) @ W, C in fp8 e4m3 -------
__global__ __launch_bounds__(256) void gemm1(
    const unsigned* __restrict__ Ab, const unsigned short* __restrict__ Wt,
    uint2* __restrict__ C,
    const float* __restrict__ sum, const float* __restrict__ sq,
    const float* __restrict__ g, const float* __restrict__ be,
    int M, int N)
{
    __shared__ char lds[53248];
    unsigned short* Al = (unsigned short*)lds;            // [64][136]
    unsigned short* Wl = (unsigned short*)(lds + 17408);  // [128][136]
    float* AscL = (float*)(lds + 52224);                  // [128]
    float* AshL = AscL + 128;
    float* Cl = (float*)lds;

    const int tid = threadIdx.x;
    const int r0 = blockIdx.x * 64;

    if (tid < 128) {
        float s = 0.f, q = 0.f;
#pragma unroll
        for (int k = 0; k < NSLICE; ++k) {
            s += sum[k * 128 + tid];
            q += sq[k * 128 + tid];
        }
        const float invN = 1.0f / (float)N;
        const float m = s * invN;
        const float var = q * invN - m * m;
        const float rs = rsqrtf(var + BN_EPS);
        AscL[tid] = g[tid] * rs;
        AshL[tid] = be[tid] - g[tid] * m * rs;
    }
    __syncthreads();

#pragma unroll
    for (int i = 0; i < 16; ++i) {
        const int idx = i * 256 + tid;
        const int n = idx >> 5, q = idx & 31;
        const ushort4 v = ((const ushort4*)Wt)[idx];
        *(ushort4*)&Wl[n * 136 + q * 4] = v;
    }
#pragma unroll
    for (int i = 0; i < 4; ++i) {
        const int idx = i * 256 + tid;
        const int row = idx >> 4, qc = idx & 15;
        const int gr = r0 + row;
        uint4 v = (gr < M) ? ((const uint4*)Ab)[(size_t)gr * 16 + qc]
                           : make_uint4(0, 0, 0, 0);
        const float4 a0 = *(const float4*)&AscL[qc * 8];
        const float4 a1 = *(const float4*)&AscL[qc * 8 + 4];
        const float4 b0 = *(const float4*)&AshL[qc * 8];
        const float4 b1 = *(const float4*)&AshL[qc * 8 + 4];
        float x0 = fmaxf(fmaf(a0.x, blo(v.x), b0.x), 0.f);
        float x1 = fmaxf(fmaf(a0.y, bhi(v.x), b0.y), 0.f);
        float x2 = fmaxf(fmaf(a0.z, blo(v.y), b0.z), 0.f);
        float x3 = fmaxf(fmaf(a0.w, bhi(v.y), b0.w), 0.f);
        float x4 = fmaxf(fmaf(a1.x, blo(v.z), b1.x), 0.f);
        float x5 = fmaxf(fmaf(a1.y, bhi(v.z), b1.y), 0.f);
        float x6 = fmaxf(fmaf(a1.z, blo(v.w), b1.z), 0.f);
        float x7 = fmaxf(fmaf(a1.w, bhi(v.w), b1.w), 0.f);
        uint4 o;
        o.x = (unsigned)f2bf(x0) | ((unsigned)f2bf(x1) << 16);
        o.y = (unsigned)f2bf(x2) | ((unsigned)f2bf(x3) << 16);
        o.z = (unsigned)f2bf(x4) | ((unsigned)f2bf(x5) << 16);
        o.w = (unsigned)f2bf(x6) | ((unsigned)f2bf(x7) << 16);
        *(uint4*)&Al[row * 136 + qc * 8] = o;
    }
    __syncthreads();

    const int wave = tid >> 6, lane = tid & 63;
    const int lrow = lane & 15, quad = lane >> 4;
    const int n0 = wave * 32;

    floatx4 acc[4][2];
#pragma unroll
    for (int mt = 0; mt < 4; ++mt)
#pragma unroll
        for (int t = 0; t < 2; ++t)
#pragma unroll
            for (int j = 0; j < 4; ++j) acc[mt][t][j] = 0.f;

#pragma unroll
    for (int c = 0; c < 4; ++c) {
        const int k0 = c * 32;
        const short8 b0 = *(const short8*)&Wl[(n0 + lrow) * 136 + k0 + quad * 8];
        const short8 b1 = *(const short8*)&Wl[(n0 + 16 + lrow) * 136 + k0 + quad * 8];
#pragma unroll
        for (int mt = 0; mt < 4; ++mt) {
            const short8 a = *(const short8*)&Al[(mt * 16 + lrow) * 136 + k0 + quad * 8];
            acc[mt][0] = __builtin_amdgcn_mfma_f32_16x16x32_bf16(a, b0, acc[mt][0], 0, 0, 0);
            acc[mt][1] = __builtin_amdgcn_mfma_f32_16x16x32_bf16(a, b1, acc[mt][1], 0, 0, 0);
        }
    }
    __syncthreads();

#pragma unroll
    for (int mt = 0; mt < 4; ++mt)
#pragma unroll
        for (int t = 0; t < 2; ++t)
#pragma unroll
            for (int j = 0; j < 4; ++j)
                Cl[(mt * 16 + quad * 4 + j) * 132 + n0 + t * 16 + lrow] = acc[mt][t][j];
    __syncthreads();

#pragma unroll
    for (int i = 0; i < 4; ++i) {
        const int row = i * 16 + (tid >> 4);
        const int c0 = (tid & 15) * 8;
        const int gr = r0 + row;
        if (gr < M) {
            const float4 v0 = *(float4*)&Cl[row * 132 + c0];
            const float4 v1 = *(float4*)&Cl[row * 132 + c0 + 4];
            C[(size_t)gr * 16 + (c0 >> 3)] = pk8_fp8(v0, v1);
        }
    }
}

// ============ atomic-free CSR build (dst side only; cw via global atomics) ====

__global__ __launch_bounds__(256) void bucket_hist(
    const int* __restrict__ dst, int* __restrict__ cntD, int E, int B, int chunk)
{
    __shared__ int hD[MAXB];
    const int tid = threadIdx.x;
    for (int i = tid; i < B; i += 256) hD[i] = 0;
    __syncthreads();
    const int lo = blockIdx.x * chunk;
    const int hi = min(E, lo + chunk);
    for (int e = lo + tid; e < hi; e += 256)
        atomicAdd(&hD[dst[e] >> NPB_SHIFT], 1);
    __syncthreads();
    for (int i = tid; i < B; i += 256)
        cntD[i * PB + blockIdx.x] = hD[i];
}

__global__ __launch_bounds__(256) void bucket_base(
    const int* __restrict__ cntD, int* __restrict__ baseD, int B, int E)
{
    __shared__ int lD[256];
    const int tid = threadIdx.x;
    int sD = 0;
    if (tid < B) {
        const int4* pD = (const int4*)(cntD + tid * PB);
        for (int j = 0; j < PB / 4; ++j) {
            const int4 a = pD[j];
            sD += a.x + a.y + a.z + a.w;
        }
    }
    lD[tid] = sD;
    __syncthreads();
    for (int st = 1; st < 256; st <<= 1) {
        const int vD = (tid >= st) ? lD[tid - st] : 0;
        __syncthreads();
        lD[tid] += vD;
        __syncthreads();
    }
    if (tid < B) baseD[tid] = lD[tid] - sD;
    if (tid == 0) baseD[B] = E;
}

__global__ __launch_bounds__(256) void bucket_cursor(
    int* __restrict__ cntD, const int* __restrict__ baseD)
{
    const int b = blockIdx.x;
    __shared__ int ls[256];
    const int tid = threadIdx.x;
    const int c0 = cntD[b * PB + 2 * tid];
    const int c1 = cntD[b * PB + 2 * tid + 1];
    const int s = c0 + c1;
    ls[tid] = s;
    __syncthreads();
    for (int st = 1; st < 256; st <<= 1) {
        const int v = (tid >= st) ? ls[tid - st] : 0;
        __syncthreads();
        ls[tid] += v;
        __syncthreads();
    }
    const int excl = ls[tid] - s + baseD[b];
    cntD[b * PB + 2 * tid] = excl;
    cntD[b * PB + 2 * tid + 1] = excl + c0;
}

__global__ __launch_bounds__(256) void bucket_place(
    const int* __restrict__ src, const int* __restrict__ dst,
    const float* __restrict__ ew,
    const int* __restrict__ curD, uint2* __restrict__ bktD,
    float* __restrict__ cw, int E, int B, int chunk)
{
    __shared__ int cD[MAXB];
    const int tid = threadIdx.x;
    for (int i = tid; i < B; i += 256)
        cD[i] = curD[i * PB + blockIdx.x];
    __syncthreads();
    const int lo = blockIdx.x * chunk;
    const int hi = min(E, lo + chunk);
    for (int e = lo + tid; e < hi; e += 256) {
        const int s = src[e], d = dst[e];
        const float wf = ew[e];
        const int pd = atomicAdd(&cD[d >> NPB_SHIFT], 1);
        bktD[pd] = make_uint2(((unsigned)s << NPB_SHIFT) | (unsigned)(d & (NPB - 1)),
                              __float_as_uint(wf));
        atomicAdd(&cw[s], wf);   // src-side segment sum (replaces bktS pipeline)
    }
}

// counting-sort bktD within each bucket -> rp / packed
__global__ __launch_bounds__(256) void bucket_sort(
    const uint2* __restrict__ bktD, const int* __restrict__ baseD,
    int* __restrict__ rp, int2* __restrict__ packed, int N)
{
    const int tid = threadIdx.x;
    const int b = blockIdx.x;
    const int lo = baseD[b], hi = baseD[b + 1];
    __shared__ int cnt[NPB], cur[NPB];
    __shared__ int ls[256];
    cnt[2 * tid] = 0; cnt[2 * tid + 1] = 0;
    __syncthreads();
    for (int i = lo + tid; i < hi; i += 256)
        atomicAdd(&cnt[bktD[i].x & (NPB - 1)], 1);
    __syncthreads();
    const int c0 = cnt[2 * tid], c1 = cnt[2 * tid + 1];
    const int s = c0 + c1;
    ls[tid] = s;
    __syncthreads();
    for (int st = 1; st < 256; st <<= 1) {
        const int v = (tid >= st) ? ls[tid - st] : 0;
        __syncthreads();
        ls[tid] += v;
        __syncthreads();
    }
    const int excl = ls[tid] - s;
    const int n0 = b * NPB + 2 * tid;
    if (n0 < N)     rp[n0]     = lo + excl + c0;
    if (n0 + 1 < N) rp[n0 + 1] = lo + excl + c0 + c1;
    cur[2 * tid]     = lo + excl;
    cur[2 * tid + 1] = lo + excl + c0;
    __syncthreads();
    for (int i = lo + tid; i < hi; i += 256) {
        const uint2 r = bktD[i];
        const int pos = atomicAdd(&cur[r.x & (NPB - 1)], 1);
        packed[pos] = make_int2((int)(r.x >> NPB_SHIFT), (int)r.y);
    }
}

// ------- fused aggregate + BN stats (v10: 2-node interleave, 2x gather MLP) ---
// R0-theory: aggregate4 was latency-bound (VALUBusy 49%, HBM 21%, MLP=4
// loads/lane, serial per-node chains). Pair nodes (r,r+1): 8 gathers in
// flight per j-iter, shared reduce, sub0/sub1 quarter-waves write A/B rows.
#define AGG_R 16

#define GATHER4(CUR, J, CNT, V0, V1, V2, V3, W0, W1, W2, W3) do { \
    const int i0_ = (J) + sub, i1_ = i0_ + 4, i2_ = i0_ + 8, i3_ = i0_ + 12; \
    const int c0_ = (i0_ < (CNT)) ? i0_ : 0; \
    const int c1_ = (i1_ < (CNT)) ? i1_ : 0; \
    const int c2_ = (i2_ < (CNT)) ? i2_ : 0; \
    const int c3_ = (i3_ < (CNT)) ? i3_ : 0; \
    const int s0_ = __shfl((CUR).x, c0_, 64); \
    const int s1_ = __shfl((CUR).x, c1_, 64); \
    const int s2_ = __shfl((CUR).x, c2_, 64); \
    const int s3_ = __shfl((CUR).x, c3_, 64); \
    W0 = __uint_as_float((unsigned)__shfl((CUR).y, c0_, 64)); \
    W1 = __uint_as_float((unsigned)__shfl((CUR).y, c1_, 64)); \
    W2 = __uint_as_float((unsigned)__shfl((CUR).y, c2_, 64)); \
    W3 = __uint_as_float((unsigned)__shfl((CUR).y, c3_, 64)); \
    if (i0_ >= (CNT)) W0 = 0.f; \
    if (i1_ >= (CNT)) W1 = 0.f; \
    if (i2_ >= (CNT)) W2 = 0.f; \
    if (i3_ >= (CNT)) W3 = 0.f; \
    V0 = h2[(size_t)s0_ * 16 + u]; \
    V1 = h2[(size_t)s1_ * 16 + u]; \
    V2 = h2[(size_t)s2_ * 16 + u]; \
    V3 = h2[(size_t)s3_ * 16 + u]; \
} while (0)

#define ACC_EDGE(V, W, A) do { \
    floatx2 f_; \
    f_ = __builtin_amdgcn_cvt_pk_f32_fp8((int)(V).x, false); \
    A[0] = fmaf(W, f_.x, A[0]); A[1] = fmaf(W, f_.y, A[1]); \
    f_ = __builtin_amdgcn_cvt_pk_f32_fp8((int)(V).x, true);  \
    A[2] = fmaf(W, f_.x, A[2]); A[3] = fmaf(W, f_.y, A[3]); \
    f_ = __builtin_amdgcn_cvt_pk_f32_fp8((int)(V).y, false); \
    A[4] = fmaf(W, f_.x, A[4]); A[5] = fmaf(W, f_.y, A[5]); \
    f_ = __builtin_amdgcn_cvt_pk_f32_fp8((int)(V).y, true);  \
    A[6] = fmaf(W, f_.x, A[6]); A[7] = fmaf(W, f_.y, A[7]); \
} while (0)

__global__ __launch_bounds__(256) void aggregate4(
    const int2* __restrict__ packed, const int* __restrict__ rp,
    const uint2* __restrict__ h2, uint4* __restrict__ aggb4,
    float* __restrict__ sum, float* __restrict__ sq, int N)
{
    const int tid = threadIdx.x;
    const int lane = tid & 63, wave = tid >> 6;
    const int sub = lane >> 4;          // quarter 0..3
    const int u = lane & 15;            // cols 8u..8u+7
    const int n0 = (blockIdx.x * 4 + wave) * AGG_R;

    // coalesced row-pointer block: lane l holds rp[n0-1+l] (rp[n]=end of node n)
    int rpv = 0;
    {
        const int idx = n0 - 1 + lane;
        if (lane <= AGG_R && idx >= 0 && idx < N) rpv = rp[idx];
    }

    float csum[8], csq[8];
#pragma unroll
    for (int k = 0; k < 8; ++k) { csum[k] = 0.f; csq[k] = 0.f; }

    // prefetch first pair's first edge chunks
    int2 curA = make_int2(0, 0), curB = make_int2(0, 0);
    if (n0 < N) {
        const int sa = __shfl(rpv, 0, 64), ea = __shfl(rpv, 1, 64);
        if (lane < min(64, ea - sa)) curA = packed[sa + lane];
    }
    if (n0 + 1 < N) {
        const int sb = __shfl(rpv, 1, 64), eb = __shfl(rpv, 2, 64);
        if (lane < min(64, eb - sb)) curB = packed[sb + lane];
    }

    for (int r = 0; r < AGG_R; r += 2) {
        const int nA = n0 + r;
        if (nA >= N) break;
        const int nB = nA + 1;
        const bool hasB = (nB < N);
        const int sA = __shfl(rpv, r, 64);
        const int eA = __shfl(rpv, r + 1, 64);
        const int sB = eA;
        const int eB = hasB ? __shfl(rpv, r + 2, 64) : sB;

        // prefetch next pair's first chunks (overlaps this pair's gathers)
        int2 nxtA = make_int2(0, 0), nxtB = make_int2(0, 0);
        if (r + 2 < AGG_R && nA + 2 < N) {
            const int ns = __shfl(rpv, r + 2, 64), ne = __shfl(rpv, r + 3, 64);
            if (lane < min(64, ne - ns)) nxtA = packed[ns + lane];
        }
        if (r + 3 < AGG_R && nA + 3 < N) {
            const int ns = __shfl(rpv, r + 3, 64), ne = __shfl(rpv, r + 4, 64);
            if (lane < min(64, ne - ns)) nxtB = packed[ns + lane];
        }

        float aA[8], aB[8];
#pragma unroll
        for (int k = 0; k < 8; ++k) { aA[k] = 0.f; aB[k] = 0.f; }

        const int cA = min(64, eA - sA);
        const int cB = min(64, eB - sB);
        const int cmax = (cA > cB) ? cA : cB;

        // interleaved first-chunk processing: up to 8 gathers in flight
        for (int j = 0; j < cmax; j += 16) {
            const bool doA = j < cA, doB = j < cB;
            uint2 vA0, vA1, vA2, vA3, vB0, vB1, vB2, vB3;
            float wA0, wA1, wA2, wA3, wB0, wB1, wB2, wB3;
            if (doA & doB) {
                GATHER4(curA, j, cA, vA0, vA1, vA2, vA3, wA0, wA1, wA2, wA3);
                GATHER4(curB, j, cB, vB0, vB1, vB2, vB3, wB0, wB1, wB2, wB3);
                ACC_EDGE(vA0, wA0, aA); ACC_EDGE(vA1, wA1, aA);
                ACC_EDGE(vA2, wA2, aA); ACC_EDGE(vA3, wA3, aA);
                ACC_EDGE(vB0, wB0, aB); ACC_EDGE(vB1, wB1, aB);
                ACC_EDGE(vB2, wB2, aB); ACC_EDGE(vB3, wB3, aB);
            } else if (doA) {
                GATHER4(curA, j, cA, vA0, vA1, vA2, vA3, wA0, wA1, wA2, wA3);
                ACC_EDGE(vA0, wA0, aA); ACC_EDGE(vA1, wA1, aA);
                ACC_EDGE(vA2, wA2, aA); ACC_EDGE(vA3, wA3, aA);
            } else {
                GATHER4(curB, j, cB, vB0, vB1, vB2, vB3, wB0, wB1, wB2, wB3);
                ACC_EDGE(vB0, wB0, aB); ACC_EDGE(vB1, wB1, aB);
                ACC_EDGE(vB2, wB2, aB); ACC_EDGE(vB3, wB3, aB);
            }
        }

        // rare overflow chunks (degree > 64), serial fallback
        for (int base = sA + 64; base < eA; base += 64) {
            const int cnt = min(64, eA - base);
            int2 myE = make_int2(0, 0);
            if (lane < cnt) myE = packed[base + lane];
            for (int j = 0; j < cnt; j += 16) {
                uint2 v0, v1, v2, v3; float w0, w1, w2, w3;
                GATHER4(myE, j, cnt, v0, v1, v2, v3, w0, w1, w2, w3);
                ACC_EDGE(v0, w0, aA); ACC_EDGE(v1, w1, aA);
                ACC_EDGE(v2, w2, aA); ACC_EDGE(v3, w3, aA);
            }
        }
        for (int base = sB + 64; base < eB; base += 64) {
            const int cnt = min(64, eB - base);
            int2 myE = make_int2(0, 0);
            if (lane < cnt) myE = packed[base + lane];
            for (int j = 0; j < cnt; j += 16) {
                uint2 v0, v1, v2, v3; float w0, w1, w2, w3;
                GATHER4(myE, j, cnt, v0, v1, v2, v3, w0, w1, w2, w3);
                ACC_EDGE(v0, w0, aB); ACC_EDGE(v1, w1, aB);
                ACC_EDGE(v2, w2, aB); ACC_EDGE(v3, w3, aB);
            }
        }

        // joint cross-quarter reduce; all lanes end with full sums
#pragma unroll
        for (int k = 0; k < 8; ++k) {
            aA[k] += __shfl_xor(aA[k], 16, 64);
            aB[k] += __shfl_xor(aB[k], 16, 64);
            aA[k] += __shfl_xor(aA[k], 32, 64);
            aB[k] += __shfl_xor(aB[k], 32, 64);
        }
        if (sub == 0) {
            uint4 o;
            o.x = (unsigned)f2bf(aA[0]) | ((unsigned)f2bf(aA[1]) << 16);
            o.y = (unsigned)f2bf(aA[2]) | ((unsigned)f2bf(aA[3]) << 16);
            o.z = (unsigned)f2bf(aA[4]) | ((unsigned)f2bf(aA[5]) << 16);
            o.w = (unsigned)f2bf(aA[6]) | ((unsigned)f2bf(aA[7]) << 16);
            aggb4[(size_t)nA * 16 + u] = o;
#pragma unroll
            for (int k = 0; k < 8; ++k) {
                csum[k] += aA[k];
                csq[k] = fmaf(aA[k], aA[k], csq[k]);
            }
        } else if (sub == 1 && hasB) {
            uint4 o;
            o.x = (unsigned)f2bf(aB[0]) | ((unsigned)f2bf(aB[1]) << 16);
            o.y = (unsigned)f2bf(aB[2]) | ((unsigned)f2bf(aB[3]) << 16);
            o.z = (unsigned)f2bf(aB[4]) | ((unsigned)f2bf(aB[5]) << 16);
            o.w = (unsigned)f2bf(aB[6]) | ((unsigned)f2bf(aB[7]) << 16);
            aggb4[(size_t)nB * 16 + u] = o;
#pragma unroll
            for (int k = 0; k < 8; ++k) {
                csum[k] += aB[k];
                csq[k] = fmaf(aB[k], aB[k], csq[k]);
            }
        }
        curA = nxtA;
        curB = nxtB;
    }

    // 8 stat slots: [wave] from sub0 (A nodes), [4+wave] from sub1 (B nodes)
    __shared__ float lsum[1024], lsq[1024];
    if (sub == 0) {
#pragma unroll
        for (int k = 0; k < 8; ++k) {
            lsum[wave * 128 + u * 8 + k] = csum[k];
            lsq[wave * 128 + u * 8 + k] = csq[k];
        }
    } else if (sub == 1) {
#pragma unroll
        for (int k = 0; k < 8; ++k) {
            lsum[(4 + wave) * 128 + u * 8 + k] = csum[k];
            lsq[(4 + wave) * 128 + u * 8 + k] = csq[k];
        }
    }
    __syncthreads();
    if (tid < 128) {
        float s = 0.f, q = 0.f;
#pragma unroll
        for (int i = 0; i < 8; ++i) {
            s += lsum[i * 128 + tid];
            q += lsq[i * 128 + tid];
        }
        const int sl = (blockIdx.x & (NSLICE - 1)) * 128;
        atomicAdd(&sum[sl + tid], s);
        atomicAdd(&sq[sl + tid], q);
    }
}

// ---------------- collapsed layer 2 (persistent grid, sliced-stat prologue) ----
__global__ __launch_bounds__(256) void wcolsum_bf16(
    const unsigned* __restrict__ xb, const float* __restrict__ cw,
    const float* __restrict__ sum1, const float* __restrict__ sq1,
    const float* __restrict__ g, const float* __restrict__ be,
    float* __restrict__ sout, int N)
{
    __shared__ float Aaf[128], Baf[128];
    __shared__ float2 ls[256];
    const int tid = threadIdx.x;
    if (tid < 128) {
        float s = 0.f, q = 0.f;
#pragma unroll
        for (int k = 0; k < NSLICE; ++k) {
            s += sum1[k * 128 + tid];
            q += sq1[k * 128 + tid];
        }
        const float invN = 1.0f / (float)N;
        const float m = s * invN;
        const float var = q * invN - m * m;
        const float rs = rsqrtf(var + BN_EPS);
        Aaf[tid] = g[tid] * rs;
        Baf[tid] = be[tid] - g[tid] * m * rs;
    }
    __syncthreads();
    const int u = tid & 63, rr = tid >> 6;
    const float ax = Aaf[2 * u], ay = Aaf[2 * u + 1];
    const float bx = Baf[2 * u], by = Baf[2 * u + 1];
    float2 s = {0.f, 0.f};
    for (int row = blockIdx.x * 4 + rr; row < N; row += gridDim.x * 4) {
        const unsigned v = xb[(size_t)row * 64 + u];
        const float c = cw[row];
        const float x = fmaxf(fmaf(ax, blo(v), bx), 0.f);
        const float y = fmaxf(fmaf(ay, bhi(v), by), 0.f);
        s.x = fmaf(c, x, s.x);
        s.y = fmaf(c, y, s.y);
    }
    ls[tid] = s;
    __syncthreads();
    if (tid < 64) {
        float sx = ls[tid].x + ls[64 + tid].x + ls[128 + tid].x + ls[192 + tid].x;
        float sy = ls[tid].y + ls[64 + tid].y + ls[128 + tid].y + ls[192 + tid].y;
        atomicAdd(&sout[2 * tid + 0], sx);
        atomicAdd(&sout[2 * tid + 1], sy);
    }
}

__global__ void final_out(
    const float* __restrict__ s, const float* __restrict__ W2,
    const float* __restrict__ b2, float* __restrict__ out, int N, int Dout)
{
    const int j = threadIdx.x;
    if (j < Dout) {
        float acc = 0.f;
        for (int f = 0; f < 128; ++f) acc = fmaf(s[f], W2[f * Dout + j], acc);
        out[j] = acc + (float)N * b2[j];
    }
}

extern "C" void kernel_launch(void* const* d_in, const int* in_sizes, int n_in,
                              void* d_out, int out_size, void* d_ws, size_t ws_size,
                              hipStream_t stream)
{
    const float* nf  = (const float*)d_in[0];
    const int*   ei  = (const int*)d_in[1];
    const float* ew  = (const float*)d_in[2];
    const float* W0  = (const float*)d_in[3];
    // b0 = d_in[4], b1 = d_in[6]: cancel inside BatchNorm, unused
    const float* W1  = (const float*)d_in[5];
    const float* W2  = (const float*)d_in[7];
    const float* b2  = (const float*)d_in[8];
    const float* g0  = (const float*)d_in[9];
    const float* be0 = (const float*)d_in[10];
    const float* g1  = (const float*)d_in[11];
    const float* be1 = (const float*)d_in[12];

    const int N = in_sizes[0] / 128;
    const int E = in_sizes[2];
    const int* srcI = ei;       // edge_index[0,:]
    const int* dstI = ei + E;   // edge_index[1,:]

    const int B = (N + NPB - 1) / NPB;        // 196 for N=100k
    const int chunk = (E + PB - 1) / PB;

    const size_t HB = ((size_t)N * 128 * 2 + 255) & ~(size_t)255;  // bf16 buf
    const size_t NA = ((size_t)N * sizeof(int) + 255) & ~(size_t)255;
    const size_t CB = (((size_t)B * PB * 4) + 255) & ~(size_t)255;
    char* ws = (char*)d_ws;
    size_t off = 0;
    float* cw    = (float*)(ws + off); off += NA;
    int*   rp    = (int*)  (ws + off); off += NA;
    float* stats = (float*)(ws + off); off += 36864;   // 4 sliced arrays + svec
    int*   cntD  = (int*)  (ws + off); off += CB;
    int*   baseD = (int*)  (ws + off); off += 2048;
    uint2* hbuf  = (uint2*)(ws + off); off += HB;      // h (fp8, oversized ok)
    unsigned* aggb = (unsigned*)(ws + off); off += HB; // agg (bf16)
    int2*  packed = (int2*)(ws + off); off += (size_t)E * 8;
    uint2* bktD  = (uint2*)(ws + off); off += (size_t)E * 8;
    unsigned short* wt0 = (unsigned short*)(ws + off); off += 32768;
    unsigned short* wt1 = (unsigned short*)(ws + off); off += 32768;
    (void)ws_size;  // previous rounds proved ws_size >= 116.5 MB; this needs ~66 MB

    // sliced stats: each array NSLICE*128 floats
    float* sum0 = stats + 0 * NSLICE * 128;
    float* sq0  = stats + 1 * NSLICE * 128;
    float* sum1 = stats + 2 * NSLICE * 128;
    float* sq1  = stats + 3 * NSLICE * 128;
    float* svec = stats + 4 * NSLICE * 128;   // [128]

    const int gemmGrid = (N + 63) / 64;
    const int aggGrid  = (N + 4 * AGG_R - 1) / (4 * AGG_R);   // 1563

    // wconv first: W transpose + stats/cw zeroing before place needs cw
    wconv<<<64, 256, 0, stream>>>(W0, W1, wt0, wt1, stats, cw, N);

    // ---- atomic-free CSR build (dst side); cw via atomics in place ----
    bucket_hist<<<PB, 256, 0, stream>>>(dstI, cntD, E, B, chunk);
    bucket_base<<<1, 256, 0, stream>>>(cntD, baseD, B, E);
    bucket_cursor<<<B, 256, 0, stream>>>(cntD, baseD);
    bucket_place<<<PB, 256, 0, stream>>>(srcI, dstI, ew, cntD, bktD, cw, E, B, chunk);
    bucket_sort<<<B, 256, 0, stream>>>(bktD, baseD, rp, packed, N);

    // ---- layer 0 ----
    gemm0<<<gemmGrid, 256, 0, stream>>>(nf, wt0, hbuf, N);
    aggregate4<<<aggGrid, 256, 0, stream>>>(
        packed, rp, (const uint2*)hbuf, (uint4*)aggb, sum0, sq0, N);

    // ---- layer 1 (BN0+ReLU folded into GEMM staging) ----
    gemm1<<<gemmGrid, 256, 0, stream>>>(aggb, wt1, hbuf, sum0, sq0, g0, be0, N, N);
    aggregate4<<<aggGrid, 256, 0, stream>>>(
        packed, rp, (const uint2*)hbuf, (uint4*)aggb, sum1, sq1, N);

    // ---- collapsed layer 2: out = (sum_n cw[n]*relu(BN1(x2))[n,:]) @ W2 + N*b2 ----
    wcolsum_bf16<<<256, 256, 0, stream>>>(aggb, cw, sum1, sq1, g1, be1, svec, N);
    final_out<<<1, 64, 0, stream>>>(svec, W2, b2, (float*)d_out, N, out_size);
}

// Round 2
// 415.537 us; speedup vs baseline: 1.0555x; 1.0555x over previous
//
#include <hip/hip_runtime.h>

#define BN_EPS 1e-5f

// Bucket-sort parameters: NPB nodes per bucket (pow2), PB placement blocks.
#define NPB 512
#define NPB_SHIFT 9
#define PB 512
#define MAXB 256
// BN-stat accumulator slices (atomic-depth reduction)
#define NSLICE 16

typedef __attribute__((ext_vector_type(8))) short short8;
typedef __attribute__((ext_vector_type(4))) float floatx4;
typedef __attribute__((ext_vector_type(2))) float floatx2;

__device__ __forceinline__ unsigned short f2bf(float f) {
    unsigned u = __float_as_uint(f);
    unsigned r = u + 0x7FFFu + ((u >> 16) & 1u);   // round-to-nearest-even
    return (unsigned short)(r >> 16);
}
__device__ __forceinline__ float blo(unsigned v) { return __uint_as_float(v << 16); }
__device__ __forceinline__ float bhi(unsigned v) { return __uint_as_float(v & 0xffff0000u); }

// pack 8 fp32 -> 8 fp8 e4m3 (2 dwords); byte k of output = value k
__device__ __forceinline__ uint2 pk8_fp8(const float4 v0, const float4 v1) {
    int lo = 0, hi = 0;
    lo = __builtin_amdgcn_cvt_pk_fp8_f32(v0.x, v0.y, lo, false);
    lo = __builtin_amdgcn_cvt_pk_fp8_f32(v0.z, v0.w, lo, true);
    hi = __builtin_amdgcn_cvt_pk_fp8_f32(v1.x, v1.y, hi, false);
    hi = __builtin_amdgcn_cvt_pk_fp8_f32(v1.z, v1.w, hi, true);
    return make_uint2((unsigned)lo, (unsigned)hi);
}

// ------- W pre-transpose (+ stats zeroing folded in, saves a dispatch) -------
__global__ __launch_bounds__(256) void wconv(
    const float* __restrict__ W0, const float* __restrict__ W1,
    unsigned short* __restrict__ wt0, unsigned short* __restrict__ wt1,
    float* __restrict__ stats)
{
    const int idx = blockIdx.x * 256 + threadIdx.x;   // < 16384
    const int n = idx >> 7, k = idx & 127;
    wt0[idx] = f2bf(W0[k * 128 + n]);
    wt1[idx] = f2bf(W1[k * 128 + n]);
    if (blockIdx.x < 9) {   // zero 9216 floats (4 sliced stat arrays + svec)
        const int o = (blockIdx.x * 256 + threadIdx.x) * 4;
        *(float4*)&stats[o] = make_float4(0.f, 0.f, 0.f, 0.f);
    }
}

// ------- layer-0 GEMM: C[M x 128] = A_fp32 @ W, C in fp8 e4m3 -------
__global__ __launch_bounds__(256) void gemm0(
    const float* __restrict__ A, const unsigned short* __restrict__ Wt,
    uint2* __restrict__ C, int M)
{
    __shared__ char lds[53248];
    unsigned short* Al = (unsigned short*)lds;            // [64][136] bf16
    unsigned short* Wl = (unsigned short*)(lds + 17408);  // [128][136] bf16
    float* Cl = (float*)lds;                              // [64][132] f32 (reuse)

    const int tid = threadIdx.x;
    const int r0 = blockIdx.x * 64;

#pragma unroll
    for (int i = 0; i < 16; ++i) {
        const int idx = i * 256 + tid;          // ushort4 units
        const int n = idx >> 5, q = idx & 31;
        const ushort4 v = ((const ushort4*)Wt)[idx];
        *(ushort4*)&Wl[n * 136 + q * 4] = v;
    }
#pragma unroll
    for (int i = 0; i < 8; ++i) {
        const int row = i * 8 + (tid >> 5), q = tid & 31;
        const int gr = r0 + row;
        float4 v = (gr < M) ? ((const float4*)A)[(size_t)gr * 32 + q]
                            : make_float4(0.f, 0.f, 0.f, 0.f);
        ushort4 o;
        o.x = f2bf(v.x); o.y = f2bf(v.y); o.z = f2bf(v.z); o.w = f2bf(v.w);
        *(ushort4*)&Al[row * 136 + q * 4] = o;
    }
    __syncthreads();

    const int wave = tid >> 6, lane = tid & 63;
    const int lrow = lane & 15, quad = lane >> 4;
    const int n0 = wave * 32;

    floatx4 acc[4][2];
#pragma unroll
    for (int mt = 0; mt < 4; ++mt)
#pragma unroll
        for (int t = 0; t < 2; ++t)
#pragma unroll
            for (int j = 0; j < 4; ++j) acc[mt][t][j] = 0.f;

#pragma unroll
    for (int c = 0; c < 4; ++c) {
        const int k0 = c * 32;
        const short8 b0 = *(const short8*)&Wl[(n0 + lrow) * 136 + k0 + quad * 8];
        const short8 b1 = *(const short8*)&Wl[(n0 + 16 + lrow) * 136 + k0 + quad * 8];
#pragma unroll
        for (int mt = 0; mt < 4; ++mt) {
            const short8 a = *(const short8*)&Al[(mt * 16 + lrow) * 136 + k0 + quad * 8];
            acc[mt][0] = __builtin_amdgcn_mfma_f32_16x16x32_bf16(a, b0, acc[mt][0], 0, 0, 0);
            acc[mt][1] = __builtin_amdgcn_mfma_f32_16x16x32_bf16(a, b1, acc[mt][1], 0, 0, 0);
        }
    }
    __syncthreads();

#pragma unroll
    for (int mt = 0; mt < 4; ++mt)
#pragma unroll
        for (int t = 0; t < 2; ++t)
#pragma unroll
            for (int j = 0; j < 4; ++j)
                Cl[(mt * 16 + quad * 4 + j) * 132 + n0 + t * 16 + lrow] = acc[mt][t][j];
    __syncthreads();

#pragma unroll
    for (int i = 0; i < 4; ++i) {
        const int row = i * 16 + (tid >> 4);
        const int c0 = (tid & 15) * 8;
        const int gr = r0 + row;
        if (gr < M) {
            const float4 v0 = *(float4*)&Cl[row * 132 + c0];
            const float4 v1 = *(float4*)&Cl[row * 132 + c0 + 4];
            C[(size_t)gr * 16 + (c0 >> 3)] = pk8_fp8(v0, v1);
        }
    }
}

// ------- layer-1 GEMM: C = relu(BN(A_bf16)) @ W, C in fp8 e4m3 -------
__global__ __launch_bounds__(256) void gemm1(
    const unsigned* __restrict__ Ab, const unsigned short* __restrict__ Wt,
    uint2* __restrict__ C,
    const float* __restrict__ sum, const float* __restrict__ sq,
    const float* __restrict__ g, const float* __restrict__ be,
    int M, int N)
{
    __shared__ char lds[53248];
    unsigned short* Al = (unsigned short*)lds;            // [64][136]
    unsigned short* Wl = (unsigned short*)(lds + 17408);  // [128][136]
    float* AscL = (float*)(lds + 52224);                  // [128]
    float* AshL = AscL + 128;
    float* Cl = (float*)lds;

    const int tid = threadIdx.x;
    const int r0 = blockIdx.x * 64;

    if (tid < 128) {
        float s = 0.f, q = 0.f;
#pragma unroll
        for (int k = 0; k < NSLICE; ++k) {
            s += sum[k * 128 + tid];
            q += sq[k * 128 + tid];
        }
        const float invN = 1.0f / (float)N;
        const float m = s * invN;
        const float var = q * invN - m * m;
        const float rs = rsqrtf(var + BN_EPS);
        AscL[tid] = g[tid] * rs;
        AshL[tid] = be[tid] - g[tid] * m * rs;
    }
    __syncthreads();

#pragma unroll
    for (int i = 0; i < 16; ++i) {
        const int idx = i * 256 + tid;
        const int n = idx >> 5, q = idx & 31;
        const ushort4 v = ((const ushort4*)Wt)[idx];
        *(ushort4*)&Wl[n * 136 + q * 4] = v;
    }
#pragma unroll
    for (int i = 0; i < 4; ++i) {
        const int idx = i * 256 + tid;
        const int row = idx >> 4, qc = idx & 15;
        const int gr = r0 + row;
        uint4 v = (gr < M) ? ((const uint4*)Ab)[(size_t)gr * 16 + qc]
                           : make_uint4(0, 0, 0, 0);
        const float4 a0 = *(const float4*)&AscL[qc * 8];
        const float4 a1 = *(const float4*)&AscL[qc * 8 + 4];
        const float4 b0 = *(const float4*)&AshL[qc * 8];
        const float4 b1 = *(const float4*)&AshL[qc * 8 + 4];
        float x0 = fmaxf(fmaf(a0.x, blo(v.x), b0.x), 0.f);
        float x1 = fmaxf(fmaf(a0.y, bhi(v.x), b0.y), 0.f);
        float x2 = fmaxf(fmaf(a0.z, blo(v.y), b0.z), 0.f);
        float x3 = fmaxf(fmaf(a0.w, bhi(v.y), b0.w), 0.f);
        float x4 = fmaxf(fmaf(a1.x, blo(v.z), b1.x), 0.f);
        float x5 = fmaxf(fmaf(a1.y, bhi(v.z), b1.y), 0.f);
        float x6 = fmaxf(fmaf(a1.z, blo(v.w), b1.z), 0.f);
        float x7 = fmaxf(fmaf(a1.w, bhi(v.w), b1.w), 0.f);
        uint4 o;
        o.x = (unsigned)f2bf(x0) | ((unsigned)f2bf(x1) << 16);
        o.y = (unsigned)f2bf(x2) | ((unsigned)f2bf(x3) << 16);
        o.z = (unsigned)f2bf(x4) | ((unsigned)f2bf(x5) << 16);
        o.w = (unsigned)f2bf(x6) | ((unsigned)f2bf(x7) << 16);
        *(uint4*)&Al[row * 136 + qc * 8] = o;
    }
    __syncthreads();

    const int wave = tid >> 6, lane = tid & 63;
    const int lrow = lane & 15, quad = lane >> 4;
    const int n0 = wave * 32;

    floatx4 acc[4][2];
#pragma unroll
    for (int mt = 0; mt < 4; ++mt)
#pragma unroll
        for (int t = 0; t < 2; ++t)
#pragma unroll
            for (int j = 0; j < 4; ++j) acc[mt][t][j] = 0.f;

#pragma unroll
    for (int c = 0; c < 4; ++c) {
        const int k0 = c * 32;
        const short8 b0 = *(const short8*)&Wl[(n0 + lrow) * 136 + k0 + quad * 8];
        const short8 b1 = *(const short8*)&Wl[(n0 + 16 + lrow) * 136 + k0 + quad * 8];
#pragma unroll
        for (int mt = 0; mt < 4; ++mt) {
            const short8 a = *(const short8*)&Al[(mt * 16 + lrow) * 136 + k0 + quad * 8];
            acc[mt][0] = __builtin_amdgcn_mfma_f32_16x16x32_bf16(a, b0, acc[mt][0], 0, 0, 0);
            acc[mt][1] = __builtin_amdgcn_mfma_f32_16x16x32_bf16(a, b1, acc[mt][1], 0, 0, 0);
        }
    }
    __syncthreads();

#pragma unroll
    for (int mt = 0; mt < 4; ++mt)
#pragma unroll
        for (int t = 0; t < 2; ++t)
#pragma unroll
            for (int j = 0; j < 4; ++j)
                Cl[(mt * 16 + quad * 4 + j) * 132 + n0 + t * 16 + lrow] = acc[mt][t][j];
    __syncthreads();

#pragma unroll
    for (int i = 0; i < 4; ++i) {
        const int row = i * 16 + (tid >> 4);
        const int c0 = (tid & 15) * 8;
        const int gr = r0 + row;
        if (gr < M) {
            const float4 v0 = *(float4*)&Cl[row * 132 + c0];
            const float4 v1 = *(float4*)&Cl[row * 132 + c0 + 4];
            C[(size_t)gr * 16 + (c0 >> 3)] = pk8_fp8(v0, v1);
        }
    }
}

// ============ atomic-free CSR build: two-level bucket counting sort ============
// R1 lesson: global atomicAdd(&cw[s]) storm cost +30us in bucket_place
// (VALUBusy 0.6%, 16-way address contention, grid-capped occupancy).
// The src-side bucket pipeline (bktS -> LDS segment sums) is cheaper: restored.

__global__ __launch_bounds__(256) void bucket_hist(
    const int* __restrict__ src, const int* __restrict__ dst,
    int* __restrict__ cntD, int* __restrict__ cntS, int E, int B, int chunk)
{
    __shared__ int hD[MAXB], hS[MAXB];
    const int tid = threadIdx.x;
    for (int i = tid; i < B; i += 256) { hD[i] = 0; hS[i] = 0; }
    __syncthreads();
    const int lo = blockIdx.x * chunk;
    const int hi = min(E, lo + chunk);
    for (int e = lo + tid; e < hi; e += 256) {
        atomicAdd(&hD[dst[e] >> NPB_SHIFT], 1);
        atomicAdd(&hS[src[e] >> NPB_SHIFT], 1);
    }
    __syncthreads();
    for (int i = tid; i < B; i += 256) {
        cntD[i * PB + blockIdx.x] = hD[i];
        cntS[i * PB + blockIdx.x] = hS[i];
    }
}

__global__ __launch_bounds__(256) void bucket_base(
    const int* __restrict__ cntD, const int* __restrict__ cntS,
    int* __restrict__ baseD, int* __restrict__ baseS, int B, int E)
{
    __shared__ int lD[256], lS[256];
    const int tid = threadIdx.x;
    int sD = 0, sS = 0;
    if (tid < B) {
        const int4* pD = (const int4*)(cntD + tid * PB);
        const int4* pS = (const int4*)(cntS + tid * PB);
        for (int j = 0; j < PB / 4; ++j) {
            const int4 a = pD[j], b = pS[j];
            sD += a.x + a.y + a.z + a.w;
            sS += b.x + b.y + b.z + b.w;
        }
    }
    lD[tid] = sD; lS[tid] = sS;
    __syncthreads();
    for (int st = 1; st < 256; st <<= 1) {
        const int vD = (tid >= st) ? lD[tid - st] : 0;
        const int vS = (tid >= st) ? lS[tid - st] : 0;
        __syncthreads();
        lD[tid] += vD; lS[tid] += vS;
        __syncthreads();
    }
    if (tid < B) { baseD[tid] = lD[tid] - sD; baseS[tid] = lS[tid] - sS; }
    if (tid == 0) { baseD[B] = E; baseS[B] = E; }
}

__global__ __launch_bounds__(256) void bucket_cursor(
    int* __restrict__ cntD, int* __restrict__ cntS,
    const int* __restrict__ baseD, const int* __restrict__ baseS, int B)
{
    int b = blockIdx.x;
    int* cnt; const int* base;
    if (b < B) { cnt = cntD; base = baseD; }
    else       { cnt = cntS; base = baseS; b -= B; }
    __shared__ int ls[256];
    const int tid = threadIdx.x;
    const int c0 = cnt[b * PB + 2 * tid];
    const int c1 = cnt[b * PB + 2 * tid + 1];
    const int s = c0 + c1;
    ls[tid] = s;
    __syncthreads();
    for (int st = 1; st < 256; st <<= 1) {
        const int v = (tid >= st) ? ls[tid - st] : 0;
        __syncthreads();
        ls[tid] += v;
        __syncthreads();
    }
    const int excl = ls[tid] - s + base[b];
    cnt[b * PB + 2 * tid] = excl;
    cnt[b * PB + 2 * tid + 1] = excl + c0;
}

__global__ __launch_bounds__(256) void bucket_place(
    const int* __restrict__ src, const int* __restrict__ dst,
    const float* __restrict__ ew,
    const int* __restrict__ curD, const int* __restrict__ curS,
    uint2* __restrict__ bktD, uint2* __restrict__ bktS, int E, int B, int chunk)
{
    __shared__ int cD[MAXB], cS[MAXB];
    const int tid = threadIdx.x;
    for (int i = tid; i < B; i += 256) {
        cD[i] = curD[i * PB + blockIdx.x];
        cS[i] = curS[i * PB + blockIdx.x];
    }
    __syncthreads();
    const int lo = blockIdx.x * chunk;
    const int hi = min(E, lo + chunk);
    for (int e = lo + tid; e < hi; e += 256) {
        const int s = src[e], d = dst[e];
        const unsigned wb = __float_as_uint(ew[e]);
        const int pd = atomicAdd(&cD[d >> NPB_SHIFT], 1);
        bktD[pd] = make_uint2(((unsigned)s << NPB_SHIFT) | (unsigned)(d & (NPB - 1)), wb);
        const int ps = atomicAdd(&cS[s >> NPB_SHIFT], 1);
        bktS[ps] = make_uint2((unsigned)(s & (NPB - 1)), wb);
    }
}

// merged: blocks [0,B) counting-sort bktD -> rp/packed; blocks [B,2B) cw sums
__global__ __launch_bounds__(256) void bucket_sortcw(
    const uint2* __restrict__ bktD, const int* __restrict__ baseD,
    int* __restrict__ rp, int2* __restrict__ packed,
    const uint2* __restrict__ bktS, const int* __restrict__ baseS,
    float* __restrict__ cw, int N, int B)
{
    const int tid = threadIdx.x;
    if (blockIdx.x >= B) {
        const int b = blockIdx.x - B;
        const int lo = baseS[b], hi = baseS[b + 1];
        __shared__ float sm[NPB];
        sm[2 * tid] = 0.f; sm[2 * tid + 1] = 0.f;
        __syncthreads();
        for (int i = lo + tid; i < hi; i += 256) {
            const uint2 r = bktS[i];
            atomicAdd(&sm[r.x], __uint_as_float(r.y));
        }
        __syncthreads();
        const int n0 = b * NPB + 2 * tid;
        if (n0 < N)     cw[n0]     = sm[2 * tid];
        if (n0 + 1 < N) cw[n0 + 1] = sm[2 * tid + 1];
        return;
    }
    const int b = blockIdx.x;
    const int lo = baseD[b], hi = baseD[b + 1];
    __shared__ int cnt[NPB], cur[NPB];
    __shared__ int ls[256];
    cnt[2 * tid] = 0; cnt[2 * tid + 1] = 0;
    __syncthreads();
    for (int i = lo + tid; i < hi; i += 256)
        atomicAdd(&cnt[bktD[i].x & (NPB - 1)], 1);
    __syncthreads();
    const int c0 = cnt[2 * tid], c1 = cnt[2 * tid + 1];
    const int s = c0 + c1;
    ls[tid] = s;
    __syncthreads();
    for (int st = 1; st < 256; st <<= 1) {
        const int v = (tid >= st) ? ls[tid - st] : 0;
        __syncthreads();
        ls[tid] += v;
        __syncthreads();
    }
    const int excl = ls[tid] - s;
    const int n0 = b * NPB + 2 * tid;
    if (n0 < N)     rp[n0]     = lo + excl + c0;
    if (n0 + 1 < N) rp[n0 + 1] = lo + excl + c0 + c1;
    cur[2 * tid]     = lo + excl;
    cur[2 * tid + 1] = lo + excl + c0;
    __syncthreads();
    for (int i = lo + tid; i < hi; i += 256) {
        const uint2 r = bktD[i];
        const int pos = atomicAdd(&cur[r.x & (NPB - 1)], 1);
        packed[pos] = make_int2((int)(r.x >> NPB_SHIFT), (int)r.y);
    }
}

// ------- fused aggregate + BN stats (v10: 2-node interleave, 2x gather MLP) ---
// R0-theory: aggregate4 was latency-bound (VALUBusy 49%, HBM 21%, MLP=4
// loads/lane, serial per-node chains). Pair nodes (r,r+1): 8 gathers in
// flight per j-iter, shared reduce, sub0/sub1 quarter-waves write A/B rows.
#define AGG_R 16

#define GATHER4(CUR, J, CNT, V0, V1, V2, V3, W0, W1, W2, W3) do { \
    const int i0_ = (J) + sub, i1_ = i0_ + 4, i2_ = i0_ + 8, i3_ = i0_ + 12; \
    const int c0_ = (i0_ < (CNT)) ? i0_ : 0; \
    const int c1_ = (i1_ < (CNT)) ? i1_ : 0; \
    const int c2_ = (i2_ < (CNT)) ? i2_ : 0; \
    const int c3_ = (i3_ < (CNT)) ? i3_ : 0; \
    const int s0_ = __shfl((CUR).x, c0_, 64); \
    const int s1_ = __shfl((CUR).x, c1_, 64); \
    const int s2_ = __shfl((CUR).x, c2_, 64); \
    const int s3_ = __shfl((CUR).x, c3_, 64); \
    W0 = __uint_as_float((unsigned)__shfl((CUR).y, c0_, 64)); \
    W1 = __uint_as_float((unsigned)__shfl((CUR).y, c1_, 64)); \
    W2 = __uint_as_float((unsigned)__shfl((CUR).y, c2_, 64)); \
    W3 = __uint_as_float((unsigned)__shfl((CUR).y, c3_, 64)); \
    if (i0_ >= (CNT)) W0 = 0.f; \
    if (i1_ >= (CNT)) W1 = 0.f; \
    if (i2_ >= (CNT)) W2 = 0.f; \
    if (i3_ >= (CNT)) W3 = 0.f; \
    V0 = h2[(size_t)s0_ * 16 + u]; \
    V1 = h2[(size_t)s1_ * 16 + u]; \
    V2 = h2[(size_t)s2_ * 16 + u]; \
    V3 = h2[(size_t)s3_ * 16 + u]; \
} while (0)

#define ACC_EDGE(V, W, A) do { \
    floatx2 f_; \
    f_ = __builtin_amdgcn_cvt_pk_f32_fp8((int)(V).x, false); \
    A[0] = fmaf(W, f_.x, A[0]); A[1] = fmaf(W, f_.y, A[1]); \
    f_ = __builtin_amdgcn_cvt_pk_f32_fp8((int)(V).x, true);  \
    A[2] = fmaf(W, f_.x, A[2]); A[3] = fmaf(W, f_.y, A[3]); \
    f_ = __builtin_amdgcn_cvt_pk_f32_fp8((int)(V).y, false); \
    A[4] = fmaf(W, f_.x, A[4]); A[5] = fmaf(W, f_.y, A[5]); \
    f_ = __builtin_amdgcn_cvt_pk_f32_fp8((int)(V).y, true);  \
    A[6] = fmaf(W, f_.x, A[6]); A[7] = fmaf(W, f_.y, A[7]); \
} while (0)

__global__ __launch_bounds__(256) void aggregate4(
    const int2* __restrict__ packed, const int* __restrict__ rp,
    const uint2* __restrict__ h2, uint4* __restrict__ aggb4,
    float* __restrict__ sum, float* __restrict__ sq, int N)
{
    const int tid = threadIdx.x;
    const int lane = tid & 63, wave = tid >> 6;
    const int sub = lane >> 4;          // quarter 0..3
    const int u = lane & 15;            // cols 8u..8u+7
    const int n0 = (blockIdx.x * 4 + wave) * AGG_R;

    // coalesced row-pointer block: lane l holds rp[n0-1+l] (rp[n]=end of node n)
    int rpv = 0;
    {
        const int idx = n0 - 1 + lane;
        if (lane <= AGG_R && idx >= 0 && idx < N) rpv = rp[idx];
    }

    float csum[8], csq[8];
#pragma unroll
    for (int k = 0; k < 8; ++k) { csum[k] = 0.f; csq[k] = 0.f; }

    // prefetch first pair's first edge chunks
    int2 curA = make_int2(0, 0), curB = make_int2(0, 0);
    if (n0 < N) {
        const int sa = __shfl(rpv, 0, 64), ea = __shfl(rpv, 1, 64);
        if (lane < min(64, ea - sa)) curA = packed[sa + lane];
    }
    if (n0 + 1 < N) {
        const int sb = __shfl(rpv, 1, 64), eb = __shfl(rpv, 2, 64);
        if (lane < min(64, eb - sb)) curB = packed[sb + lane];
    }

    for (int r = 0; r < AGG_R; r += 2) {
        const int nA = n0 + r;
        if (nA >= N) break;
        const int nB = nA + 1;
        const bool hasB = (nB < N);
        const int sA = __shfl(rpv, r, 64);
        const int eA = __shfl(rpv, r + 1, 64);
        const int sB = eA;
        const int eB = hasB ? __shfl(rpv, r + 2, 64) : sB;

        // prefetch next pair's first chunks (overlaps this pair's gathers)
        int2 nxtA = make_int2(0, 0), nxtB = make_int2(0, 0);
        if (r + 2 < AGG_R && nA + 2 < N) {
            const int ns = __shfl(rpv, r + 2, 64), ne = __shfl(rpv, r + 3, 64);
            if (lane < min(64, ne - ns)) nxtA = packed[ns + lane];
        }
        if (r + 3 < AGG_R && nA + 3 < N) {
            const int ns = __shfl(rpv, r + 3, 64), ne = __shfl(rpv, r + 4, 64);
            if (lane < min(64, ne - ns)) nxtB = packed[ns + lane];
        }

        float aA[8], aB[8];
#pragma unroll
        for (int k = 0; k < 8; ++k) { aA[k] = 0.f; aB[k] = 0.f; }

        const int cA = min(64, eA - sA);
        const int cB = min(64, eB - sB);
        const int cmax = (cA > cB) ? cA : cB;

        // interleaved first-chunk processing: up to 8 gathers in flight
        for (int j = 0; j < cmax; j += 16) {
            const bool doA = j < cA, doB = j < cB;
            uint2 vA0, vA1, vA2, vA3, vB0, vB1, vB2, vB3;
            float wA0, wA1, wA2, wA3, wB0, wB1, wB2, wB3;
            if (doA & doB) {
                GATHER4(curA, j, cA, vA0, vA1, vA2, vA3, wA0, wA1, wA2, wA3);
                GATHER4(curB, j, cB, vB0, vB1, vB2, vB3, wB0, wB1, wB2, wB3);
                ACC_EDGE(vA0, wA0, aA); ACC_EDGE(vA1, wA1, aA);
                ACC_EDGE(vA2, wA2, aA); ACC_EDGE(vA3, wA3, aA);
                ACC_EDGE(vB0, wB0, aB); ACC_EDGE(vB1, wB1, aB);
                ACC_EDGE(vB2, wB2, aB); ACC_EDGE(vB3, wB3, aB);
            } else if (doA) {
                GATHER4(curA, j, cA, vA0, vA1, vA2, vA3, wA0, wA1, wA2, wA3);
                ACC_EDGE(vA0, wA0, aA); ACC_EDGE(vA1, wA1, aA);
                ACC_EDGE(vA2, wA2, aA); ACC_EDGE(vA3, wA3, aA);
            } else {
                GATHER4(curB, j, cB, vB0, vB1, vB2, vB3, wB0, wB1, wB2, wB3);
                ACC_EDGE(vB0, wB0, aB); ACC_EDGE(vB1, wB1, aB);
                ACC_EDGE(vB2, wB2, aB); ACC_EDGE(vB3, wB3, aB);
            }
        }

        // rare overflow chunks (degree > 64), serial fallback
        for (int base = sA + 64; base < eA; base += 64) {
            const int cnt = min(64, eA - base);
            int2 myE = make_int2(0, 0);
            if (lane < cnt) myE = packed[base + lane];
            for (int j = 0; j < cnt; j += 16) {
                uint2 v0, v1, v2, v3; float w0, w1, w2, w3;
                GATHER4(myE, j, cnt, v0, v1, v2, v3, w0, w1, w2, w3);
                ACC_EDGE(v0, w0, aA); ACC_EDGE(v1, w1, aA);
                ACC_EDGE(v2, w2, aA); ACC_EDGE(v3, w3, aA);
            }
        }
        for (int base = sB + 64; base < eB; base += 64) {
            const int cnt = min(64, eB - base);
            int2 myE = make_int2(0, 0);
            if (lane < cnt) myE = packed[base + lane];
            for (int j = 0; j < cnt; j += 16) {
                uint2 v0, v1, v2, v3; float w0, w1, w2, w3;
                GATHER4(myE, j, cnt, v0, v1, v2, v3, w0, w1, w2, w3);
                ACC_EDGE(v0, w0, aB); ACC_EDGE(v1, w1, aB);
                ACC_EDGE(v2, w2, aB); ACC_EDGE(v3, w3, aB);
            }
        }

        // joint cross-quarter reduce; all lanes end with full sums
#pragma unroll
        for (int k = 0; k < 8; ++k) {
            aA[k] += __shfl_xor(aA[k], 16, 64);
            aB[k] += __shfl_xor(aB[k], 16, 64);
            aA[k] += __shfl_xor(aA[k], 32, 64);
            aB[k] += __shfl_xor(aB[k], 32, 64);
        }
        if (sub == 0) {
            uint4 o;
            o.x = (unsigned)f2bf(aA[0]) | ((unsigned)f2bf(aA[1]) << 16);
            o.y = (unsigned)f2bf(aA[2]) | ((unsigned)f2bf(aA[3]) << 16);
            o.z = (unsigned)f2bf(aA[4]) | ((unsigned)f2bf(aA[5]) << 16);
            o.w = (unsigned)f2bf(aA[6]) | ((unsigned)f2bf(aA[7]) << 16);
            aggb4[(size_t)nA * 16 + u] = o;
#pragma unroll
            for (int k = 0; k < 8; ++k) {
                csum[k] += aA[k];
                csq[k] = fmaf(aA[k], aA[k], csq[k]);
            }
        } else if (sub == 1 && hasB) {
            uint4 o;
            o.x = (unsigned)f2bf(aB[0]) | ((unsigned)f2bf(aB[1]) << 16);
            o.y = (unsigned)f2bf(aB[2]) | ((unsigned)f2bf(aB[3]) << 16);
            o.z = (unsigned)f2bf(aB[4]) | ((unsigned)f2bf(aB[5]) << 16);
            o.w = (unsigned)f2bf(aB[6]) | ((unsigned)f2bf(aB[7]) << 16);
            aggb4[(size_t)nB * 16 + u] = o;
#pragma unroll
            for (int k = 0; k < 8; ++k) {
                csum[k] += aB[k];
                csq[k] = fmaf(aB[k], aB[k], csq[k]);
            }
        }
        curA = nxtA;
        curB = nxtB;
    }

    // 8 stat slots: [wave] from sub0 (A nodes), [4+wave] from sub1 (B nodes)
    __shared__ float lsum[1024], lsq[1024];
    if (sub == 0) {
#pragma unroll
        for (int k = 0; k < 8; ++k) {
            lsum[wave * 128 + u * 8 + k] = csum[k];
            lsq[wave * 128 + u * 8 + k] = csq[k];
        }
    } else if (sub == 1) {
#pragma unroll
        for (int k = 0; k < 8; ++k) {
            lsum[(4 + wave) * 128 + u * 8 + k] = csum[k];
            lsq[(4 + wave) * 128 + u * 8 + k] = csq[k];
        }
    }
    __syncthreads();
    if (tid < 128) {
        float s = 0.f, q = 0.f;
#pragma unroll
        for (int i = 0; i < 8; ++i) {
            s += lsum[i * 128 + tid];
            q += lsq[i * 128 + tid];
        }
        const int sl = (blockIdx.x & (NSLICE - 1)) * 128;
        atomicAdd(&sum[sl + tid], s);
        atomicAdd(&sq[sl + tid], q);
    }
}

// ---------------- collapsed layer 2 (persistent grid, sliced-stat prologue) ----
__global__ __launch_bounds__(256) void wcolsum_bf16(
    const unsigned* __restrict__ xb, const float* __restrict__ cw,
    const float* __restrict__ sum1, const float* __restrict__ sq1,
    const float* __restrict__ g, const float* __restrict__ be,
    float* __restrict__ sout, int N)
{
    __shared__ float Aaf[128], Baf[128];
    __shared__ float2 ls[256];
    const int tid = threadIdx.x;
    if (tid < 128) {
        float s = 0.f, q = 0.f;
#pragma unroll
        for (int k = 0; k < NSLICE; ++k) {
            s += sum1[k * 128 + tid];
            q += sq1[k * 128 + tid];
        }
        const float invN = 1.0f / (float)N;
        const float m = s * invN;
        const float var = q * invN - m * m;
        const float rs = rsqrtf(var + BN_EPS);
        Aaf[tid] = g[tid] * rs;
        Baf[tid] = be[tid] - g[tid] * m * rs;
    }
    __syncthreads();
    const int u = tid & 63, rr = tid >> 6;
    const float ax = Aaf[2 * u], ay = Aaf[2 * u + 1];
    const float bx = Baf[2 * u], by = Baf[2 * u + 1];
    float2 s = {0.f, 0.f};
    for (int row = blockIdx.x * 4 + rr; row < N; row += gridDim.x * 4) {
        const unsigned v = xb[(size_t)row * 64 + u];
        const float c = cw[row];
        const float x = fmaxf(fmaf(ax, blo(v), bx), 0.f);
        const float y = fmaxf(fmaf(ay, bhi(v), by), 0.f);
        s.x = fmaf(c, x, s.x);
        s.y = fmaf(c, y, s.y);
    }
    ls[tid] = s;
    __syncthreads();
    if (tid < 64) {
        float sx = ls[tid].x + ls[64 + tid].x + ls[128 + tid].x + ls[192 + tid].x;
        float sy = ls[tid].y + ls[64 + tid].y + ls[128 + tid].y + ls[192 + tid].y;
        atomicAdd(&sout[2 * tid + 0], sx);
        atomicAdd(&sout[2 * tid + 1], sy);
    }
}

__global__ void final_out(
    const float* __restrict__ s, const float* __restrict__ W2,
    const float* __restrict__ b2, float* __restrict__ out, int N, int Dout)
{
    const int j = threadIdx.x;
    if (j < Dout) {
        float acc = 0.f;
        for (int f = 0; f < 128; ++f) acc = fmaf(s[f], W2[f * Dout + j], acc);
        out[j] = acc + (float)N * b2[j];
    }
}

extern "C" void kernel_launch(void* const* d_in, const int* in_sizes, int n_in,
                              void* d_out, int out_size, void* d_ws, size_t ws_size,
                              hipStream_t stream)
{
    const float* nf  = (const float*)d_in[0];
    const int*   ei  = (const int*)d_in[1];
    const float* ew  = (const float*)d_in[2];
    const float* W0  = (const float*)d_in[3];
    // b0 = d_in[4], b1 = d_in[6]: cancel inside BatchNorm, unused
    const float* W1  = (const float*)d_in[5];
    const float* W2  = (const float*)d_in[7];
    const float* b2  = (const float*)d_in[8];
    const float* g0  = (const float*)d_in[9];
    const float* be0 = (const float*)d_in[10];
    const float* g1  = (const float*)d_in[11];
    const float* be1 = (const float*)d_in[12];

    const int N = in_sizes[0] / 128;
    const int E = in_sizes[2];
    const int* srcI = ei;       // edge_index[0,:]
    const int* dstI = ei + E;   // edge_index[1,:]

    const int B = (N + NPB - 1) / NPB;        // 196 for N=100k
    const int chunk = (E + PB - 1) / PB;

    const size_t HB = ((size_t)N * 128 * 2 + 255) & ~(size_t)255;  // bf16 buf
    const size_t NA = ((size_t)N * sizeof(int) + 255) & ~(size_t)255;
    const size_t CB = (((size_t)B * PB * 4) + 255) & ~(size_t)255;
    char* ws = (char*)d_ws;
    size_t off = 0;
    float* cw    = (float*)(ws + off); off += NA;
    int*   rp    = (int*)  (ws + off); off += NA;
    float* stats = (float*)(ws + off); off += 36864;   // 4 sliced arrays + svec
    int*   cntD  = (int*)  (ws + off); off += CB;
    int*   cntS  = (int*)  (ws + off); off += CB;
    int*   baseD = (int*)  (ws + off); off += 2048;
    int*   baseS = (int*)  (ws + off); off += 2048;
    uint2* hbuf  = (uint2*)(ws + off); off += HB;      // h (fp8, oversized ok)
    unsigned* aggb = (unsigned*)(ws + off); off += HB; // agg (bf16)
    int2*  packed = (int2*)(ws + off); off += (size_t)E * 8;
    uint2* bktD  = (uint2*)(ws + off); off += (size_t)E * 8;
    uint2* bktS  = (uint2*)(ws + off); off += (size_t)E * 8;
    unsigned short* wt0 = (unsigned short*)(ws + off); off += 32768;
    unsigned short* wt1 = (unsigned short*)(ws + off); off += 32768;
    (void)ws_size;  // rounds 1-11 proved ws_size >= 116.5 MB; this needs ~92 MB

    // sliced stats: each array NSLICE*128 floats
    float* sum0 = stats + 0 * NSLICE * 128;
    float* sq0  = stats + 1 * NSLICE * 128;
    float* sum1 = stats + 2 * NSLICE * 128;
    float* sq1  = stats + 3 * NSLICE * 128;
    float* svec = stats + 4 * NSLICE * 128;   // [128]

    const int gemmGrid = (N + 63) / 64;
    const int aggGrid  = (N + 4 * AGG_R - 1) / (4 * AGG_R);   // 1563

    // ---- atomic-free CSR build + cw (graph identical both layers) ----
    bucket_hist<<<PB, 256, 0, stream>>>(srcI, dstI, cntD, cntS, E, B, chunk);
    bucket_base<<<1, 256, 0, stream>>>(cntD, cntS, baseD, baseS, B, E);
    bucket_cursor<<<2 * B, 256, 0, stream>>>(cntD, cntS, baseD, baseS, B);
    bucket_place<<<PB, 256, 0, stream>>>(srcI, dstI, ew, cntD, cntS, bktD, bktS, E, B, chunk);
    bucket_sortcw<<<2 * B, 256, 0, stream>>>(bktD, baseD, rp, packed,
                                             bktS, baseS, cw, N, B);
    wconv<<<64, 256, 0, stream>>>(W0, W1, wt0, wt1, stats);   // + stats zeroing

    // ---- layer 0 ----
    gemm0<<<gemmGrid, 256, 0, stream>>>(nf, wt0, hbuf, N);
    aggregate4<<<aggGrid, 256, 0, stream>>>(
        packed, rp, (const uint2*)hbuf, (uint4*)aggb, sum0, sq0, N);

    // ---- layer 1 (BN0+ReLU folded into GEMM staging) ----
    gemm1<<<gemmGrid, 256, 0, stream>>>(aggb, wt1, hbuf, sum0, sq0, g0, be0, N, N);
    aggregate4<<<aggGrid, 256, 0, stream>>>(
        packed, rp, (const uint2*)hbuf, (uint4*)aggb, sum1, sq1, N);

    // ---- collapsed layer 2: out = (sum_n cw[n]*relu(BN1(x2))[n,:]) @ W2 + N*b2 ----
    wcolsum_bf16<<<256, 256, 0, stream>>>(aggb, cw, sum1, sq1, g1, be1, svec, N);
    final_out<<<1, 64, 0, stream>>>(svec, W2, b2, (float*)d_out, N, out_size);
}

// Round 3
// 396.232 us; speedup vs baseline: 1.1069x; 1.0487x over previous
//
#include <hip/hip_runtime.h>

#define BN_EPS 1e-5f

// Bucket-sort parameters: NPB nodes per bucket (pow2), PB placement blocks.
#define NPB 512
#define NPB_SHIFT 9
#define PB 512
#define MAXB 256
// BN-stat accumulator slices (atomic-depth reduction)
#define NSLICE 16

typedef __attribute__((ext_vector_type(8))) short short8;
typedef __attribute__((ext_vector_type(4))) float floatx4;
typedef __attribute__((ext_vector_type(2))) float floatx2;

__device__ __forceinline__ unsigned short f2bf(float f) {
    unsigned u = __float_as_uint(f);
    unsigned r = u + 0x7FFFu + ((u >> 16) & 1u);   // round-to-nearest-even
    return (unsigned short)(r >> 16);
}
__device__ __forceinline__ float blo(unsigned v) { return __uint_as_float(v << 16); }
__device__ __forceinline__ float bhi(unsigned v) { return __uint_as_float(v & 0xffff0000u); }

// pack 8 fp32 -> 8 fp8 e4m3 (2 dwords); byte k of output = value k
__device__ __forceinline__ uint2 pk8_fp8(const float4 v0, const float4 v1) {
    int lo = 0, hi = 0;
    lo = __builtin_amdgcn_cvt_pk_fp8_f32(v0.x, v0.y, lo, false);
    lo = __builtin_amdgcn_cvt_pk_fp8_f32(v0.z, v0.w, lo, true);
    hi = __builtin_amdgcn_cvt_pk_fp8_f32(v1.x, v1.y, hi, false);
    hi = __builtin_amdgcn_cvt_pk_fp8_f32(v1.z, v1.w, hi, true);
    return make_uint2((unsigned)lo, (unsigned)hi);
}

// ------- W pre-transpose (+ stats zeroing folded in, saves a dispatch) -------
__global__ __launch_bounds__(256) void wconv(
    const float* __restrict__ W0, const float* __restrict__ W1,
    unsigned short* __restrict__ wt0, unsigned short* __restrict__ wt1,
    float* __restrict__ stats)
{
    const int idx = blockIdx.x * 256 + threadIdx.x;   // < 16384
    const int n = idx >> 7, k = idx & 127;
    wt0[idx] = f2bf(W0[k * 128 + n]);
    wt1[idx] = f2bf(W1[k * 128 + n]);
    if (blockIdx.x < 9) {   // zero 9216 floats (4 sliced stat arrays + svec)
        const int o = (blockIdx.x * 256 + threadIdx.x) * 4;
        *(float4*)&stats[o] = make_float4(0.f, 0.f, 0.f, 0.f);
    }
}

// ------- layer-0 GEMM: C[M x 128] = A_fp32 @ W, C in fp8 e4m3 -------
__global__ __launch_bounds__(256) void gemm0(
    const float* __restrict__ A, const unsigned short* __restrict__ Wt,
    uint2* __restrict__ C, int M)
{
    __shared__ char lds[53248];
    unsigned short* Al = (unsigned short*)lds;            // [64][136] bf16
    unsigned short* Wl = (unsigned short*)(lds + 17408);  // [128][136] bf16
    float* Cl = (float*)lds;                              // [64][132] f32 (reuse)

    const int tid = threadIdx.x;
    const int r0 = blockIdx.x * 64;

#pragma unroll
    for (int i = 0; i < 16; ++i) {
        const int idx = i * 256 + tid;          // ushort4 units
        const int n = idx >> 5, q = idx & 31;
        const ushort4 v = ((const ushort4*)Wt)[idx];
        *(ushort4*)&Wl[n * 136 + q * 4] = v;
    }
#pragma unroll
    for (int i = 0; i < 8; ++i) {
        const int row = i * 8 + (tid >> 5), q = tid & 31;
        const int gr = r0 + row;
        float4 v = (gr < M) ? ((const float4*)A)[(size_t)gr * 32 + q]
                            : make_float4(0.f, 0.f, 0.f, 0.f);
        ushort4 o;
        o.x = f2bf(v.x); o.y = f2bf(v.y); o.z = f2bf(v.z); o.w = f2bf(v.w);
        *(ushort4*)&Al[row * 136 + q * 4] = o;
    }
    __syncthreads();

    const int wave = tid >> 6, lane = tid & 63;
    const int lrow = lane & 15, quad = lane >> 4;
    const int n0 = wave * 32;

    floatx4 acc[4][2];
#pragma unroll
    for (int mt = 0; mt < 4; ++mt)
#pragma unroll
        for (int t = 0; t < 2; ++t)
#pragma unroll
            for (int j = 0; j < 4; ++j) acc[mt][t][j] = 0.f;

#pragma unroll
    for (int c = 0; c < 4; ++c) {
        const int k0 = c * 32;
        const short8 b0 = *(const short8*)&Wl[(n0 + lrow) * 136 + k0 + quad * 8];
        const short8 b1 = *(const short8*)&Wl[(n0 + 16 + lrow) * 136 + k0 + quad * 8];
#pragma unroll
        for (int mt = 0; mt < 4; ++mt) {
            const short8 a = *(const short8*)&Al[(mt * 16 + lrow) * 136 + k0 + quad * 8];
            acc[mt][0] = __builtin_amdgcn_mfma_f32_16x16x32_bf16(a, b0, acc[mt][0], 0, 0, 0);
            acc[mt][1] = __builtin_amdgcn_mfma_f32_16x16x32_bf16(a, b1, acc[mt][1], 0, 0, 0);
        }
    }
    __syncthreads();

#pragma unroll
    for (int mt = 0; mt < 4; ++mt)
#pragma unroll
        for (int t = 0; t < 2; ++t)
#pragma unroll
            for (int j = 0; j < 4; ++j)
                Cl[(mt * 16 + quad * 4 + j) * 132 + n0 + t * 16 + lrow] = acc[mt][t][j];
    __syncthreads();

#pragma unroll
    for (int i = 0; i < 4; ++i) {
        const int row = i * 16 + (tid >> 4);
        const int c0 = (tid & 15) * 8;
        const int gr = r0 + row;
        if (gr < M) {
            const float4 v0 = *(float4*)&Cl[row * 132 + c0];
            const float4 v1 = *(float4*)&Cl[row * 132 + c0 + 4];
            C[(size_t)gr * 16 + (c0 >> 3)] = pk8_fp8(v0, v1);
        }
    }
}

// ------- layer-1 GEMM: C = relu(BN(A_bf16)) @ W, C in fp8 e4m3 -------
__global__ __launch_bounds__(256) void gemm1(
    const unsigned* __restrict__ Ab, const unsigned short* __restrict__ Wt,
    uint2* __restrict__ C,
    const float* __restrict__ sum, const float* __restrict__ sq,
    const float* __restrict__ g, const float* __restrict__ be,
    int M, int N)
{
    __shared__ char lds[53248];
    unsigned short* Al = (unsigned short*)lds;            // [64][136]
    unsigned short* Wl = (unsigned short*)(lds + 17408);  // [128][136]
    float* AscL = (float*)(lds + 52224);                  // [128]
    float* AshL = AscL + 128;
    float* Cl = (float*)lds;

    const int tid = threadIdx.x;
    const int r0 = blockIdx.x * 64;

    if (tid < 128) {
        float s = 0.f, q = 0.f;
#pragma unroll
        for (int k = 0; k < NSLICE; ++k) {
            s += sum[k * 128 + tid];
            q += sq[k * 128 + tid];
        }
        const float invN = 1.0f / (float)N;
        const float m = s * invN;
        const float var = q * invN - m * m;
        const float rs = rsqrtf(var + BN_EPS);
        AscL[tid] = g[tid] * rs;
        AshL[tid] = be[tid] - g[tid] * m * rs;
    }
    __syncthreads();

#pragma unroll
    for (int i = 0; i < 16; ++i) {
        const int idx = i * 256 + tid;
        const int n = idx >> 5, q = idx & 31;
        const ushort4 v = ((const ushort4*)Wt)[idx];
        *(ushort4*)&Wl[n * 136 + q * 4] = v;
    }
#pragma unroll
    for (int i = 0; i < 4; ++i) {
        const int idx = i * 256 + tid;
        const int row = idx >> 4, qc = idx & 15;
        const int gr = r0 + row;
        uint4 v = (gr < M) ? ((const uint4*)Ab)[(size_t)gr * 16 + qc]
                           : make_uint4(0, 0, 0, 0);
        const float4 a0 = *(const float4*)&AscL[qc * 8];
        const float4 a1 = *(const float4*)&AscL[qc * 8 + 4];
        const float4 b0 = *(const float4*)&AshL[qc * 8];
        const float4 b1 = *(const float4*)&AshL[qc * 8 + 4];
        float x0 = fmaxf(fmaf(a0.x, blo(v.x), b0.x), 0.f);
        float x1 = fmaxf(fmaf(a0.y, bhi(v.x), b0.y), 0.f);
        float x2 = fmaxf(fmaf(a0.z, blo(v.y), b0.z), 0.f);
        float x3 = fmaxf(fmaf(a0.w, bhi(v.y), b0.w), 0.f);
        float x4 = fmaxf(fmaf(a1.x, blo(v.z), b1.x), 0.f);
        float x5 = fmaxf(fmaf(a1.y, bhi(v.z), b1.y), 0.f);
        float x6 = fmaxf(fmaf(a1.z, blo(v.w), b1.z), 0.f);
        float x7 = fmaxf(fmaf(a1.w, bhi(v.w), b1.w), 0.f);
        uint4 o;
        o.x = (unsigned)f2bf(x0) | ((unsigned)f2bf(x1) << 16);
        o.y = (unsigned)f2bf(x2) | ((unsigned)f2bf(x3) << 16);
        o.z = (unsigned)f2bf(x4) | ((unsigned)f2bf(x5) << 16);
        o.w = (unsigned)f2bf(x6) | ((unsigned)f2bf(x7) << 16);
        *(uint4*)&Al[row * 136 + qc * 8] = o;
    }
    __syncthreads();

    const int wave = tid >> 6, lane = tid & 63;
    const int lrow = lane & 15, quad = lane >> 4;
    const int n0 = wave * 32;

    floatx4 acc[4][2];
#pragma unroll
    for (int mt = 0; mt < 4; ++mt)
#pragma unroll
        for (int t = 0; t < 2; ++t)
#pragma unroll
            for (int j = 0; j < 4; ++j) acc[mt][t][j] = 0.f;

#pragma unroll
    for (int c = 0; c < 4; ++c) {
        const int k0 = c * 32;
        const short8 b0 = *(const short8*)&Wl[(n0 + lrow) * 136 + k0 + quad * 8];
        const short8 b1 = *(const short8*)&Wl[(n0 + 16 + lrow) * 136 + k0 + quad * 8];
#pragma unroll
        for (int mt = 0; mt < 4; ++mt) {
            const short8 a = *(const short8*)&Al[(mt * 16 + lrow) * 136 + k0 + quad * 8];
            acc[mt][0] = __builtin_amdgcn_mfma_f32_16x16x32_bf16(a, b0, acc[mt][0], 0, 0, 0);
            acc[mt][1] = __builtin_amdgcn_mfma_f32_16x16x32_bf16(a, b1, acc[mt][1], 0, 0, 0);
        }
    }
    __syncthreads();

#pragma unroll
    for (int mt = 0; mt < 4; ++mt)
#pragma unroll
        for (int t = 0; t < 2; ++t)
#pragma unroll
            for (int j = 0; j < 4; ++j)
                Cl[(mt * 16 + quad * 4 + j) * 132 + n0 + t * 16 + lrow] = acc[mt][t][j];
    __syncthreads();

#pragma unroll
    for (int i = 0; i < 4; ++i) {
        const int row = i * 16 + (tid >> 4);
        const int c0 = (tid & 15) * 8;
        const int gr = r0 + row;
        if (gr < M) {
            const float4 v0 = *(float4*)&Cl[row * 132 + c0];
            const float4 v1 = *(float4*)&Cl[row * 132 + c0 + 4];
            C[(size_t)gr * 16 + (c0 >> 3)] = pk8_fp8(v0, v1);
        }
    }
}

// ============ atomic-free CSR build: two-level bucket counting sort ============
// R1 lesson: global atomicAdd(&cw[s]) storm cost +30us in bucket_place
// (VALUBusy 0.6%, 16-way address contention, grid-capped occupancy).
// The src-side bucket pipeline (bktS -> LDS segment sums) is cheaper.

__global__ __launch_bounds__(256) void bucket_hist(
    const int* __restrict__ src, const int* __restrict__ dst,
    int* __restrict__ cntD, int* __restrict__ cntS, int E, int B, int chunk)
{
    __shared__ int hD[MAXB], hS[MAXB];
    const int tid = threadIdx.x;
    for (int i = tid; i < B; i += 256) { hD[i] = 0; hS[i] = 0; }
    __syncthreads();
    const int lo = blockIdx.x * chunk;
    const int hi = min(E, lo + chunk);
    for (int e = lo + tid; e < hi; e += 256) {
        atomicAdd(&hD[dst[e] >> NPB_SHIFT], 1);
        atomicAdd(&hS[src[e] >> NPB_SHIFT], 1);
    }
    __syncthreads();
    for (int i = tid; i < B; i += 256) {
        cntD[i * PB + blockIdx.x] = hD[i];
        cntS[i * PB + blockIdx.x] = hS[i];
    }
}

__global__ __launch_bounds__(256) void bucket_base(
    const int* __restrict__ cntD, const int* __restrict__ cntS,
    int* __restrict__ baseD, int* __restrict__ baseS, int B, int E)
{
    __shared__ int lD[256], lS[256];
    const int tid = threadIdx.x;
    int sD = 0, sS = 0;
    if (tid < B) {
        const int4* pD = (const int4*)(cntD + tid * PB);
        const int4* pS = (const int4*)(cntS + tid * PB);
        for (int j = 0; j < PB / 4; ++j) {
            const int4 a = pD[j], b = pS[j];
            sD += a.x + a.y + a.z + a.w;
            sS += b.x + b.y + b.z + b.w;
        }
    }
    lD[tid] = sD; lS[tid] = sS;
    __syncthreads();
    for (int st = 1; st < 256; st <<= 1) {
        const int vD = (tid >= st) ? lD[tid - st] : 0;
        const int vS = (tid >= st) ? lS[tid - st] : 0;
        __syncthreads();
        lD[tid] += vD; lS[tid] += vS;
        __syncthreads();
    }
    if (tid < B) { baseD[tid] = lD[tid] - sD; baseS[tid] = lS[tid] - sS; }
    if (tid == 0) { baseD[B] = E; baseS[B] = E; }
}

__global__ __launch_bounds__(256) void bucket_cursor(
    int* __restrict__ cntD, int* __restrict__ cntS,
    const int* __restrict__ baseD, const int* __restrict__ baseS, int B)
{
    int b = blockIdx.x;
    int* cnt; const int* base;
    if (b < B) { cnt = cntD; base = baseD; }
    else       { cnt = cntS; base = baseS; b -= B; }
    __shared__ int ls[256];
    const int tid = threadIdx.x;
    const int c0 = cnt[b * PB + 2 * tid];
    const int c1 = cnt[b * PB + 2 * tid + 1];
    const int s = c0 + c1;
    ls[tid] = s;
    __syncthreads();
    for (int st = 1; st < 256; st <<= 1) {
        const int v = (tid >= st) ? ls[tid - st] : 0;
        __syncthreads();
        ls[tid] += v;
        __syncthreads();
    }
    const int excl = ls[tid] - s + base[b];
    cnt[b * PB + 2 * tid] = excl;
    cnt[b * PB + 2 * tid + 1] = excl + c0;
}

__global__ __launch_bounds__(256) void bucket_place(
    const int* __restrict__ src, const int* __restrict__ dst,
    const float* __restrict__ ew,
    const int* __restrict__ curD, const int* __restrict__ curS,
    uint2* __restrict__ bktD, uint2* __restrict__ bktS, int E, int B, int chunk)
{
    __shared__ int cD[MAXB], cS[MAXB];
    const int tid = threadIdx.x;
    for (int i = tid; i < B; i += 256) {
        cD[i] = curD[i * PB + blockIdx.x];
        cS[i] = curS[i * PB + blockIdx.x];
    }
    __syncthreads();
    const int lo = blockIdx.x * chunk;
    const int hi = min(E, lo + chunk);
    for (int e = lo + tid; e < hi; e += 256) {
        const int s = src[e], d = dst[e];
        const unsigned wb = __float_as_uint(ew[e]);
        const int pd = atomicAdd(&cD[d >> NPB_SHIFT], 1);
        bktD[pd] = make_uint2(((unsigned)s << NPB_SHIFT) | (unsigned)(d & (NPB - 1)), wb);
        const int ps = atomicAdd(&cS[s >> NPB_SHIFT], 1);
        bktS[ps] = make_uint2((unsigned)(s & (NPB - 1)), wb);
    }
}

// merged: blocks [0,B) counting-sort bktD -> rp/packed; blocks [B,2B) cw sums
// packed.x stores src*16 (uint2 index pre-scale: kills a v_mul in the gather)
__global__ __launch_bounds__(256) void bucket_sortcw(
    const uint2* __restrict__ bktD, const int* __restrict__ baseD,
    int* __restrict__ rp, int2* __restrict__ packed,
    const uint2* __restrict__ bktS, const int* __restrict__ baseS,
    float* __restrict__ cw, int N, int B)
{
    const int tid = threadIdx.x;
    if (blockIdx.x >= B) {
        const int b = blockIdx.x - B;
        const int lo = baseS[b], hi = baseS[b + 1];
        __shared__ float sm[NPB];
        sm[2 * tid] = 0.f; sm[2 * tid + 1] = 0.f;
        __syncthreads();
        for (int i = lo + tid; i < hi; i += 256) {
            const uint2 r = bktS[i];
            atomicAdd(&sm[r.x], __uint_as_float(r.y));
        }
        __syncthreads();
        const int n0 = b * NPB + 2 * tid;
        if (n0 < N)     cw[n0]     = sm[2 * tid];
        if (n0 + 1 < N) cw[n0 + 1] = sm[2 * tid + 1];
        return;
    }
    const int b = blockIdx.x;
    const int lo = baseD[b], hi = baseD[b + 1];
    __shared__ int cnt[NPB], cur[NPB];
    __shared__ int ls[256];
    cnt[2 * tid] = 0; cnt[2 * tid + 1] = 0;
    __syncthreads();
    for (int i = lo + tid; i < hi; i += 256)
        atomicAdd(&cnt[bktD[i].x & (NPB - 1)], 1);
    __syncthreads();
    const int c0 = cnt[2 * tid], c1 = cnt[2 * tid + 1];
    const int s = c0 + c1;
    ls[tid] = s;
    __syncthreads();
    for (int st = 1; st < 256; st <<= 1) {
        const int v = (tid >= st) ? ls[tid - st] : 0;
        __syncthreads();
        ls[tid] += v;
        __syncthreads();
    }
    const int excl = ls[tid] - s;
    const int n0 = b * NPB + 2 * tid;
    if (n0 < N)     rp[n0]     = lo + excl + c0;
    if (n0 + 1 < N) rp[n0 + 1] = lo + excl + c0 + c1;
    cur[2 * tid]     = lo + excl;
    cur[2 * tid + 1] = lo + excl + c0;
    __syncthreads();
    for (int i = lo + tid; i < hi; i += 256) {
        const uint2 r = bktD[i];
        const int pos = atomicAdd(&cur[r.x & (NPB - 1)], 1);
        packed[pos] = make_int2((int)(r.x >> NPB_SHIFT) << 4, (int)r.y);
    }
}

// ------- fused aggregate + BN stats (v11: AGG_R 16->8 for occupancy) ---------
// R2 post-mortem: OccupancyPercent 30% (2.4 waves/SIMD avg) -- the kernel is
// concurrency-starved, not ILP-starved (pairing was neutral). Halve the strip:
// 3125 blocks = 12.2/CU -> full residency + refill + finer load balance.
// packed.x is pre-scaled src*16 (saves v_mul_lo per gather address).
#define AGG_R 8

#define GATHER4(CUR, J, CNT, V0, V1, V2, V3, W0, W1, W2, W3) do { \
    const int i0_ = (J) + sub, i1_ = i0_ + 4, i2_ = i0_ + 8, i3_ = i0_ + 12; \
    const int c0_ = (i0_ < (CNT)) ? i0_ : 0; \
    const int c1_ = (i1_ < (CNT)) ? i1_ : 0; \
    const int c2_ = (i2_ < (CNT)) ? i2_ : 0; \
    const int c3_ = (i3_ < (CNT)) ? i3_ : 0; \
    const int s0_ = __shfl((CUR).x, c0_, 64); \
    const int s1_ = __shfl((CUR).x, c1_, 64); \
    const int s2_ = __shfl((CUR).x, c2_, 64); \
    const int s3_ = __shfl((CUR).x, c3_, 64); \
    W0 = __uint_as_float((unsigned)__shfl((CUR).y, c0_, 64)); \
    W1 = __uint_as_float((unsigned)__shfl((CUR).y, c1_, 64)); \
    W2 = __uint_as_float((unsigned)__shfl((CUR).y, c2_, 64)); \
    W3 = __uint_as_float((unsigned)__shfl((CUR).y, c3_, 64)); \
    if (i0_ >= (CNT)) W0 = 0.f; \
    if (i1_ >= (CNT)) W1 = 0.f; \
    if (i2_ >= (CNT)) W2 = 0.f; \
    if (i3_ >= (CNT)) W3 = 0.f; \
    V0 = h2[(size_t)(unsigned)(s0_ + u)]; \
    V1 = h2[(size_t)(unsigned)(s1_ + u)]; \
    V2 = h2[(size_t)(unsigned)(s2_ + u)]; \
    V3 = h2[(size_t)(unsigned)(s3_ + u)]; \
} while (0)

#define ACC_EDGE(V, W, A) do { \
    floatx2 f_; \
    f_ = __builtin_amdgcn_cvt_pk_f32_fp8((int)(V).x, false); \
    A[0] = fmaf(W, f_.x, A[0]); A[1] = fmaf(W, f_.y, A[1]); \
    f_ = __builtin_amdgcn_cvt_pk_f32_fp8((int)(V).x, true);  \
    A[2] = fmaf(W, f_.x, A[2]); A[3] = fmaf(W, f_.y, A[3]); \
    f_ = __builtin_amdgcn_cvt_pk_f32_fp8((int)(V).y, false); \
    A[4] = fmaf(W, f_.x, A[4]); A[5] = fmaf(W, f_.y, A[5]); \
    f_ = __builtin_amdgcn_cvt_pk_f32_fp8((int)(V).y, true);  \
    A[6] = fmaf(W, f_.x, A[6]); A[7] = fmaf(W, f_.y, A[7]); \
} while (0)

__global__ __launch_bounds__(256) void aggregate4(
    const int2* __restrict__ packed, const int* __restrict__ rp,
    const uint2* __restrict__ h2, uint4* __restrict__ aggb4,
    float* __restrict__ sum, float* __restrict__ sq, int N)
{
    const int tid = threadIdx.x;
    const int lane = tid & 63, wave = tid >> 6;
    const int sub = lane >> 4;          // quarter 0..3
    const int u = lane & 15;            // cols 8u..8u+7
    const int n0 = (blockIdx.x * 4 + wave) * AGG_R;

    // coalesced row-pointer block: lane l holds rp[n0-1+l] (rp[n]=end of node n)
    int rpv = 0;
    {
        const int idx = n0 - 1 + lane;
        if (lane <= AGG_R && idx >= 0 && idx < N) rpv = rp[idx];
    }

    float csum[8], csq[8];
#pragma unroll
    for (int k = 0; k < 8; ++k) { csum[k] = 0.f; csq[k] = 0.f; }

    // prefetch first pair's first edge chunks
    int2 curA = make_int2(0, 0), curB = make_int2(0, 0);
    if (n0 < N) {
        const int sa = __shfl(rpv, 0, 64), ea = __shfl(rpv, 1, 64);
        if (lane < min(64, ea - sa)) curA = packed[sa + lane];
    }
    if (n0 + 1 < N) {
        const int sb = __shfl(rpv, 1, 64), eb = __shfl(rpv, 2, 64);
        if (lane < min(64, eb - sb)) curB = packed[sb + lane];
    }

    for (int r = 0; r < AGG_R; r += 2) {
        const int nA = n0 + r;
        if (nA >= N) break;
        const int nB = nA + 1;
        const bool hasB = (nB < N);
        const int sA = __shfl(rpv, r, 64);
        const int eA = __shfl(rpv, r + 1, 64);
        const int sB = eA;
        const int eB = hasB ? __shfl(rpv, r + 2, 64) : sB;

        // prefetch next pair's first chunks (overlaps this pair's gathers)
        int2 nxtA = make_int2(0, 0), nxtB = make_int2(0, 0);
        if (r + 2 < AGG_R && nA + 2 < N) {
            const int ns = __shfl(rpv, r + 2, 64), ne = __shfl(rpv, r + 3, 64);
            if (lane < min(64, ne - ns)) nxtA = packed[ns + lane];
        }
        if (r + 3 < AGG_R && nA + 3 < N) {
            const int ns = __shfl(rpv, r + 3, 64), ne = __shfl(rpv, r + 4, 64);
            if (lane < min(64, ne - ns)) nxtB = packed[ns + lane];
        }

        float aA[8], aB[8];
#pragma unroll
        for (int k = 0; k < 8; ++k) { aA[k] = 0.f; aB[k] = 0.f; }

        const int cA = min(64, eA - sA);
        const int cB = min(64, eB - sB);
        const int cmax = (cA > cB) ? cA : cB;

        // interleaved first-chunk processing: up to 8 gathers in flight
        for (int j = 0; j < cmax; j += 16) {
            const bool doA = j < cA, doB = j < cB;
            uint2 vA0, vA1, vA2, vA3, vB0, vB1, vB2, vB3;
            float wA0, wA1, wA2, wA3, wB0, wB1, wB2, wB3;
            if (doA & doB) {
                GATHER4(curA, j, cA, vA0, vA1, vA2, vA3, wA0, wA1, wA2, wA3);
                GATHER4(curB, j, cB, vB0, vB1, vB2, vB3, wB0, wB1, wB2, wB3);
                ACC_EDGE(vA0, wA0, aA); ACC_EDGE(vA1, wA1, aA);
                ACC_EDGE(vA2, wA2, aA); ACC_EDGE(vA3, wA3, aA);
                ACC_EDGE(vB0, wB0, aB); ACC_EDGE(vB1, wB1, aB);
                ACC_EDGE(vB2, wB2, aB); ACC_EDGE(vB3, wB3, aB);
            } else if (doA) {
                GATHER4(curA, j, cA, vA0, vA1, vA2, vA3, wA0, wA1, wA2, wA3);
                ACC_EDGE(vA0, wA0, aA); ACC_EDGE(vA1, wA1, aA);
                ACC_EDGE(vA2, wA2, aA); ACC_EDGE(vA3, wA3, aA);
            } else {
                GATHER4(curB, j, cB, vB0, vB1, vB2, vB3, wB0, wB1, wB2, wB3);
                ACC_EDGE(vB0, wB0, aB); ACC_EDGE(vB1, wB1, aB);
                ACC_EDGE(vB2, wB2, aB); ACC_EDGE(vB3, wB3, aB);
            }
        }

        // rare overflow chunks (degree > 64), serial fallback
        for (int base = sA + 64; base < eA; base += 64) {
            const int cnt = min(64, eA - base);
            int2 myE = make_int2(0, 0);
            if (lane < cnt) myE = packed[base + lane];
            for (int j = 0; j < cnt; j += 16) {
                uint2 v0, v1, v2, v3; float w0, w1, w2, w3;
                GATHER4(myE, j, cnt, v0, v1, v2, v3, w0, w1, w2, w3);
                ACC_EDGE(v0, w0, aA); ACC_EDGE(v1, w1, aA);
                ACC_EDGE(v2, w2, aA); ACC_EDGE(v3, w3, aA);
            }
        }
        for (int base = sB + 64; base < eB; base += 64) {
            const int cnt = min(64, eB - base);
            int2 myE = make_int2(0, 0);
            if (lane < cnt) myE = packed[base + lane];
            for (int j = 0; j < cnt; j += 16) {
                uint2 v0, v1, v2, v3; float w0, w1, w2, w3;
                GATHER4(myE, j, cnt, v0, v1, v2, v3, w0, w1, w2, w3);
                ACC_EDGE(v0, w0, aB); ACC_EDGE(v1, w1, aB);
                ACC_EDGE(v2, w2, aB); ACC_EDGE(v3, w3, aB);
            }
        }

        // joint cross-quarter reduce; all lanes end with full sums
#pragma unroll
        for (int k = 0; k < 8; ++k) {
            aA[k] += __shfl_xor(aA[k], 16, 64);
            aB[k] += __shfl_xor(aB[k], 16, 64);
            aA[k] += __shfl_xor(aA[k], 32, 64);
            aB[k] += __shfl_xor(aB[k], 32, 64);
        }
        if (sub == 0) {
            uint4 o;
            o.x = (unsigned)f2bf(aA[0]) | ((unsigned)f2bf(aA[1]) << 16);
            o.y = (unsigned)f2bf(aA[2]) | ((unsigned)f2bf(aA[3]) << 16);
            o.z = (unsigned)f2bf(aA[4]) | ((unsigned)f2bf(aA[5]) << 16);
            o.w = (unsigned)f2bf(aA[6]) | ((unsigned)f2bf(aA[7]) << 16);
            aggb4[(size_t)nA * 16 + u] = o;
#pragma unroll
            for (int k = 0; k < 8; ++k) {
                csum[k] += aA[k];
                csq[k] = fmaf(aA[k], aA[k], csq[k]);
            }
        } else if (sub == 1 && hasB) {
            uint4 o;
            o.x = (unsigned)f2bf(aB[0]) | ((unsigned)f2bf(aB[1]) << 16);
            o.y = (unsigned)f2bf(aB[2]) | ((unsigned)f2bf(aB[3]) << 16);
            o.z = (unsigned)f2bf(aB[4]) | ((unsigned)f2bf(aB[5]) << 16);
            o.w = (unsigned)f2bf(aB[6]) | ((unsigned)f2bf(aB[7]) << 16);
            aggb4[(size_t)nB * 16 + u] = o;
#pragma unroll
            for (int k = 0; k < 8; ++k) {
                csum[k] += aB[k];
                csq[k] = fmaf(aB[k], aB[k], csq[k]);
            }
        }
        curA = nxtA;
        curB = nxtB;
    }

    // 8 stat slots: [wave] from sub0 (A nodes), [4+wave] from sub1 (B nodes)
    __shared__ float lsum[1024], lsq[1024];
    if (sub == 0) {
#pragma unroll
        for (int k = 0; k < 8; ++k) {
            lsum[wave * 128 + u * 8 + k] = csum[k];
            lsq[wave * 128 + u * 8 + k] = csq[k];
        }
    } else if (sub == 1) {
#pragma unroll
        for (int k = 0; k < 8; ++k) {
            lsum[(4 + wave) * 128 + u * 8 + k] = csum[k];
            lsq[(4 + wave) * 128 + u * 8 + k] = csq[k];
        }
    }
    __syncthreads();
    if (tid < 128) {
        float s = 0.f, q = 0.f;
#pragma unroll
        for (int i = 0; i < 8; ++i) {
            s += lsum[i * 128 + tid];
            q += lsq[i * 128 + tid];
        }
        const int sl = (blockIdx.x & (NSLICE - 1)) * 128;
        atomicAdd(&sum[sl + tid], s);
        atomicAdd(&sq[sl + tid], q);
    }
}

// ---------------- collapsed layer 2 (persistent grid, sliced-stat prologue) ----
__global__ __launch_bounds__(256) void wcolsum_bf16(
    const unsigned* __restrict__ xb, const float* __restrict__ cw,
    const float* __restrict__ sum1, const float* __restrict__ sq1,
    const float* __restrict__ g, const float* __restrict__ be,
    float* __restrict__ sout, int N)
{
    __shared__ float Aaf[128], Baf[128];
    __shared__ float2 ls[256];
    const int tid = threadIdx.x;
    if (tid < 128) {
        float s = 0.f, q = 0.f;
#pragma unroll
        for (int k = 0; k < NSLICE; ++k) {
            s += sum1[k * 128 + tid];
            q += sq1[k * 128 + tid];
        }
        const float invN = 1.0f / (float)N;
        const float m = s * invN;
        const float var = q * invN - m * m;
        const float rs = rsqrtf(var + BN_EPS);
        Aaf[tid] = g[tid] * rs;
        Baf[tid] = be[tid] - g[tid] * m * rs;
    }
    __syncthreads();
    const int u = tid & 63, rr = tid >> 6;
    const float ax = Aaf[2 * u], ay = Aaf[2 * u + 1];
    const float bx = Baf[2 * u], by = Baf[2 * u + 1];
    float2 s = {0.f, 0.f};
    for (int row = blockIdx.x * 4 + rr; row < N; row += gridDim.x * 4) {
        const unsigned v = xb[(size_t)row * 64 + u];
        const float c = cw[row];
        const float x = fmaxf(fmaf(ax, blo(v), bx), 0.f);
        const float y = fmaxf(fmaf(ay, bhi(v), by), 0.f);
        s.x = fmaf(c, x, s.x);
        s.y = fmaf(c, y, s.y);
    }
    ls[tid] = s;
    __syncthreads();
    if (tid < 64) {
        float sx = ls[tid].x + ls[64 + tid].x + ls[128 + tid].x + ls[192 + tid].x;
        float sy = ls[tid].y + ls[64 + tid].y + ls[128 + tid].y + ls[192 + tid].y;
        atomicAdd(&sout[2 * tid + 0], sx);
        atomicAdd(&sout[2 * tid + 1], sy);
    }
}

__global__ void final_out(
    const float* __restrict__ s, const float* __restrict__ W2,
    const float* __restrict__ b2, float* __restrict__ out, int N, int Dout)
{
    const int j = threadIdx.x;
    if (j < Dout) {
        float acc = 0.f;
        for (int f = 0; f < 128; ++f) acc = fmaf(s[f], W2[f * Dout + j], acc);
        out[j] = acc + (float)N * b2[j];
    }
}

extern "C" void kernel_launch(void* const* d_in, const int* in_sizes, int n_in,
                              void* d_out, int out_size, void* d_ws, size_t ws_size,
                              hipStream_t stream)
{
    const float* nf  = (const float*)d_in[0];
    const int*   ei  = (const int*)d_in[1];
    const float* ew  = (const float*)d_in[2];
    const float* W0  = (const float*)d_in[3];
    // b0 = d_in[4], b1 = d_in[6]: cancel inside BatchNorm, unused
    const float* W1  = (const float*)d_in[5];
    const float* W2  = (const float*)d_in[7];
    const float* b2  = (const float*)d_in[8];
    const float* g0  = (const float*)d_in[9];
    const float* be0 = (const float*)d_in[10];
    const float* g1  = (const float*)d_in[11];
    const float* be1 = (const float*)d_in[12];

    const int N = in_sizes[0] / 128;
    const int E = in_sizes[2];
    const int* srcI = ei;       // edge_index[0,:]
    const int* dstI = ei + E;   // edge_index[1,:]

    const int B = (N + NPB - 1) / NPB;        // 196 for N=100k
    const int chunk = (E + PB - 1) / PB;

    const size_t HB = ((size_t)N * 128 * 2 + 255) & ~(size_t)255;  // bf16 buf
    const size_t NA = ((size_t)N * sizeof(int) + 255) & ~(size_t)255;
    const size_t CB = (((size_t)B * PB * 4) + 255) & ~(size_t)255;
    char* ws = (char*)d_ws;
    size_t off = 0;
    float* cw    = (float*)(ws + off); off += NA;
    int*   rp    = (int*)  (ws + off); off += NA;
    float* stats = (float*)(ws + off); off += 36864;   // 4 sliced arrays + svec
    int*   cntD  = (int*)  (ws + off); off += CB;
    int*   cntS  = (int*)  (ws + off); off += CB;
    int*   baseD = (int*)  (ws + off); off += 2048;
    int*   baseS = (int*)  (ws + off); off += 2048;
    uint2* hbuf  = (uint2*)(ws + off); off += HB;      // h (fp8, oversized ok)
    unsigned* aggb = (unsigned*)(ws + off); off += HB; // agg (bf16)
    int2*  packed = (int2*)(ws + off); off += (size_t)E * 8;
    uint2* bktD  = (uint2*)(ws + off); off += (size_t)E * 8;
    uint2* bktS  = (uint2*)(ws + off); off += (size_t)E * 8;
    unsigned short* wt0 = (unsigned short*)(ws + off); off += 32768;
    unsigned short* wt1 = (unsigned short*)(ws + off); off += 32768;
    (void)ws_size;  // rounds 1-11 proved ws_size >= 116.5 MB; this needs ~92 MB

    // sliced stats: each array NSLICE*128 floats
    float* sum0 = stats + 0 * NSLICE * 128;
    float* sq0  = stats + 1 * NSLICE * 128;
    float* sum1 = stats + 2 * NSLICE * 128;
    float* sq1  = stats + 3 * NSLICE * 128;
    float* svec = stats + 4 * NSLICE * 128;   // [128]

    const int gemmGrid = (N + 63) / 64;
    const int aggGrid  = (N + 4 * AGG_R - 1) / (4 * AGG_R);   // 3125

    // ---- atomic-free CSR build + cw (graph identical both layers) ----
    bucket_hist<<<PB, 256, 0, stream>>>(srcI, dstI, cntD, cntS, E, B, chunk);
    bucket_base<<<1, 256, 0, stream>>>(cntD, cntS, baseD, baseS, B, E);
    bucket_cursor<<<2 * B, 256, 0, stream>>>(cntD, cntS, baseD, baseS, B);
    bucket_place<<<PB, 256, 0, stream>>>(srcI, dstI, ew, cntD, cntS, bktD, bktS, E, B, chunk);
    bucket_sortcw<<<2 * B, 256, 0, stream>>>(bktD, baseD, rp, packed,
                                             bktS, baseS, cw, N, B);
    wconv<<<64, 256, 0, stream>>>(W0, W1, wt0, wt1, stats);   // + stats zeroing

    // ---- layer 0 ----
    gemm0<<<gemmGrid, 256, 0, stream>>>(nf, wt0, hbuf, N);
    aggregate4<<<aggGrid, 256, 0, stream>>>(
        packed, rp, (const uint2*)hbuf, (uint4*)aggb, sum0, sq0, N);

    // ---- layer 1 (BN0+ReLU folded into GEMM staging) ----
    gemm1<<<gemmGrid, 256, 0, stream>>>(aggb, wt1, hbuf, sum0, sq0, g0, be0, N, N);
    aggregate4<<<aggGrid, 256, 0, stream>>>(
        packed, rp, (const uint2*)hbuf, (uint4*)aggb, sum1, sq1, N);

    // ---- collapsed layer 2: out = (sum_n cw[n]*relu(BN1(x2))[n,:]) @ W2 + N*b2 ----
    wcolsum_bf16<<<256, 256, 0, stream>>>(aggb, cw, sum1, sq1, g1, be1, svec, N);
    final_out<<<1, 64, 0, stream>>>(svec, W2, b2, (float*)d_out, N, out_size);
}

// Round 4
// 392.907 us; speedup vs baseline: 1.1163x; 1.0085x over previous
//
#include <hip/hip_runtime.h>

#define BN_EPS 1e-5f

// Bucket-sort parameters: NPB nodes per bucket (pow2), PB placement blocks.
#define NPB 512
#define NPB_SHIFT 9
#define PB 512
#define MAXB 256
// BN-stat accumulator slices (atomic-depth reduction)
#define NSLICE 16

typedef __attribute__((ext_vector_type(8))) short short8;
typedef __attribute__((ext_vector_type(4))) float floatx4;
typedef __attribute__((ext_vector_type(2))) float floatx2;

__device__ __forceinline__ unsigned short f2bf(float f) {
    unsigned u = __float_as_uint(f);
    unsigned r = u + 0x7FFFu + ((u >> 16) & 1u);   // round-to-nearest-even
    return (unsigned short)(r >> 16);
}
__device__ __forceinline__ float blo(unsigned v) { return __uint_as_float(v << 16); }
__device__ __forceinline__ float bhi(unsigned v) { return __uint_as_float(v & 0xffff0000u); }

// pack 8 fp32 -> 8 fp8 e4m3 (2 dwords); byte k of output = value k
__device__ __forceinline__ uint2 pk8_fp8(const float4 v0, const float4 v1) {
    int lo = 0, hi = 0;
    lo = __builtin_amdgcn_cvt_pk_fp8_f32(v0.x, v0.y, lo, false);
    lo = __builtin_amdgcn_cvt_pk_fp8_f32(v0.z, v0.w, lo, true);
    hi = __builtin_amdgcn_cvt_pk_fp8_f32(v1.x, v1.y, hi, false);
    hi = __builtin_amdgcn_cvt_pk_fp8_f32(v1.z, v1.w, hi, true);
    return make_uint2((unsigned)lo, (unsigned)hi);
}

// ------- W pre-transpose (+ stats zeroing folded in, saves a dispatch) -------
__global__ __launch_bounds__(256) void wconv(
    const float* __restrict__ W0, const float* __restrict__ W1,
    unsigned short* __restrict__ wt0, unsigned short* __restrict__ wt1,
    float* __restrict__ stats)
{
    const int idx = blockIdx.x * 256 + threadIdx.x;   // < 16384
    const int n = idx >> 7, k = idx & 127;
    wt0[idx] = f2bf(W0[k * 128 + n]);
    wt1[idx] = f2bf(W1[k * 128 + n]);
    if (blockIdx.x < 9) {   // zero 9216 floats (4 sliced stat arrays + svec)
        const int o = (blockIdx.x * 256 + threadIdx.x) * 4;
        *(float4*)&stats[o] = make_float4(0.f, 0.f, 0.f, 0.f);
    }
}

// ------- layer-0 GEMM: C[M x 128] = A_fp32 @ W, C in fp8 e4m3 -------
__global__ __launch_bounds__(256) void gemm0(
    const float* __restrict__ A, const unsigned short* __restrict__ Wt,
    uint2* __restrict__ C, int M)
{
    __shared__ char lds[53248];
    unsigned short* Al = (unsigned short*)lds;            // [64][136] bf16
    unsigned short* Wl = (unsigned short*)(lds + 17408);  // [128][136] bf16
    float* Cl = (float*)lds;                              // [64][132] f32 (reuse)

    const int tid = threadIdx.x;
    const int r0 = blockIdx.x * 64;

#pragma unroll
    for (int i = 0; i < 16; ++i) {
        const int idx = i * 256 + tid;          // ushort4 units
        const int n = idx >> 5, q = idx & 31;
        const ushort4 v = ((const ushort4*)Wt)[idx];
        *(ushort4*)&Wl[n * 136 + q * 4] = v;
    }
#pragma unroll
    for (int i = 0; i < 8; ++i) {
        const int row = i * 8 + (tid >> 5), q = tid & 31;
        const int gr = r0 + row;
        float4 v = (gr < M) ? ((const float4*)A)[(size_t)gr * 32 + q]
                            : make_float4(0.f, 0.f, 0.f, 0.f);
        ushort4 o;
        o.x = f2bf(v.x); o.y = f2bf(v.y); o.z = f2bf(v.z); o.w = f2bf(v.w);
        *(ushort4*)&Al[row * 136 + q * 4] = o;
    }
    __syncthreads();

    const int wave = tid >> 6, lane = tid & 63;
    const int lrow = lane & 15, quad = lane >> 4;
    const int n0 = wave * 32;

    floatx4 acc[4][2];
#pragma unroll
    for (int mt = 0; mt < 4; ++mt)
#pragma unroll
        for (int t = 0; t < 2; ++t)
#pragma unroll
            for (int j = 0; j < 4; ++j) acc[mt][t][j] = 0.f;

#pragma unroll
    for (int c = 0; c < 4; ++c) {
        const int k0 = c * 32;
        const short8 b0 = *(const short8*)&Wl[(n0 + lrow) * 136 + k0 + quad * 8];
        const short8 b1 = *(const short8*)&Wl[(n0 + 16 + lrow) * 136 + k0 + quad * 8];
#pragma unroll
        for (int mt = 0; mt < 4; ++mt) {
            const short8 a = *(const short8*)&Al[(mt * 16 + lrow) * 136 + k0 + quad * 8];
            acc[mt][0] = __builtin_amdgcn_mfma_f32_16x16x32_bf16(a, b0, acc[mt][0], 0, 0, 0);
            acc[mt][1] = __builtin_amdgcn_mfma_f32_16x16x32_bf16(a, b1, acc[mt][1], 0, 0, 0);
        }
    }
    __syncthreads();

#pragma unroll
    for (int mt = 0; mt < 4; ++mt)
#pragma unroll
        for (int t = 0; t < 2; ++t)
#pragma unroll
            for (int j = 0; j < 4; ++j)
                Cl[(mt * 16 + quad * 4 + j) * 132 + n0 + t * 16 + lrow] = acc[mt][t][j];
    __syncthreads();

#pragma unroll
    for (int i = 0; i < 4; ++i) {
        const int row = i * 16 + (tid >> 4);
        const int c0 = (tid & 15) * 8;
        const int gr = r0 + row;
        if (gr < M) {
            const float4 v0 = *(float4*)&Cl[row * 132 + c0];
            const float4 v1 = *(float4*)&Cl[row * 132 + c0 + 4];
            C[(size_t)gr * 16 + (c0 >> 3)] = pk8_fp8(v0, v1);
        }
    }
}

// ------- layer-1 GEMM: C = relu(BN(A_bf16)) @ W, C in fp8 e4m3 -------
__global__ __launch_bounds__(256) void gemm1(
    const unsigned* __restrict__ Ab, const unsigned short* __restrict__ Wt,
    uint2* __restrict__ C,
    const float* __restrict__ sum, const float* __restrict__ sq,
    const float* __restrict__ g, const float* __restrict__ be,
    int M, int N)
{
    __shared__ char lds[53248];
    unsigned short* Al = (unsigned short*)lds;            // [64][136]
    unsigned short* Wl = (unsigned short*)(lds + 17408);  // [128][136]
    float* AscL = (float*)(lds + 52224);                  // [128]
    float* AshL = AscL + 128;
    float* Cl = (float*)lds;

    const int tid = threadIdx.x;
    const int r0 = blockIdx.x * 64;

    if (tid < 128) {
        float s = 0.f, q = 0.f;
#pragma unroll
        for (int k = 0; k < NSLICE; ++k) {
            s += sum[k * 128 + tid];
            q += sq[k * 128 + tid];
        }
        const float invN = 1.0f / (float)N;
        const float m = s * invN;
        const float var = q * invN - m * m;
        const float rs = rsqrtf(var + BN_EPS);
        AscL[tid] = g[tid] * rs;
        AshL[tid] = be[tid] - g[tid] * m * rs;
    }
    __syncthreads();

#pragma unroll
    for (int i = 0; i < 16; ++i) {
        const int idx = i * 256 + tid;
        const int n = idx >> 5, q = idx & 31;
        const ushort4 v = ((const ushort4*)Wt)[idx];
        *(ushort4*)&Wl[n * 136 + q * 4] = v;
    }
#pragma unroll
    for (int i = 0; i < 4; ++i) {
        const int idx = i * 256 + tid;
        const int row = idx >> 4, qc = idx & 15;
        const int gr = r0 + row;
        uint4 v = (gr < M) ? ((const uint4*)Ab)[(size_t)gr * 16 + qc]
                           : make_uint4(0, 0, 0, 0);
        const float4 a0 = *(const float4*)&AscL[qc * 8];
        const float4 a1 = *(const float4*)&AscL[qc * 8 + 4];
        const float4 b0 = *(const float4*)&AshL[qc * 8];
        const float4 b1 = *(const float4*)&AshL[qc * 8 + 4];
        float x0 = fmaxf(fmaf(a0.x, blo(v.x), b0.x), 0.f);
        float x1 = fmaxf(fmaf(a0.y, bhi(v.x), b0.y), 0.f);
        float x2 = fmaxf(fmaf(a0.z, blo(v.y), b0.z), 0.f);
        float x3 = fmaxf(fmaf(a0.w, bhi(v.y), b0.w), 0.f);
        float x4 = fmaxf(fmaf(a1.x, blo(v.z), b1.x), 0.f);
        float x5 = fmaxf(fmaf(a1.y, bhi(v.z), b1.y), 0.f);
        float x6 = fmaxf(fmaf(a1.z, blo(v.w), b1.z), 0.f);
        float x7 = fmaxf(fmaf(a1.w, bhi(v.w), b1.w), 0.f);
        uint4 o;
        o.x = (unsigned)f2bf(x0) | ((unsigned)f2bf(x1) << 16);
        o.y = (unsigned)f2bf(x2) | ((unsigned)f2bf(x3) << 16);
        o.z = (unsigned)f2bf(x4) | ((unsigned)f2bf(x5) << 16);
        o.w = (unsigned)f2bf(x6) | ((unsigned)f2bf(x7) << 16);
        *(uint4*)&Al[row * 136 + qc * 8] = o;
    }
    __syncthreads();

    const int wave = tid >> 6, lane = tid & 63;
    const int lrow = lane & 15, quad = lane >> 4;
    const int n0 = wave * 32;

    floatx4 acc[4][2];
#pragma unroll
    for (int mt = 0; mt < 4; ++mt)
#pragma unroll
        for (int t = 0; t < 2; ++t)
#pragma unroll
            for (int j = 0; j < 4; ++j) acc[mt][t][j] = 0.f;

#pragma unroll
    for (int c = 0; c < 4; ++c) {
        const int k0 = c * 32;
        const short8 b0 = *(const short8*)&Wl[(n0 + lrow) * 136 + k0 + quad * 8];
        const short8 b1 = *(const short8*)&Wl[(n0 + 16 + lrow) * 136 + k0 + quad * 8];
#pragma unroll
        for (int mt = 0; mt < 4; ++mt) {
            const short8 a = *(const short8*)&Al[(mt * 16 + lrow) * 136 + k0 + quad * 8];
            acc[mt][0] = __builtin_amdgcn_mfma_f32_16x16x32_bf16(a, b0, acc[mt][0], 0, 0, 0);
            acc[mt][1] = __builtin_amdgcn_mfma_f32_16x16x32_bf16(a, b1, acc[mt][1], 0, 0, 0);
        }
    }
    __syncthreads();

#pragma unroll
    for (int mt = 0; mt < 4; ++mt)
#pragma unroll
        for (int t = 0; t < 2; ++t)
#pragma unroll
            for (int j = 0; j < 4; ++j)
                Cl[(mt * 16 + quad * 4 + j) * 132 + n0 + t * 16 + lrow] = acc[mt][t][j];
    __syncthreads();

#pragma unroll
    for (int i = 0; i < 4; ++i) {
        const int row = i * 16 + (tid >> 4);
        const int c0 = (tid & 15) * 8;
        const int gr = r0 + row;
        if (gr < M) {
            const float4 v0 = *(float4*)&Cl[row * 132 + c0];
            const float4 v1 = *(float4*)&Cl[row * 132 + c0 + 4];
            C[(size_t)gr * 16 + (c0 >> 3)] = pk8_fp8(v0, v1);
        }
    }
}

// ============ atomic-free CSR build: two-level bucket counting sort ============
// R1 lesson: global atomicAdd(&cw[s]) storm cost +30us in bucket_place.
// The src-side bucket pipeline (bktS -> LDS segment sums) is cheaper.

__global__ __launch_bounds__(256) void bucket_hist(
    const int* __restrict__ src, const int* __restrict__ dst,
    int* __restrict__ cntD, int* __restrict__ cntS, int E, int B, int chunk)
{
    __shared__ int hD[MAXB], hS[MAXB];
    const int tid = threadIdx.x;
    for (int i = tid; i < B; i += 256) { hD[i] = 0; hS[i] = 0; }
    __syncthreads();
    const int lo = blockIdx.x * chunk;
    const int hi = min(E, lo + chunk);
    for (int e = lo + tid; e < hi; e += 256) {
        atomicAdd(&hD[dst[e] >> NPB_SHIFT], 1);
        atomicAdd(&hS[src[e] >> NPB_SHIFT], 1);
    }
    __syncthreads();
    for (int i = tid; i < B; i += 256) {
        cntD[i * PB + blockIdx.x] = hD[i];
        cntS[i * PB + blockIdx.x] = hS[i];
    }
}

__global__ __launch_bounds__(256) void bucket_base(
    const int* __restrict__ cntD, const int* __restrict__ cntS,
    int* __restrict__ baseD, int* __restrict__ baseS, int B, int E)
{
    __shared__ int lD[256], lS[256];
    const int tid = threadIdx.x;
    int sD = 0, sS = 0;
    if (tid < B) {
        const int4* pD = (const int4*)(cntD + tid * PB);
        const int4* pS = (const int4*)(cntS + tid * PB);
        for (int j = 0; j < PB / 4; ++j) {
            const int4 a = pD[j], b = pS[j];
            sD += a.x + a.y + a.z + a.w;
            sS += b.x + b.y + b.z + b.w;
        }
    }
    lD[tid] = sD; lS[tid] = sS;
    __syncthreads();
    for (int st = 1; st < 256; st <<= 1) {
        const int vD = (tid >= st) ? lD[tid - st] : 0;
        const int vS = (tid >= st) ? lS[tid - st] : 0;
        __syncthreads();
        lD[tid] += vD; lS[tid] += vS;
        __syncthreads();
    }
    if (tid < B) { baseD[tid] = lD[tid] - sD; baseS[tid] = lS[tid] - sS; }
    if (tid == 0) { baseD[B] = E; baseS[B] = E; }
}

__global__ __launch_bounds__(256) void bucket_cursor(
    int* __restrict__ cntD, int* __restrict__ cntS,
    const int* __restrict__ baseD, const int* __restrict__ baseS, int B)
{
    int b = blockIdx.x;
    int* cnt; const int* base;
    if (b < B) { cnt = cntD; base = baseD; }
    else       { cnt = cntS; base = baseS; b -= B; }
    __shared__ int ls[256];
    const int tid = threadIdx.x;
    const int c0 = cnt[b * PB + 2 * tid];
    const int c1 = cnt[b * PB + 2 * tid + 1];
    const int s = c0 + c1;
    ls[tid] = s;
    __syncthreads();
    for (int st = 1; st < 256; st <<= 1) {
        const int v = (tid >= st) ? ls[tid - st] : 0;
        __syncthreads();
        ls[tid] += v;
        __syncthreads();
    }
    const int excl = ls[tid] - s + base[b];
    cnt[b * PB + 2 * tid] = excl;
    cnt[b * PB + 2 * tid + 1] = excl + c0;
}

__global__ __launch_bounds__(256) void bucket_place(
    const int* __restrict__ src, const int* __restrict__ dst,
    const float* __restrict__ ew,
    const int* __restrict__ curD, const int* __restrict__ curS,
    uint2* __restrict__ bktD, uint2* __restrict__ bktS, int E, int B, int chunk)
{
    __shared__ int cD[MAXB], cS[MAXB];
    const int tid = threadIdx.x;
    for (int i = tid; i < B; i += 256) {
        cD[i] = curD[i * PB + blockIdx.x];
        cS[i] = curS[i * PB + blockIdx.x];
    }
    __syncthreads();
    const int lo = blockIdx.x * chunk;
    const int hi = min(E, lo + chunk);
    for (int e = lo + tid; e < hi; e += 256) {
        const int s = src[e], d = dst[e];
        const unsigned wb = __float_as_uint(ew[e]);
        const int pd = atomicAdd(&cD[d >> NPB_SHIFT], 1);
        bktD[pd] = make_uint2(((unsigned)s << NPB_SHIFT) | (unsigned)(d & (NPB - 1)), wb);
        const int ps = atomicAdd(&cS[s >> NPB_SHIFT], 1);
        bktS[ps] = make_uint2((unsigned)(s & (NPB - 1)), wb);
    }
}

// merged: blocks [0,B) counting-sort bktD -> rp/packed; blocks [B,2B) cw sums
// packed.x stores src*16 (uint2 index pre-scale: kills a v_mul in the gather)
__global__ __launch_bounds__(256) void bucket_sortcw(
    const uint2* __restrict__ bktD, const int* __restrict__ baseD,
    int* __restrict__ rp, int2* __restrict__ packed,
    const uint2* __restrict__ bktS, const int* __restrict__ baseS,
    float* __restrict__ cw, int N, int B)
{
    const int tid = threadIdx.x;
    if (blockIdx.x >= B) {
        const int b = blockIdx.x - B;
        const int lo = baseS[b], hi = baseS[b + 1];
        __shared__ float sm[NPB];
        sm[2 * tid] = 0.f; sm[2 * tid + 1] = 0.f;
        __syncthreads();
        for (int i = lo + tid; i < hi; i += 256) {
            const uint2 r = bktS[i];
            atomicAdd(&sm[r.x], __uint_as_float(r.y));
        }
        __syncthreads();
        const int n0 = b * NPB + 2 * tid;
        if (n0 < N)     cw[n0]     = sm[2 * tid];
        if (n0 + 1 < N) cw[n0 + 1] = sm[2 * tid + 1];
        return;
    }
    const int b = blockIdx.x;
    const int lo = baseD[b], hi = baseD[b + 1];
    __shared__ int cnt[NPB], cur[NPB];
    __shared__ int ls[256];
    cnt[2 * tid] = 0; cnt[2 * tid + 1] = 0;
    __syncthreads();
    for (int i = lo + tid; i < hi; i += 256)
        atomicAdd(&cnt[bktD[i].x & (NPB - 1)], 1);
    __syncthreads();
    const int c0 = cnt[2 * tid], c1 = cnt[2 * tid + 1];
    const int s = c0 + c1;
    ls[tid] = s;
    __syncthreads();
    for (int st = 1; st < 256; st <<= 1) {
        const int v = (tid >= st) ? ls[tid - st] : 0;
        __syncthreads();
        ls[tid] += v;
        __syncthreads();
    }
    const int excl = ls[tid] - s;
    const int n0 = b * NPB + 2 * tid;
    if (n0 < N)     rp[n0]     = lo + excl + c0;
    if (n0 + 1 < N) rp[n0 + 1] = lo + excl + c0 + c1;
    cur[2 * tid]     = lo + excl;
    cur[2 * tid + 1] = lo + excl + c0;
    __syncthreads();
    for (int i = lo + tid; i < hi; i += 256) {
        const uint2 r = bktD[i];
        const int pos = atomicAdd(&cur[r.x & (NPB - 1)], 1);
        packed[pos] = make_int2((int)(r.x >> NPB_SHIFT) << 4, (int)r.y);
    }
}

// ------- fused aggregate + BN stats (v12: LDS-staged edges + pk-f32 math) -----
// R3 post-mortem: VALUBusy 54% -> instruction stream is the floor (~31us at
// 100% issue). Diet: (1) per-wave LDS edge strip replaces ds_bpermute
// redistribution (8 broadcast ds_read_b64 per pair-iter vs 16 bpermute +
// 8 clamps); (2) floatx2 accumulators so w*f+a lowers to v_pk_fma_f32.
#define AGG_R 8

// lane-local edge fetch from the wave's LDS strip. Slots >= cnt hold {0,0}
// (masked prefetch lanes) or a stale valid record -- address always in-bounds,
// contribution killed via W=0.
#define LGATHER4(EBW, BASE, J, CNT, V0, V1, V2, V3, W0, W1, W2, W3) do { \
    const int i0_ = (J) + sub, i1_ = i0_ + 4, i2_ = i0_ + 8, i3_ = i0_ + 12; \
    const int2 e0_ = (EBW)[(BASE) + i0_]; \
    const int2 e1_ = (EBW)[(BASE) + i1_]; \
    const int2 e2_ = (EBW)[(BASE) + i2_]; \
    const int2 e3_ = (EBW)[(BASE) + i3_]; \
    W0 = (i0_ < (CNT)) ? __uint_as_float((unsigned)e0_.y) : 0.f; \
    W1 = (i1_ < (CNT)) ? __uint_as_float((unsigned)e1_.y) : 0.f; \
    W2 = (i2_ < (CNT)) ? __uint_as_float((unsigned)e2_.y) : 0.f; \
    W3 = (i3_ < (CNT)) ? __uint_as_float((unsigned)e3_.y) : 0.f; \
    V0 = h2[(size_t)(unsigned)(e0_.x + u)]; \
    V1 = h2[(size_t)(unsigned)(e1_.x + u)]; \
    V2 = h2[(size_t)(unsigned)(e2_.x + u)]; \
    V3 = h2[(size_t)(unsigned)(e3_.x + u)]; \
} while (0)

// floatx2 accumulate: a = f*w2 + a contracts to v_pk_fma_f32
#define ACC_EDGE(V, W, A) do { \
    floatx2 w2_; w2_.x = (W); w2_.y = (W); \
    floatx2 f_; \
    f_ = __builtin_amdgcn_cvt_pk_f32_fp8((int)(V).x, false); \
    A[0] = f_ * w2_ + A[0]; \
    f_ = __builtin_amdgcn_cvt_pk_f32_fp8((int)(V).x, true);  \
    A[1] = f_ * w2_ + A[1]; \
    f_ = __builtin_amdgcn_cvt_pk_f32_fp8((int)(V).y, false); \
    A[2] = f_ * w2_ + A[2]; \
    f_ = __builtin_amdgcn_cvt_pk_f32_fp8((int)(V).y, true);  \
    A[3] = f_ * w2_ + A[3]; \
} while (0)

__global__ __launch_bounds__(256) void aggregate4(
    const int2* __restrict__ packed, const int* __restrict__ rp,
    const uint2* __restrict__ h2, uint4* __restrict__ aggb4,
    float* __restrict__ sum, float* __restrict__ sq, int N)
{
    // per-wave private edge strip: [wave][slotA 0..63 | slotB 64..127]
    __shared__ int2 eb[4][128];
    __shared__ float lsum[1024], lsq[1024];

    const int tid = threadIdx.x;
    const int lane = tid & 63, wave = tid >> 6;
    const int sub = lane >> 4;          // quarter 0..3
    const int u = lane & 15;            // cols 8u..8u+7
    const int n0 = (blockIdx.x * 4 + wave) * AGG_R;
    int2* ebw = eb[wave];

    // coalesced row-pointer block: lane l holds rp[n0-1+l] (rp[n]=end of node n)
    int rpv = 0;
    {
        const int idx = n0 - 1 + lane;
        if (lane <= AGG_R && idx >= 0 && idx < N) rpv = rp[idx];
    }

    floatx2 csum[4], csq[4];
#pragma unroll
    for (int k = 0; k < 4; ++k) { csum[k] = 0.f; csq[k] = 0.f; }

    // prefetch first pair's first edge chunks (masked lanes stay {0,0})
    int2 curA = make_int2(0, 0), curB = make_int2(0, 0);
    if (n0 < N) {
        const int sa = __shfl(rpv, 0, 64), ea = __shfl(rpv, 1, 64);
        if (lane < min(64, ea - sa)) curA = packed[sa + lane];
    }
    if (n0 + 1 < N) {
        const int sb = __shfl(rpv, 1, 64), eb2 = __shfl(rpv, 2, 64);
        if (lane < min(64, eb2 - sb)) curB = packed[sb + lane];
    }

    for (int r = 0; r < AGG_R; r += 2) {
        const int nA = n0 + r;
        if (nA >= N) break;
        const int nB = nA + 1;
        const bool hasB = (nB < N);
        const int sA = __shfl(rpv, r, 64);
        const int eA = __shfl(rpv, r + 1, 64);
        const int sB = eA;
        const int eB = hasB ? __shfl(rpv, r + 2, 64) : sB;

        // stage current chunks into the wave's LDS strip (full 64 slots each;
        // DS ops are in-order per wave, so no barrier and no double-buffer)
        ebw[lane] = curA;
        ebw[64 + lane] = curB;

        // prefetch next pair's first chunks (overlaps this pair's gathers)
        int2 nxtA = make_int2(0, 0), nxtB = make_int2(0, 0);
        if (r + 2 < AGG_R && nA + 2 < N) {
            const int ns = __shfl(rpv, r + 2, 64), ne = __shfl(rpv, r + 3, 64);
            if (lane < min(64, ne - ns)) nxtA = packed[ns + lane];
        }
        if (r + 3 < AGG_R && nA + 3 < N) {
            const int ns = __shfl(rpv, r + 3, 64), ne = __shfl(rpv, r + 4, 64);
            if (lane < min(64, ne - ns)) nxtB = packed[ns + lane];
        }

        floatx2 aA[4], aB[4];
#pragma unroll
        for (int k = 0; k < 4; ++k) { aA[k] = 0.f; aB[k] = 0.f; }

        const int cA = min(64, eA - sA);
        const int cB = min(64, eB - sB);
        const int cmax = (cA > cB) ? cA : cB;

        // interleaved first-chunk processing: up to 8 h2 gathers in flight
        for (int j = 0; j < cmax; j += 16) {
            const bool doA = j < cA, doB = j < cB;
            uint2 vA0, vA1, vA2, vA3, vB0, vB1, vB2, vB3;
            float wA0, wA1, wA2, wA3, wB0, wB1, wB2, wB3;
            if (doA & doB) {
                LGATHER4(ebw, 0, j, cA, vA0, vA1, vA2, vA3, wA0, wA1, wA2, wA3);
                LGATHER4(ebw, 64, j, cB, vB0, vB1, vB2, vB3, wB0, wB1, wB2, wB3);
                ACC_EDGE(vA0, wA0, aA); ACC_EDGE(vA1, wA1, aA);
                ACC_EDGE(vA2, wA2, aA); ACC_EDGE(vA3, wA3, aA);
                ACC_EDGE(vB0, wB0, aB); ACC_EDGE(vB1, wB1, aB);
                ACC_EDGE(vB2, wB2, aB); ACC_EDGE(vB3, wB3, aB);
            } else if (doA) {
                LGATHER4(ebw, 0, j, cA, vA0, vA1, vA2, vA3, wA0, wA1, wA2, wA3);
                ACC_EDGE(vA0, wA0, aA); ACC_EDGE(vA1, wA1, aA);
                ACC_EDGE(vA2, wA2, aA); ACC_EDGE(vA3, wA3, aA);
            } else {
                LGATHER4(ebw, 64, j, cB, vB0, vB1, vB2, vB3, wB0, wB1, wB2, wB3);
                ACC_EDGE(vB0, wB0, aB); ACC_EDGE(vB1, wB1, aB);
                ACC_EDGE(vB2, wB2, aB); ACC_EDGE(vB3, wB3, aB);
            }
        }

        // rare overflow chunks (degree > 64), serial fallback via A-slots
        for (int base = sA + 64; base < eA; base += 64) {
            const int cnt = min(64, eA - base);
            int2 myE = make_int2(0, 0);
            if (lane < cnt) myE = packed[base + lane];
            ebw[lane] = myE;
            for (int j = 0; j < cnt; j += 16) {
                uint2 v0, v1, v2, v3; float w0, w1, w2, w3;
                LGATHER4(ebw, 0, j, cnt, v0, v1, v2, v3, w0, w1, w2, w3);
                ACC_EDGE(v0, w0, aA); ACC_EDGE(v1, w1, aA);
                ACC_EDGE(v2, w2, aA); ACC_EDGE(v3, w3, aA);
            }
        }
        for (int base = sB + 64; base < eB; base += 64) {
            const int cnt = min(64, eB - base);
            int2 myE = make_int2(0, 0);
            if (lane < cnt) myE = packed[base + lane];
            ebw[lane] = myE;
            for (int j = 0; j < cnt; j += 16) {
                uint2 v0, v1, v2, v3; float w0, w1, w2, w3;
                LGATHER4(ebw, 0, j, cnt, v0, v1, v2, v3, w0, w1, w2, w3);
                ACC_EDGE(v0, w0, aB); ACC_EDGE(v1, w1, aB);
                ACC_EDGE(v2, w2, aB); ACC_EDGE(v3, w3, aB);
            }
        }

        // joint cross-quarter reduce; all lanes end with full sums
#pragma unroll
        for (int k = 0; k < 4; ++k) {
            aA[k].x += __shfl_xor(aA[k].x, 16, 64);
            aA[k].y += __shfl_xor(aA[k].y, 16, 64);
            aB[k].x += __shfl_xor(aB[k].x, 16, 64);
            aB[k].y += __shfl_xor(aB[k].y, 16, 64);
            aA[k].x += __shfl_xor(aA[k].x, 32, 64);
            aA[k].y += __shfl_xor(aA[k].y, 32, 64);
            aB[k].x += __shfl_xor(aB[k].x, 32, 64);
            aB[k].y += __shfl_xor(aB[k].y, 32, 64);
        }
        if (sub == 0) {
            uint4 o;
            o.x = (unsigned)f2bf(aA[0].x) | ((unsigned)f2bf(aA[0].y) << 16);
            o.y = (unsigned)f2bf(aA[1].x) | ((unsigned)f2bf(aA[1].y) << 16);
            o.z = (unsigned)f2bf(aA[2].x) | ((unsigned)f2bf(aA[2].y) << 16);
            o.w = (unsigned)f2bf(aA[3].x) | ((unsigned)f2bf(aA[3].y) << 16);
            aggb4[(size_t)nA * 16 + u] = o;
#pragma unroll
            for (int k = 0; k < 4; ++k) {
                csum[k] += aA[k];
                csq[k] = aA[k] * aA[k] + csq[k];
            }
        } else if (sub == 1 && hasB) {
            uint4 o;
            o.x = (unsigned)f2bf(aB[0].x) | ((unsigned)f2bf(aB[0].y) << 16);
            o.y = (unsigned)f2bf(aB[1].x) | ((unsigned)f2bf(aB[1].y) << 16);
            o.z = (unsigned)f2bf(aB[2].x) | ((unsigned)f2bf(aB[2].y) << 16);
            o.w = (unsigned)f2bf(aB[3].x) | ((unsigned)f2bf(aB[3].y) << 16);
            aggb4[(size_t)nB * 16 + u] = o;
#pragma unroll
            for (int k = 0; k < 4; ++k) {
                csum[k] += aB[k];
                csq[k] = aB[k] * aB[k] + csq[k];
            }
        }
        curA = nxtA;
        curB = nxtB;
    }

    // 8 stat slots: [wave] from sub0 (A nodes), [4+wave] from sub1 (B nodes)
    if (sub == 0) {
#pragma unroll
        for (int k = 0; k < 4; ++k) {
            lsum[wave * 128 + u * 8 + 2 * k]     = csum[k].x;
            lsum[wave * 128 + u * 8 + 2 * k + 1] = csum[k].y;
            lsq[wave * 128 + u * 8 + 2 * k]      = csq[k].x;
            lsq[wave * 128 + u * 8 + 2 * k + 1]  = csq[k].y;
        }
    } else if (sub == 1) {
#pragma unroll
        for (int k = 0; k < 4; ++k) {
            lsum[(4 + wave) * 128 + u * 8 + 2 * k]     = csum[k].x;
            lsum[(4 + wave) * 128 + u * 8 + 2 * k + 1] = csum[k].y;
            lsq[(4 + wave) * 128 + u * 8 + 2 * k]      = csq[k].x;
            lsq[(4 + wave) * 128 + u * 8 + 2 * k + 1]  = csq[k].y;
        }
    }
    __syncthreads();
    if (tid < 128) {
        float s = 0.f, q = 0.f;
#pragma unroll
        for (int i = 0; i < 8; ++i) {
            s += lsum[i * 128 + tid];
            q += lsq[i * 128 + tid];
        }
        const int sl = (blockIdx.x & (NSLICE - 1)) * 128;
        atomicAdd(&sum[sl + tid], s);
        atomicAdd(&sq[sl + tid], q);
    }
}

// ---------------- collapsed layer 2 (persistent grid, sliced-stat prologue) ----
__global__ __launch_bounds__(256) void wcolsum_bf16(
    const unsigned* __restrict__ xb, const float* __restrict__ cw,
    const float* __restrict__ sum1, const float* __restrict__ sq1,
    const float* __restrict__ g, const float* __restrict__ be,
    float* __restrict__ sout, int N)
{
    __shared__ float Aaf[128], Baf[128];
    __shared__ float2 ls[256];
    const int tid = threadIdx.x;
    if (tid < 128) {
        float s = 0.f, q = 0.f;
#pragma unroll
        for (int k = 0; k < NSLICE; ++k) {
            s += sum1[k * 128 + tid];
            q += sq1[k * 128 + tid];
        }
        const float invN = 1.0f / (float)N;
        const float m = s * invN;
        const float var = q * invN - m * m;
        const float rs = rsqrtf(var + BN_EPS);
        Aaf[tid] = g[tid] * rs;
        Baf[tid] = be[tid] - g[tid] * m * rs;
    }
    __syncthreads();
    const int u = tid & 63, rr = tid >> 6;
    const float ax = Aaf[2 * u], ay = Aaf[2 * u + 1];
    const float bx = Baf[2 * u], by = Baf[2 * u + 1];
    float2 s = {0.f, 0.f};
    for (int row = blockIdx.x * 4 + rr; row < N; row += gridDim.x * 4) {
        const unsigned v = xb[(size_t)row * 64 + u];
        const float c = cw[row];
        const float x = fmaxf(fmaf(ax, blo(v), bx), 0.f);
        const float y = fmaxf(fmaf(ay, bhi(v), by), 0.f);
        s.x = fmaf(c, x, s.x);
        s.y = fmaf(c, y, s.y);
    }
    ls[tid] = s;
    __syncthreads();
    if (tid < 64) {
        float sx = ls[tid].x + ls[64 + tid].x + ls[128 + tid].x + ls[192 + tid].x;
        float sy = ls[tid].y + ls[64 + tid].y + ls[128 + tid].y + ls[192 + tid].y;
        atomicAdd(&sout[2 * tid + 0], sx);
        atomicAdd(&sout[2 * tid + 1], sy);
    }
}

__global__ void final_out(
    const float* __restrict__ s, const float* __restrict__ W2,
    const float* __restrict__ b2, float* __restrict__ out, int N, int Dout)
{
    const int j = threadIdx.x;
    if (j < Dout) {
        float acc = 0.f;
        for (int f = 0; f < 128; ++f) acc = fmaf(s[f], W2[f * Dout + j], acc);
        out[j] = acc + (float)N * b2[j];
    }
}

extern "C" void kernel_launch(void* const* d_in, const int* in_sizes, int n_in,
                              void* d_out, int out_size, void* d_ws, size_t ws_size,
                              hipStream_t stream)
{
    const float* nf  = (const float*)d_in[0];
    const int*   ei  = (const int*)d_in[1];
    const float* ew  = (const float*)d_in[2];
    const float* W0  = (const float*)d_in[3];
    // b0 = d_in[4], b1 = d_in[6]: cancel inside BatchNorm, unused
    const float* W1  = (const float*)d_in[5];
    const float* W2  = (const float*)d_in[7];
    const float* b2  = (const float*)d_in[8];
    const float* g0  = (const float*)d_in[9];
    const float* be0 = (const float*)d_in[10];
    const float* g1  = (const float*)d_in[11];
    const float* be1 = (const float*)d_in[12];

    const int N = in_sizes[0] / 128;
    const int E = in_sizes[2];
    const int* srcI = ei;       // edge_index[0,:]
    const int* dstI = ei + E;   // edge_index[1,:]

    const int B = (N + NPB - 1) / NPB;        // 196 for N=100k
    const int chunk = (E + PB - 1) / PB;

    const size_t HB = ((size_t)N * 128 * 2 + 255) & ~(size_t)255;  // bf16 buf
    const size_t NA = ((size_t)N * sizeof(int) + 255) & ~(size_t)255;
    const size_t CB = (((size_t)B * PB * 4) + 255) & ~(size_t)255;
    char* ws = (char*)d_ws;
    size_t off = 0;
    float* cw    = (float*)(ws + off); off += NA;
    int*   rp    = (int*)  (ws + off); off += NA;
    float* stats = (float*)(ws + off); off += 36864;   // 4 sliced arrays + svec
    int*   cntD  = (int*)  (ws + off); off += CB;
    int*   cntS  = (int*)  (ws + off); off += CB;
    int*   baseD = (int*)  (ws + off); off += 2048;
    int*   baseS = (int*)  (ws + off); off += 2048;
    uint2* hbuf  = (uint2*)(ws + off); off += HB;      // h (fp8, oversized ok)
    unsigned* aggb = (unsigned*)(ws + off); off += HB; // agg (bf16)
    int2*  packed = (int2*)(ws + off); off += (size_t)E * 8;
    uint2* bktD  = (uint2*)(ws + off); off += (size_t)E * 8;
    uint2* bktS  = (uint2*)(ws + off); off += (size_t)E * 8;
    unsigned short* wt0 = (unsigned short*)(ws + off); off += 32768;
    unsigned short* wt1 = (unsigned short*)(ws + off); off += 32768;
    (void)ws_size;  // rounds 1-11 proved ws_size >= 116.5 MB; this needs ~92 MB

    // sliced stats: each array NSLICE*128 floats
    float* sum0 = stats + 0 * NSLICE * 128;
    float* sq0  = stats + 1 * NSLICE * 128;
    float* sum1 = stats + 2 * NSLICE * 128;
    float* sq1  = stats + 3 * NSLICE * 128;
    float* svec = stats + 4 * NSLICE * 128;   // [128]

    const int gemmGrid = (N + 63) / 64;
    const int aggGrid  = (N + 4 * AGG_R - 1) / (4 * AGG_R);   // 3125

    // ---- atomic-free CSR build + cw (graph identical both layers) ----
    bucket_hist<<<PB, 256, 0, stream>>>(srcI, dstI, cntD, cntS, E, B, chunk);
    bucket_base<<<1, 256, 0, stream>>>(cntD, cntS, baseD, baseS, B, E);
    bucket_cursor<<<2 * B, 256, 0, stream>>>(cntD, cntS, baseD, baseS, B);
    bucket_place<<<PB, 256, 0, stream>>>(srcI, dstI, ew, cntD, cntS, bktD, bktS, E, B, chunk);
    bucket_sortcw<<<2 * B, 256, 0, stream>>>(bktD, baseD, rp, packed,
                                             bktS, baseS, cw, N, B);
    wconv<<<64, 256, 0, stream>>>(W0, W1, wt0, wt1, stats);   // + stats zeroing

    // ---- layer 0 ----
    gemm0<<<gemmGrid, 256, 0, stream>>>(nf, wt0, hbuf, N);
    aggregate4<<<aggGrid, 256, 0, stream>>>(
        packed, rp, (const uint2*)hbuf, (uint4*)aggb, sum0, sq0, N);

    // ---- layer 1 (BN0+ReLU folded into GEMM staging) ----
    gemm1<<<gemmGrid, 256, 0, stream>>>(aggb, wt1, hbuf, sum0, sq0, g0, be0, N, N);
    aggregate4<<<aggGrid, 256, 0, stream>>>(
        packed, rp, (const uint2*)hbuf, (uint4*)aggb, sum1, sq1, N);

    // ---- collapsed layer 2: out = (sum_n cw[n]*relu(BN1(x2))[n,:]) @ W2 + N*b2 ----
    wcolsum_bf16<<<256, 256, 0, stream>>>(aggb, cw, sum1, sq1, g1, be1, svec, N);
    final_out<<<1, 64, 0, stream>>>(svec, W2, b2, (float*)d_out, N, out_size);
}

// Round 5
// 357.696 us; speedup vs baseline: 1.2261x; 1.0984x over previous
//
#include <hip/hip_runtime.h>

#define BN_EPS 1e-5f

// Bucket-sort parameters: NPB nodes per bucket (pow2), PB placement blocks.
#define NPB 512
#define NPB_SHIFT 9
#define PB 512
#define MAXB 256
// BN-stat accumulator slices (atomic-depth reduction)
#define NSLICE 16

typedef __attribute__((ext_vector_type(8))) short short8;
typedef __attribute__((ext_vector_type(4))) float floatx4;
typedef __attribute__((ext_vector_type(2))) float floatx2;

__device__ __forceinline__ unsigned short f2bf(float f) {
    unsigned u = __float_as_uint(f);
    unsigned r = u + 0x7FFFu + ((u >> 16) & 1u);   // round-to-nearest-even
    return (unsigned short)(r >> 16);
}
__device__ __forceinline__ float blo(unsigned v) { return __uint_as_float(v << 16); }
__device__ __forceinline__ float bhi(unsigned v) { return __uint_as_float(v & 0xffff0000u); }

// pack 8 fp32 -> 8 fp8 e4m3 (2 dwords); byte k of output = value k
__device__ __forceinline__ uint2 pk8_fp8(const float4 v0, const float4 v1) {
    int lo = 0, hi = 0;
    lo = __builtin_amdgcn_cvt_pk_fp8_f32(v0.x, v0.y, lo, false);
    lo = __builtin_amdgcn_cvt_pk_fp8_f32(v0.z, v0.w, lo, true);
    hi = __builtin_amdgcn_cvt_pk_fp8_f32(v1.x, v1.y, hi, false);
    hi = __builtin_amdgcn_cvt_pk_fp8_f32(v1.z, v1.w, hi, true);
    return make_uint2((unsigned)lo, (unsigned)hi);
}

// ------- W pre-transpose (+ stats zeroing folded in, saves a dispatch) -------
__global__ __launch_bounds__(256) void wconv(
    const float* __restrict__ W0, const float* __restrict__ W1,
    unsigned short* __restrict__ wt0, unsigned short* __restrict__ wt1,
    float* __restrict__ stats)
{
    const int idx = blockIdx.x * 256 + threadIdx.x;   // < 16384
    const int n = idx >> 7, k = idx & 127;
    wt0[idx] = f2bf(W0[k * 128 + n]);
    wt1[idx] = f2bf(W1[k * 128 + n]);
    if (blockIdx.x < 9) {   // zero 9216 floats (4 sliced stat arrays + svec)
        const int o = (blockIdx.x * 256 + threadIdx.x) * 4;
        *(float4*)&stats[o] = make_float4(0.f, 0.f, 0.f, 0.f);
    }
}

// ------- layer-0 GEMM: C[M x 128] = A_fp32 @ W, C in fp8 e4m3 -------
__global__ __launch_bounds__(256) void gemm0(
    const float* __restrict__ A, const unsigned short* __restrict__ Wt,
    uint2* __restrict__ C, int M)
{
    __shared__ char lds[53248];
    unsigned short* Al = (unsigned short*)lds;            // [64][136] bf16
    unsigned short* Wl = (unsigned short*)(lds + 17408);  // [128][136] bf16
    float* Cl = (float*)lds;                              // [64][132] f32 (reuse)

    const int tid = threadIdx.x;
    const int r0 = blockIdx.x * 64;

#pragma unroll
    for (int i = 0; i < 16; ++i) {
        const int idx = i * 256 + tid;          // ushort4 units
        const int n = idx >> 5, q = idx & 31;
        const ushort4 v = ((const ushort4*)Wt)[idx];
        *(ushort4*)&Wl[n * 136 + q * 4] = v;
    }
#pragma unroll
    for (int i = 0; i < 8; ++i) {
        const int row = i * 8 + (tid >> 5), q = tid & 31;
        const int gr = r0 + row;
        float4 v = (gr < M) ? ((const float4*)A)[(size_t)gr * 32 + q]
                            : make_float4(0.f, 0.f, 0.f, 0.f);
        ushort4 o;
        o.x = f2bf(v.x); o.y = f2bf(v.y); o.z = f2bf(v.z); o.w = f2bf(v.w);
        *(ushort4*)&Al[row * 136 + q * 4] = o;
    }
    __syncthreads();

    const int wave = tid >> 6, lane = tid & 63;
    const int lrow = lane & 15, quad = lane >> 4;
    const int n0 = wave * 32;

    floatx4 acc[4][2];
#pragma unroll
    for (int mt = 0; mt < 4; ++mt)
#pragma unroll
        for (int t = 0; t < 2; ++t)
#pragma unroll
            for (int j = 0; j < 4; ++j) acc[mt][t][j] = 0.f;

#pragma unroll
    for (int c = 0; c < 4; ++c) {
        const int k0 = c * 32;
        const short8 b0 = *(const short8*)&Wl[(n0 + lrow) * 136 + k0 + quad * 8];
        const short8 b1 = *(const short8*)&Wl[(n0 + 16 + lrow) * 136 + k0 + quad * 8];
#pragma unroll
        for (int mt = 0; mt < 4; ++mt) {
            const short8 a = *(const short8*)&Al[(mt * 16 + lrow) * 136 + k0 + quad * 8];
            acc[mt][0] = __builtin_amdgcn_mfma_f32_16x16x32_bf16(a, b0, acc[mt][0], 0, 0, 0);
            acc[mt][1] = __builtin_amdgcn_mfma_f32_16x16x32_bf16(a, b1, acc[mt][1], 0, 0, 0);
        }
    }
    __syncthreads();

#pragma unroll
    for (int mt = 0; mt < 4; ++mt)
#pragma unroll
        for (int t = 0; t < 2; ++t)
#pragma unroll
            for (int j = 0; j < 4; ++j)
                Cl[(mt * 16 + quad * 4 + j) * 132 + n0 + t * 16 + lrow] = acc[mt][t][j];
    __syncthreads();

#pragma unroll
    for (int i = 0; i < 4; ++i) {
        const int row = i * 16 + (tid >> 4);
        const int c0 = (tid & 15) * 8;
        const int gr = r0 + row;
        if (gr < M) {
            const float4 v0 = *(float4*)&Cl[row * 132 + c0];
            const float4 v1 = *(float4*)&Cl[row * 132 + c0 + 4];
            C[(size_t)gr * 16 + (c0 >> 3)] = pk8_fp8(v0, v1);
        }
    }
}

// ------- layer-1 GEMM: C = relu(BN(A_bf16)) @ W, C in fp8 e4m3 -------
__global__ __launch_bounds__(256) void gemm1(
    const unsigned* __restrict__ Ab, const unsigned short* __restrict__ Wt,
    uint2* __restrict__ C,
    const float* __restrict__ sum, const float* __restrict__ sq,
    const float* __restrict__ g, const float* __restrict__ be,
    int M, int N)
{
    __shared__ char lds[53248];
    unsigned short* Al = (unsigned short*)lds;            // [64][136]
    unsigned short* Wl = (unsigned short*)(lds + 17408);  // [128][136]
    float* AscL = (float*)(lds + 52224);                  // [128]
    float* AshL = AscL + 128;
    float* Cl = (float*)lds;

    const int tid = threadIdx.x;
    const int r0 = blockIdx.x * 64;

    if (tid < 128) {
        float s = 0.f, q = 0.f;
#pragma unroll
        for (int k = 0; k < NSLICE; ++k) {
            s += sum[k * 128 + tid];
            q += sq[k * 128 + tid];
        }
        const float invN = 1.0f / (float)N;
        const float m = s * invN;
        const float var = q * invN - m * m;
        const float rs = rsqrtf(var + BN_EPS);
        AscL[tid] = g[tid] * rs;
        AshL[tid] = be[tid] - g[tid] * m * rs;
    }
    __syncthreads();

#pragma unroll
    for (int i = 0; i < 16; ++i) {
        const int idx = i * 256 + tid;
        const int n = idx >> 5, q = idx & 31;
        const ushort4 v = ((const ushort4*)Wt)[idx];
        *(ushort4*)&Wl[n * 136 + q * 4] = v;
    }
#pragma unroll
    for (int i = 0; i < 4; ++i) {
        const int idx = i * 256 + tid;
        const int row = idx >> 4, qc = idx & 15;
        const int gr = r0 + row;
        uint4 v = (gr < M) ? ((const uint4*)Ab)[(size_t)gr * 16 + qc]
                           : make_uint4(0, 0, 0, 0);
        const float4 a0 = *(const float4*)&AscL[qc * 8];
        const float4 a1 = *(const float4*)&AscL[qc * 8 + 4];
        const float4 b0 = *(const float4*)&AshL[qc * 8];
        const float4 b1 = *(const float4*)&AshL[qc * 8 + 4];
        float x0 = fmaxf(fmaf(a0.x, blo(v.x), b0.x), 0.f);
        float x1 = fmaxf(fmaf(a0.y, bhi(v.x), b0.y), 0.f);
        float x2 = fmaxf(fmaf(a0.z, blo(v.y), b0.z), 0.f);
        float x3 = fmaxf(fmaf(a0.w, bhi(v.y), b0.w), 0.f);
        float x4 = fmaxf(fmaf(a1.x, blo(v.z), b1.x), 0.f);
        float x5 = fmaxf(fmaf(a1.y, bhi(v.z), b1.y), 0.f);
        float x6 = fmaxf(fmaf(a1.z, blo(v.w), b1.z), 0.f);
        float x7 = fmaxf(fmaf(a1.w, bhi(v.w), b1.w), 0.f);
        uint4 o;
        o.x = (unsigned)f2bf(x0) | ((unsigned)f2bf(x1) << 16);
        o.y = (unsigned)f2bf(x2) | ((unsigned)f2bf(x3) << 16);
        o.z = (unsigned)f2bf(x4) | ((unsigned)f2bf(x5) << 16);
        o.w = (unsigned)f2bf(x6) | ((unsigned)f2bf(x7) << 16);
        *(uint4*)&Al[row * 136 + qc * 8] = o;
    }
    __syncthreads();

    const int wave = tid >> 6, lane = tid & 63;
    const int lrow = lane & 15, quad = lane >> 4;
    const int n0 = wave * 32;

    floatx4 acc[4][2];
#pragma unroll
    for (int mt = 0; mt < 4; ++mt)
#pragma unroll
        for (int t = 0; t < 2; ++t)
#pragma unroll
            for (int j = 0; j < 4; ++j) acc[mt][t][j] = 0.f;

#pragma unroll
    for (int c = 0; c < 4; ++c) {
        const int k0 = c * 32;
        const short8 b0 = *(const short8*)&Wl[(n0 + lrow) * 136 + k0 + quad * 8];
        const short8 b1 = *(const short8*)&Wl[(n0 + 16 + lrow) * 136 + k0 + quad * 8];
#pragma unroll
        for (int mt = 0; mt < 4; ++mt) {
            const short8 a = *(const short8*)&Al[(mt * 16 + lrow) * 136 + k0 + quad * 8];
            acc[mt][0] = __builtin_amdgcn_mfma_f32_16x16x32_bf16(a, b0, acc[mt][0], 0, 0, 0);
            acc[mt][1] = __builtin_amdgcn_mfma_f32_16x16x32_bf16(a, b1, acc[mt][1], 0, 0, 0);
        }
    }
    __syncthreads();

#pragma unroll
    for (int mt = 0; mt < 4; ++mt)
#pragma unroll
        for (int t = 0; t < 2; ++t)
#pragma unroll
            for (int j = 0; j < 4; ++j)
                Cl[(mt * 16 + quad * 4 + j) * 132 + n0 + t * 16 + lrow] = acc[mt][t][j];
    __syncthreads();

#pragma unroll
    for (int i = 0; i < 4; ++i) {
        const int row = i * 16 + (tid >> 4);
        const int c0 = (tid & 15) * 8;
        const int gr = r0 + row;
        if (gr < M) {
            const float4 v0 = *(float4*)&Cl[row * 132 + c0];
            const float4 v1 = *(float4*)&Cl[row * 132 + c0 + 4];
            C[(size_t)gr * 16 + (c0 >> 3)] = pk8_fp8(v0, v1);
        }
    }
}

// ============ atomic-free CSR build: two-level bucket counting sort ============
// R1 lesson: global atomicAdd(&cw[s]) storm cost +30us in bucket_place.
// The src-side bucket pipeline (bktS -> LDS segment sums) is cheaper.

__global__ __launch_bounds__(256) void bucket_hist(
    const int* __restrict__ src, const int* __restrict__ dst,
    int* __restrict__ cntD, int* __restrict__ cntS, int E, int B, int chunk)
{
    __shared__ int hD[MAXB], hS[MAXB];
    const int tid = threadIdx.x;
    for (int i = tid; i < B; i += 256) { hD[i] = 0; hS[i] = 0; }
    __syncthreads();
    const int lo = blockIdx.x * chunk;
    const int hi = min(E, lo + chunk);
    for (int e = lo + tid; e < hi; e += 256) {
        atomicAdd(&hD[dst[e] >> NPB_SHIFT], 1);
        atomicAdd(&hS[src[e] >> NPB_SHIFT], 1);
    }
    __syncthreads();
    for (int i = tid; i < B; i += 256) {
        cntD[i * PB + blockIdx.x] = hD[i];
        cntS[i * PB + blockIdx.x] = hS[i];
    }
}

__global__ __launch_bounds__(256) void bucket_base(
    const int* __restrict__ cntD, const int* __restrict__ cntS,
    int* __restrict__ baseD, int* __restrict__ baseS, int B, int E)
{
    __shared__ int lD[256], lS[256];
    const int tid = threadIdx.x;
    int sD = 0, sS = 0;
    if (tid < B) {
        const int4* pD = (const int4*)(cntD + tid * PB);
        const int4* pS = (const int4*)(cntS + tid * PB);
        for (int j = 0; j < PB / 4; ++j) {
            const int4 a = pD[j], b = pS[j];
            sD += a.x + a.y + a.z + a.w;
            sS += b.x + b.y + b.z + b.w;
        }
    }
    lD[tid] = sD; lS[tid] = sS;
    __syncthreads();
    for (int st = 1; st < 256; st <<= 1) {
        const int vD = (tid >= st) ? lD[tid - st] : 0;
        const int vS = (tid >= st) ? lS[tid - st] : 0;
        __syncthreads();
        lD[tid] += vD; lS[tid] += vS;
        __syncthreads();
    }
    if (tid < B) { baseD[tid] = lD[tid] - sD; baseS[tid] = lS[tid] - sS; }
    if (tid == 0) { baseD[B] = E; baseS[B] = E; }
}

__global__ __launch_bounds__(256) void bucket_cursor(
    int* __restrict__ cntD, int* __restrict__ cntS,
    const int* __restrict__ baseD, const int* __restrict__ baseS, int B)
{
    int b = blockIdx.x;
    int* cnt; const int* base;
    if (b < B) { cnt = cntD; base = baseD; }
    else       { cnt = cntS; base = baseS; b -= B; }
    __shared__ int ls[256];
    const int tid = threadIdx.x;
    const int c0 = cnt[b * PB + 2 * tid];
    const int c1 = cnt[b * PB + 2 * tid + 1];
    const int s = c0 + c1;
    ls[tid] = s;
    __syncthreads();
    for (int st = 1; st < 256; st <<= 1) {
        const int v = (tid >= st) ? ls[tid - st] : 0;
        __syncthreads();
        ls[tid] += v;
        __syncthreads();
    }
    const int excl = ls[tid] - s + base[b];
    cnt[b * PB + 2 * tid] = excl;
    cnt[b * PB + 2 * tid + 1] = excl + c0;
}

__global__ __launch_bounds__(256) void bucket_place(
    const int* __restrict__ src, const int* __restrict__ dst,
    const float* __restrict__ ew,
    const int* __restrict__ curD, const int* __restrict__ curS,
    uint2* __restrict__ bktD, uint2* __restrict__ bktS, int E, int B, int chunk)
{
    __shared__ int cD[MAXB], cS[MAXB];
    const int tid = threadIdx.x;
    for (int i = tid; i < B; i += 256) {
        cD[i] = curD[i * PB + blockIdx.x];
        cS[i] = curS[i * PB + blockIdx.x];
    }
    __syncthreads();
    const int lo = blockIdx.x * chunk;
    const int hi = min(E, lo + chunk);
    for (int e = lo + tid; e < hi; e += 256) {
        const int s = src[e], d = dst[e];
        const unsigned wb = __float_as_uint(ew[e]);
        const int pd = atomicAdd(&cD[d >> NPB_SHIFT], 1);
        bktD[pd] = make_uint2(((unsigned)s << NPB_SHIFT) | (unsigned)(d & (NPB - 1)), wb);
        const int ps = atomicAdd(&cS[s >> NPB_SHIFT], 1);
        bktS[ps] = make_uint2((unsigned)(s & (NPB - 1)), wb);
    }
}

// merged: blocks [0,B) counting-sort bktD -> rp/packed; blocks [B,2B) cw sums
// packed.x stores src*16 (uint2 index pre-scale: kills a v_mul in the gather)
__global__ __launch_bounds__(256) void bucket_sortcw(
    const uint2* __restrict__ bktD, const int* __restrict__ baseD,
    int* __restrict__ rp, int2* __restrict__ packed,
    const uint2* __restrict__ bktS, const int* __restrict__ baseS,
    float* __restrict__ cw, int N, int B)
{
    const int tid = threadIdx.x;
    if (blockIdx.x >= B) {
        const int b = blockIdx.x - B;
        const int lo = baseS[b], hi = baseS[b + 1];
        __shared__ float sm[NPB];
        sm[2 * tid] = 0.f; sm[2 * tid + 1] = 0.f;
        __syncthreads();
        for (int i = lo + tid; i < hi; i += 256) {
            const uint2 r = bktS[i];
            atomicAdd(&sm[r.x], __uint_as_float(r.y));
        }
        __syncthreads();
        const int n0 = b * NPB + 2 * tid;
        if (n0 < N)     cw[n0]     = sm[2 * tid];
        if (n0 + 1 < N) cw[n0 + 1] = sm[2 * tid + 1];
        return;
    }
    const int b = blockIdx.x;
    const int lo = baseD[b], hi = baseD[b + 1];
    __shared__ int cnt[NPB], cur[NPB];
    __shared__ int ls[256];
    cnt[2 * tid] = 0; cnt[2 * tid + 1] = 0;
    __syncthreads();
    for (int i = lo + tid; i < hi; i += 256)
        atomicAdd(&cnt[bktD[i].x & (NPB - 1)], 1);
    __syncthreads();
    const int c0 = cnt[2 * tid], c1 = cnt[2 * tid + 1];
    const int s = c0 + c1;
    ls[tid] = s;
    __syncthreads();
    for (int st = 1; st < 256; st <<= 1) {
        const int v = (tid >= st) ? ls[tid - st] : 0;
        __syncthreads();
        ls[tid] += v;
        __syncthreads();
    }
    const int excl = ls[tid] - s;
    const int n0 = b * NPB + 2 * tid;
    if (n0 < N)     rp[n0]     = lo + excl + c0;
    if (n0 + 1 < N) rp[n0 + 1] = lo + excl + c0 + c1;
    cur[2 * tid]     = lo + excl;
    cur[2 * tid + 1] = lo + excl + c0;
    __syncthreads();
    for (int i = lo + tid; i < hi; i += 256) {
        const uint2 r = bktD[i];
        const int pos = atomicAdd(&cur[r.x & (NPB - 1)], 1);
        packed[pos] = make_int2((int)(r.x >> NPB_SHIFT) << 4, (int)r.y);
    }
}

// ------- fused aggregate + BN stats (v13: quarter-per-node, branch-free) -----
// R4 post-mortem: pair scheme = ~7.4 instr/real-edge (reduce 32/pair, 16-slot
// masking, 3/4-idle writes); gathers carried 512B each. New layout: each
// 16-lane quarter owns node pair (X,Y); lane u = cols 8u..8u+7. No cross-lane
// reduce, parallel writes, 4-slot mask granularity with ZERO branches: padded
// slots are {0,0} records -> w=0, gather row 0 (valid fp8, finite). Each gather
// instruction now moves 16 quarters x 128B = 2KB. Records staged in a
// bank-staggered per-quarter LDS strip (stride 65 -> conflict-free broadcast).

#define ACC_EDGE(V, W, A) do { \
    floatx2 w2_; w2_.x = (W); w2_.y = (W); \
    floatx2 f_; \
    f_ = __builtin_amdgcn_cvt_pk_f32_fp8((int)(V).x, false); \
    A[0] = f_ * w2_ + A[0]; \
    f_ = __builtin_amdgcn_cvt_pk_f32_fp8((int)(V).x, true);  \
    A[1] = f_ * w2_ + A[1]; \
    f_ = __builtin_amdgcn_cvt_pk_f32_fp8((int)(V).y, false); \
    A[2] = f_ * w2_ + A[2]; \
    f_ = __builtin_amdgcn_cvt_pk_f32_fp8((int)(V).y, true);  \
    A[3] = f_ * w2_ + A[3]; \
} while (0)

__global__ __launch_bounds__(256) void aggq(
    const int2* __restrict__ packed, const int* __restrict__ rp,
    const uint2* __restrict__ h2, uint4* __restrict__ aggb4,
    float* __restrict__ sum, float* __restrict__ sq, int N)
{
    __shared__ int2 eb[16][65];           // per-quarter: X slots 0..31, Y 32..63
    __shared__ float lsum[512], lsq[512]; // per-wave col strips

    const int tid = threadIdx.x;
    const int lane = tid & 63, wave = tid >> 6;
    const int sub = lane >> 4;            // quarter within wave
    const int u = lane & 15;              // col group 8u..8u+7
    const int wq = wave * 4 + sub;        // block-quarter 0..15
    const int nb0 = blockIdx.x * 32;
    const int nX = nb0 + wq * 2, nY = nX + 1;
    int2* ebq = eb[wq];

    // coalesced row-pointer block: lane l holds rp[nb0-1+l], l in [0,32]
    int rpv = 0;
    {
        const int idx = nb0 - 1 + lane;
        if (lane <= 32 && idx >= 0 && idx < N) rpv = rp[idx];
    }
    const int sX = __shfl(rpv, 2 * wq, 64);
    const int eX = __shfl(rpv, 2 * wq + 1, 64);
    const int eYr = __shfl(rpv, 2 * wq + 2, 64);
    const int sY = eX;
    const int dXf = max(eX - sX, 0), dYf = max(eYr - sY, 0);
    const int eXe = sX + dXf, eYe = sY + dYf;

    // stage first 32 records per node; pad slots = {0,0} (w=0 kills contrib)
    {
        int2 r;
        r = (u      < dXf) ? packed[sX + u]      : make_int2(0, 0); ebq[u]      = r;
        r = (u + 16 < dXf) ? packed[sX + 16 + u] : make_int2(0, 0); ebq[16 + u] = r;
        r = (u      < dYf) ? packed[sY + u]      : make_int2(0, 0); ebq[32 + u] = r;
        r = (u + 16 < dYf) ? packed[sY + 16 + u] : make_int2(0, 0); ebq[48 + u] = r;
    }

    floatx2 aX[4], aY[4];
#pragma unroll
    for (int k = 0; k < 4; ++k) { aX[k] = 0.f; aY[k] = 0.f; }

    const int cX = min(dXf, 32), cY = min(dYf, 32);
    const int jmax = (cX > cY) ? cX : cY;

    // branch-free main loop; quarter-divergent trip count via exec mask
    for (int j = 0; j < jmax; j += 4) {
        const int2 x0 = ebq[j],      x1 = ebq[j + 1];
        const int2 x2 = ebq[j + 2],  x3 = ebq[j + 3];
        const int2 y0 = ebq[32 + j],     y1 = ebq[32 + j + 1];
        const int2 y2 = ebq[32 + j + 2], y3 = ebq[32 + j + 3];
        const uint2 vx0 = h2[(size_t)(unsigned)(x0.x + u)];
        const uint2 vx1 = h2[(size_t)(unsigned)(x1.x + u)];
        const uint2 vx2 = h2[(size_t)(unsigned)(x2.x + u)];
        const uint2 vx3 = h2[(size_t)(unsigned)(x3.x + u)];
        const uint2 vy0 = h2[(size_t)(unsigned)(y0.x + u)];
        const uint2 vy1 = h2[(size_t)(unsigned)(y1.x + u)];
        const uint2 vy2 = h2[(size_t)(unsigned)(y2.x + u)];
        const uint2 vy3 = h2[(size_t)(unsigned)(y3.x + u)];
        ACC_EDGE(vx0, __int_as_float(x0.y), aX);
        ACC_EDGE(vx1, __int_as_float(x1.y), aX);
        ACC_EDGE(vx2, __int_as_float(x2.y), aX);
        ACC_EDGE(vx3, __int_as_float(x3.y), aX);
        ACC_EDGE(vy0, __int_as_float(y0.y), aY);
        ACC_EDGE(vy1, __int_as_float(y1.y), aY);
        ACC_EDGE(vy2, __int_as_float(y2.y), aY);
        ACC_EDGE(vy3, __int_as_float(y3.y), aY);
    }

    // rare overflow (degree > 32): reload X region in 32-chunks
    for (int base = sX + 32; base < eXe; base += 32) {
        const int rem = eXe - base;
        int2 r;
        r = (u      < rem) ? packed[base + u]      : make_int2(0, 0); ebq[u]      = r;
        r = (u + 16 < rem) ? packed[base + 16 + u] : make_int2(0, 0); ebq[16 + u] = r;
        const int cc = min(rem, 32);
        for (int j = 0; j < cc; j += 4) {
            const int2 x0 = ebq[j], x1 = ebq[j + 1], x2 = ebq[j + 2], x3 = ebq[j + 3];
            const uint2 v0 = h2[(size_t)(unsigned)(x0.x + u)];
            const uint2 v1 = h2[(size_t)(unsigned)(x1.x + u)];
            const uint2 v2 = h2[(size_t)(unsigned)(x2.x + u)];
            const uint2 v3 = h2[(size_t)(unsigned)(x3.x + u)];
            ACC_EDGE(v0, __int_as_float(x0.y), aX);
            ACC_EDGE(v1, __int_as_float(x1.y), aX);
            ACC_EDGE(v2, __int_as_float(x2.y), aX);
            ACC_EDGE(v3, __int_as_float(x3.y), aX);
        }
    }
    for (int base = sY + 32; base < eYe; base += 32) {
        const int rem = eYe - base;
        int2 r;
        r = (u      < rem) ? packed[base + u]      : make_int2(0, 0); ebq[32 + u] = r;
        r = (u + 16 < rem) ? packed[base + 16 + u] : make_int2(0, 0); ebq[48 + u] = r;
        const int cc = min(rem, 32);
        for (int j = 0; j < cc; j += 4) {
            const int2 y0 = ebq[32 + j], y1 = ebq[32 + j + 1];
            const int2 y2 = ebq[32 + j + 2], y3 = ebq[32 + j + 3];
            const uint2 v0 = h2[(size_t)(unsigned)(y0.x + u)];
            const uint2 v1 = h2[(size_t)(unsigned)(y1.x + u)];
            const uint2 v2 = h2[(size_t)(unsigned)(y2.x + u)];
            const uint2 v3 = h2[(size_t)(unsigned)(y3.x + u)];
            ACC_EDGE(v0, __int_as_float(y0.y), aY);
            ACC_EDGE(v1, __int_as_float(y1.y), aY);
            ACC_EDGE(v2, __int_as_float(y2.y), aY);
            ACC_EDGE(v3, __int_as_float(y3.y), aY);
        }
    }

    // parallel writes: every lane stores its own 16B row-slice
    if (nX < N) {
        uint4 o;
        o.x = (unsigned)f2bf(aX[0].x) | ((unsigned)f2bf(aX[0].y) << 16);
        o.y = (unsigned)f2bf(aX[1].x) | ((unsigned)f2bf(aX[1].y) << 16);
        o.z = (unsigned)f2bf(aX[2].x) | ((unsigned)f2bf(aX[2].y) << 16);
        o.w = (unsigned)f2bf(aX[3].x) | ((unsigned)f2bf(aX[3].y) << 16);
        aggb4[(size_t)nX * 16 + u] = o;
    }
    if (nY < N) {
        uint4 o;
        o.x = (unsigned)f2bf(aY[0].x) | ((unsigned)f2bf(aY[0].y) << 16);
        o.y = (unsigned)f2bf(aY[1].x) | ((unsigned)f2bf(aY[1].y) << 16);
        o.z = (unsigned)f2bf(aY[2].x) | ((unsigned)f2bf(aY[2].y) << 16);
        o.w = (unsigned)f2bf(aY[3].x) | ((unsigned)f2bf(aY[3].y) << 16);
        aggb4[(size_t)nY * 16 + u] = o;
    }

    // BN stats: per-lane pair totals, cross-sub shfl reduce (once per block)
    floatx2 cs0 = aX[0] + aY[0], cs1 = aX[1] + aY[1];
    floatx2 cs2 = aX[2] + aY[2], cs3 = aX[3] + aY[3];
    floatx2 cq0 = aX[0] * aX[0] + aY[0] * aY[0];
    floatx2 cq1 = aX[1] * aX[1] + aY[1] * aY[1];
    floatx2 cq2 = aX[2] * aX[2] + aY[2] * aY[2];
    floatx2 cq3 = aX[3] * aX[3] + aY[3] * aY[3];
#define XRED(V) \
    V.x += __shfl_xor(V.x, 16, 64); V.y += __shfl_xor(V.y, 16, 64); \
    V.x += __shfl_xor(V.x, 32, 64); V.y += __shfl_xor(V.y, 32, 64);
    XRED(cs0) XRED(cs1) XRED(cs2) XRED(cs3)
    XRED(cq0) XRED(cq1) XRED(cq2) XRED(cq3)
#undef XRED
    // lane (sub,u) stores col pair u*8+2*sub (2-way bank alias only)
    const floatx2 ws = (sub == 0) ? cs0 : (sub == 1) ? cs1 : (sub == 2) ? cs2 : cs3;
    const floatx2 wwq = (sub == 0) ? cq0 : (sub == 1) ? cq1 : (sub == 2) ? cq2 : cq3;
    const int col = u * 8 + 2 * sub;
    lsum[wave * 128 + col] = ws.x;  lsum[wave * 128 + col + 1] = ws.y;
    lsq[wave * 128 + col]  = wwq.x; lsq[wave * 128 + col + 1]  = wwq.y;
    __syncthreads();
    if (tid < 128) {
        float s = 0.f, q = 0.f;
#pragma unroll
        for (int i = 0; i < 4; ++i) {
            s += lsum[i * 128 + tid];
            q += lsq[i * 128 + tid];
        }
        const int sl = (blockIdx.x & (NSLICE - 1)) * 128;
        atomicAdd(&sum[sl + tid], s);
        atomicAdd(&sq[sl + tid], q);
    }
}

// ---------------- collapsed layer 2 (persistent grid, sliced-stat prologue) ----
__global__ __launch_bounds__(256) void wcolsum_bf16(
    const unsigned* __restrict__ xb, const float* __restrict__ cw,
    const float* __restrict__ sum1, const float* __restrict__ sq1,
    const float* __restrict__ g, const float* __restrict__ be,
    float* __restrict__ sout, int N)
{
    __shared__ float Aaf[128], Baf[128];
    __shared__ float2 ls[256];
    const int tid = threadIdx.x;
    if (tid < 128) {
        float s = 0.f, q = 0.f;
#pragma unroll
        for (int k = 0; k < NSLICE; ++k) {
            s += sum1[k * 128 + tid];
            q += sq1[k * 128 + tid];
        }
        const float invN = 1.0f / (float)N;
        const float m = s * invN;
        const float var = q * invN - m * m;
        const float rs = rsqrtf(var + BN_EPS);
        Aaf[tid] = g[tid] * rs;
        Baf[tid] = be[tid] - g[tid] * m * rs;
    }
    __syncthreads();
    const int u = tid & 63, rr = tid >> 6;
    const float ax = Aaf[2 * u], ay = Aaf[2 * u + 1];
    const float bx = Baf[2 * u], by = Baf[2 * u + 1];
    float2 s = {0.f, 0.f};
    for (int row = blockIdx.x * 4 + rr; row < N; row += gridDim.x * 4) {
        const unsigned v = xb[(size_t)row * 64 + u];
        const float c = cw[row];
        const float x = fmaxf(fmaf(ax, blo(v), bx), 0.f);
        const float y = fmaxf(fmaf(ay, bhi(v), by), 0.f);
        s.x = fmaf(c, x, s.x);
        s.y = fmaf(c, y, s.y);
    }
    ls[tid] = s;
    __syncthreads();
    if (tid < 64) {
        float sx = ls[tid].x + ls[64 + tid].x + ls[128 + tid].x + ls[192 + tid].x;
        float sy = ls[tid].y + ls[64 + tid].y + ls[128 + tid].y + ls[192 + tid].y;
        atomicAdd(&sout[2 * tid + 0], sx);
        atomicAdd(&sout[2 * tid + 1], sy);
    }
}

__global__ void final_out(
    const float* __restrict__ s, const float* __restrict__ W2,
    const float* __restrict__ b2, float* __restrict__ out, int N, int Dout)
{
    const int j = threadIdx.x;
    if (j < Dout) {
        float acc = 0.f;
        for (int f = 0; f < 128; ++f) acc = fmaf(s[f], W2[f * Dout + j], acc);
        out[j] = acc + (float)N * b2[j];
    }
}

extern "C" void kernel_launch(void* const* d_in, const int* in_sizes, int n_in,
                              void* d_out, int out_size, void* d_ws, size_t ws_size,
                              hipStream_t stream)
{
    const float* nf  = (const float*)d_in[0];
    const int*   ei  = (const int*)d_in[1];
    const float* ew  = (const float*)d_in[2];
    const float* W0  = (const float*)d_in[3];
    // b0 = d_in[4], b1 = d_in[6]: cancel inside BatchNorm, unused
    const float* W1  = (const float*)d_in[5];
    const float* W2  = (const float*)d_in[7];
    const float* b2  = (const float*)d_in[8];
    const float* g0  = (const float*)d_in[9];
    const float* be0 = (const float*)d_in[10];
    const float* g1  = (const float*)d_in[11];
    const float* be1 = (const float*)d_in[12];

    const int N = in_sizes[0] / 128;
    const int E = in_sizes[2];
    const int* srcI = ei;       // edge_index[0,:]
    const int* dstI = ei + E;   // edge_index[1,:]

    const int B = (N + NPB - 1) / NPB;        // 196 for N=100k
    const int chunk = (E + PB - 1) / PB;

    const size_t HB = ((size_t)N * 128 * 2 + 255) & ~(size_t)255;  // bf16 buf
    const size_t NA = ((size_t)N * sizeof(int) + 255) & ~(size_t)255;
    const size_t CB = (((size_t)B * PB * 4) + 255) & ~(size_t)255;
    char* ws = (char*)d_ws;
    size_t off = 0;
    float* cw    = (float*)(ws + off); off += NA;
    int*   rp    = (int*)  (ws + off); off += NA;
    float* stats = (float*)(ws + off); off += 36864;   // 4 sliced arrays + svec
    int*   cntD  = (int*)  (ws + off); off += CB;
    int*   cntS  = (int*)  (ws + off); off += CB;
    int*   baseD = (int*)  (ws + off); off += 2048;
    int*   baseS = (int*)  (ws + off); off += 2048;
    uint2* hbuf  = (uint2*)(ws + off); off += HB;      // h (fp8, oversized ok)
    unsigned* aggb = (unsigned*)(ws + off); off += HB; // agg (bf16)
    int2*  packed = (int2*)(ws + off); off += (size_t)E * 8;
    uint2* bktD  = (uint2*)(ws + off); off += (size_t)E * 8;
    uint2* bktS  = (uint2*)(ws + off); off += (size_t)E * 8;
    unsigned short* wt0 = (unsigned short*)(ws + off); off += 32768;
    unsigned short* wt1 = (unsigned short*)(ws + off); off += 32768;
    (void)ws_size;  // rounds 1-11 proved ws_size >= 116.5 MB; this needs ~92 MB

    // sliced stats: each array NSLICE*128 floats
    float* sum0 = stats + 0 * NSLICE * 128;
    float* sq0  = stats + 1 * NSLICE * 128;
    float* sum1 = stats + 2 * NSLICE * 128;
    float* sq1  = stats + 3 * NSLICE * 128;
    float* svec = stats + 4 * NSLICE * 128;   // [128]

    const int gemmGrid = (N + 63) / 64;
    const int aggGrid  = (N + 31) / 32;       // 3125

    // ---- atomic-free CSR build + cw (graph identical both layers) ----
    bucket_hist<<<PB, 256, 0, stream>>>(srcI, dstI, cntD, cntS, E, B, chunk);
    bucket_base<<<1, 256, 0, stream>>>(cntD, cntS, baseD, baseS, B, E);
    bucket_cursor<<<2 * B, 256, 0, stream>>>(cntD, cntS, baseD, baseS, B);
    bucket_place<<<PB, 256, 0, stream>>>(srcI, dstI, ew, cntD, cntS, bktD, bktS, E, B, chunk);
    bucket_sortcw<<<2 * B, 256, 0, stream>>>(bktD, baseD, rp, packed,
                                             bktS, baseS, cw, N, B);
    wconv<<<64, 256, 0, stream>>>(W0, W1, wt0, wt1, stats);   // + stats zeroing

    // ---- layer 0 ----
    gemm0<<<gemmGrid, 256, 0, stream>>>(nf, wt0, hbuf, N);
    aggq<<<aggGrid, 256, 0, stream>>>(
        packed, rp, (const uint2*)hbuf, (uint4*)aggb, sum0, sq0, N);

    // ---- layer 1 (BN0+ReLU folded into GEMM staging) ----
    gemm1<<<gemmGrid, 256, 0, stream>>>(aggb, wt1, hbuf, sum0, sq0, g0, be0, N, N);
    aggq<<<aggGrid, 256, 0, stream>>>(
        packed, rp, (const uint2*)hbuf, (uint4*)aggb, sum1, sq1, N);

    // ---- collapsed layer 2: out = (sum_n cw[n]*relu(BN1(x2))[n,:]) @ W2 + N*b2 ----
    wcolsum_bf16<<<256, 256, 0, stream>>>(aggb, cw, sum1, sq1, g1, be1, svec, N);
    final_out<<<1, 64, 0, stream>>>(svec, W2, b2, (float*)d_out, N, out_size);
}

// Round 6
// 342.374 us; speedup vs baseline: 1.2810x; 1.0448x over previous
//
#include <hip/hip_runtime.h>

#define BN_EPS 1e-5f

// Bucket-sort parameters: NPB nodes per bucket (pow2), PB placement blocks.
#define NPB 512
#define NPB_SHIFT 9
#define PB 512
#define MAXB 256
// BN-stat accumulator slices (atomic-depth reduction)
#define NSLICE 16

typedef __attribute__((ext_vector_type(8))) short short8;
typedef __attribute__((ext_vector_type(4))) float floatx4;
typedef __attribute__((ext_vector_type(2))) float floatx2;

__device__ __forceinline__ unsigned short f2bf(float f) {
    unsigned u = __float_as_uint(f);
    unsigned r = u + 0x7FFFu + ((u >> 16) & 1u);   // round-to-nearest-even
    return (unsigned short)(r >> 16);
}
__device__ __forceinline__ float blo(unsigned v) { return __uint_as_float(v << 16); }
__device__ __forceinline__ float bhi(unsigned v) { return __uint_as_float(v & 0xffff0000u); }

// pack 8 fp32 -> 8 fp8 e4m3 (2 dwords); byte k of output = value k
__device__ __forceinline__ uint2 pk8_fp8(const float4 v0, const float4 v1) {
    int lo = 0, hi = 0;
    lo = __builtin_amdgcn_cvt_pk_fp8_f32(v0.x, v0.y, lo, false);
    lo = __builtin_amdgcn_cvt_pk_fp8_f32(v0.z, v0.w, lo, true);
    hi = __builtin_amdgcn_cvt_pk_fp8_f32(v1.x, v1.y, hi, false);
    hi = __builtin_amdgcn_cvt_pk_fp8_f32(v1.z, v1.w, hi, true);
    return make_uint2((unsigned)lo, (unsigned)hi);
}

// ------- W pre-transpose (+ stats zeroing folded in, saves a dispatch) -------
__global__ __launch_bounds__(256) void wconv(
    const float* __restrict__ W0, const float* __restrict__ W1,
    unsigned short* __restrict__ wt0, unsigned short* __restrict__ wt1,
    float* __restrict__ stats)
{
    const int idx = blockIdx.x * 256 + threadIdx.x;   // < 16384
    const int n = idx >> 7, k = idx & 127;
    wt0[idx] = f2bf(W0[k * 128 + n]);
    wt1[idx] = f2bf(W1[k * 128 + n]);
    if (blockIdx.x < 10) {  // zero 10240 floats (4 sliced stat arrays + sliced svec)
        const int o = (blockIdx.x * 256 + threadIdx.x) * 4;
        *(float4*)&stats[o] = make_float4(0.f, 0.f, 0.f, 0.f);
    }
}

// ------- layer-0 GEMM: C[M x 128] = A_fp32 @ W, C in fp8 e4m3 -------
__global__ __launch_bounds__(256) void gemm0(
    const float* __restrict__ A, const unsigned short* __restrict__ Wt,
    uint2* __restrict__ C, int M)
{
    __shared__ char lds[53248];
    unsigned short* Al = (unsigned short*)lds;            // [64][136] bf16
    unsigned short* Wl = (unsigned short*)(lds + 17408);  // [128][136] bf16
    float* Cl = (float*)lds;                              // [64][132] f32 (reuse)

    const int tid = threadIdx.x;
    const int r0 = blockIdx.x * 64;

#pragma unroll
    for (int i = 0; i < 16; ++i) {
        const int idx = i * 256 + tid;          // ushort4 units
        const int n = idx >> 5, q = idx & 31;
        const ushort4 v = ((const ushort4*)Wt)[idx];
        *(ushort4*)&Wl[n * 136 + q * 4] = v;
    }
#pragma unroll
    for (int i = 0; i < 8; ++i) {
        const int row = i * 8 + (tid >> 5), q = tid & 31;
        const int gr = r0 + row;
        float4 v = (gr < M) ? ((const float4*)A)[(size_t)gr * 32 + q]
                            : make_float4(0.f, 0.f, 0.f, 0.f);
        ushort4 o;
        o.x = f2bf(v.x); o.y = f2bf(v.y); o.z = f2bf(v.z); o.w = f2bf(v.w);
        *(ushort4*)&Al[row * 136 + q * 4] = o;
    }
    __syncthreads();

    const int wave = tid >> 6, lane = tid & 63;
    const int lrow = lane & 15, quad = lane >> 4;
    const int n0 = wave * 32;

    floatx4 acc[4][2];
#pragma unroll
    for (int mt = 0; mt < 4; ++mt)
#pragma unroll
        for (int t = 0; t < 2; ++t)
#pragma unroll
            for (int j = 0; j < 4; ++j) acc[mt][t][j] = 0.f;

#pragma unroll
    for (int c = 0; c < 4; ++c) {
        const int k0 = c * 32;
        const short8 b0 = *(const short8*)&Wl[(n0 + lrow) * 136 + k0 + quad * 8];
        const short8 b1 = *(const short8*)&Wl[(n0 + 16 + lrow) * 136 + k0 + quad * 8];
#pragma unroll
        for (int mt = 0; mt < 4; ++mt) {
            const short8 a = *(const short8*)&Al[(mt * 16 + lrow) * 136 + k0 + quad * 8];
            acc[mt][0] = __builtin_amdgcn_mfma_f32_16x16x32_bf16(a, b0, acc[mt][0], 0, 0, 0);
            acc[mt][1] = __builtin_amdgcn_mfma_f32_16x16x32_bf16(a, b1, acc[mt][1], 0, 0, 0);
        }
    }
    __syncthreads();

#pragma unroll
    for (int mt = 0; mt < 4; ++mt)
#pragma unroll
        for (int t = 0; t < 2; ++t)
#pragma unroll
            for (int j = 0; j < 4; ++j)
                Cl[(mt * 16 + quad * 4 + j) * 132 + n0 + t * 16 + lrow] = acc[mt][t][j];
    __syncthreads();

#pragma unroll
    for (int i = 0; i < 4; ++i) {
        const int row = i * 16 + (tid >> 4);
        const int c0 = (tid & 15) * 8;
        const int gr = r0 + row;
        if (gr < M) {
            const float4 v0 = *(float4*)&Cl[row * 132 + c0];
            const float4 v1 = *(float4*)&Cl[row * 132 + c0 + 4];
            C[(size_t)gr * 16 + (c0 >> 3)] = pk8_fp8(v0, v1);
        }
    }
}

// ------- layer-1 GEMM: C = relu(BN(A_bf16)) @ W, C in fp8 e4m3 -------
__global__ __launch_bounds__(256) void gemm1(
    const unsigned* __restrict__ Ab, const unsigned short* __restrict__ Wt,
    uint2* __restrict__ C,
    const float* __restrict__ sum, const float* __restrict__ sq,
    const float* __restrict__ g, const float* __restrict__ be,
    int M, int N)
{
    __shared__ char lds[53248];
    unsigned short* Al = (unsigned short*)lds;            // [64][136]
    unsigned short* Wl = (unsigned short*)(lds + 17408);  // [128][136]
    float* AscL = (float*)(lds + 52224);                  // [128]
    float* AshL = AscL + 128;
    float* Cl = (float*)lds;

    const int tid = threadIdx.x;
    const int r0 = blockIdx.x * 64;

    if (tid < 128) {
        float s = 0.f, q = 0.f;
#pragma unroll
        for (int k = 0; k < NSLICE; ++k) {
            s += sum[k * 128 + tid];
            q += sq[k * 128 + tid];
        }
        const float invN = 1.0f / (float)N;
        const float m = s * invN;
        const float var = q * invN - m * m;
        const float rs = rsqrtf(var + BN_EPS);
        AscL[tid] = g[tid] * rs;
        AshL[tid] = be[tid] - g[tid] * m * rs;
    }
    __syncthreads();

#pragma unroll
    for (int i = 0; i < 16; ++i) {
        const int idx = i * 256 + tid;
        const int n = idx >> 5, q = idx & 31;
        const ushort4 v = ((const ushort4*)Wt)[idx];
        *(ushort4*)&Wl[n * 136 + q * 4] = v;
    }
#pragma unroll
    for (int i = 0; i < 4; ++i) {
        const int idx = i * 256 + tid;
        const int row = idx >> 4, qc = idx & 15;
        const int gr = r0 + row;
        uint4 v = (gr < M) ? ((const uint4*)Ab)[(size_t)gr * 16 + qc]
                           : make_uint4(0, 0, 0, 0);
        const float4 a0 = *(const float4*)&AscL[qc * 8];
        const float4 a1 = *(const float4*)&AscL[qc * 8 + 4];
        const float4 b0 = *(const float4*)&AshL[qc * 8];
        const float4 b1 = *(const float4*)&AshL[qc * 8 + 4];
        float x0 = fmaxf(fmaf(a0.x, blo(v.x), b0.x), 0.f);
        float x1 = fmaxf(fmaf(a0.y, bhi(v.x), b0.y), 0.f);
        float x2 = fmaxf(fmaf(a0.z, blo(v.y), b0.z), 0.f);
        float x3 = fmaxf(fmaf(a0.w, bhi(v.y), b0.w), 0.f);
        float x4 = fmaxf(fmaf(a1.x, blo(v.z), b1.x), 0.f);
        float x5 = fmaxf(fmaf(a1.y, bhi(v.z), b1.y), 0.f);
        float x6 = fmaxf(fmaf(a1.z, blo(v.w), b1.z), 0.f);
        float x7 = fmaxf(fmaf(a1.w, bhi(v.w), b1.w), 0.f);
        uint4 o;
        o.x = (unsigned)f2bf(x0) | ((unsigned)f2bf(x1) << 16);
        o.y = (unsigned)f2bf(x2) | ((unsigned)f2bf(x3) << 16);
        o.z = (unsigned)f2bf(x4) | ((unsigned)f2bf(x5) << 16);
        o.w = (unsigned)f2bf(x6) | ((unsigned)f2bf(x7) << 16);
        *(uint4*)&Al[row * 136 + qc * 8] = o;
    }
    __syncthreads();

    const int wave = tid >> 6, lane = tid & 63;
    const int lrow = lane & 15, quad = lane >> 4;
    const int n0 = wave * 32;

    floatx4 acc[4][2];
#pragma unroll
    for (int mt = 0; mt < 4; ++mt)
#pragma unroll
        for (int t = 0; t < 2; ++t)
#pragma unroll
            for (int j = 0; j < 4; ++j) acc[mt][t][j] = 0.f;

#pragma unroll
    for (int c = 0; c < 4; ++c) {
        const int k0 = c * 32;
        const short8 b0 = *(const short8*)&Wl[(n0 + lrow) * 136 + k0 + quad * 8];
        const short8 b1 = *(const short8*)&Wl[(n0 + 16 + lrow) * 136 + k0 + quad * 8];
#pragma unroll
        for (int mt = 0; mt < 4; ++mt) {
            const short8 a = *(const short8*)&Al[(mt * 16 + lrow) * 136 + k0 + quad * 8];
            acc[mt][0] = __builtin_amdgcn_mfma_f32_16x16x32_bf16(a, b0, acc[mt][0], 0, 0, 0);
            acc[mt][1] = __builtin_amdgcn_mfma_f32_16x16x32_bf16(a, b1, acc[mt][1], 0, 0, 0);
        }
    }
    __syncthreads();

#pragma unroll
    for (int mt = 0; mt < 4; ++mt)
#pragma unroll
        for (int t = 0; t < 2; ++t)
#pragma unroll
            for (int j = 0; j < 4; ++j)
                Cl[(mt * 16 + quad * 4 + j) * 132 + n0 + t * 16 + lrow] = acc[mt][t][j];
    __syncthreads();

#pragma unroll
    for (int i = 0; i < 4; ++i) {
        const int row = i * 16 + (tid >> 4);
        const int c0 = (tid & 15) * 8;
        const int gr = r0 + row;
        if (gr < M) {
            const float4 v0 = *(float4*)&Cl[row * 132 + c0];
            const float4 v1 = *(float4*)&Cl[row * 132 + c0 + 4];
            C[(size_t)gr * 16 + (c0 >> 3)] = pk8_fp8(v0, v1);
        }
    }
}

// ============ atomic-free CSR build: two-level bucket counting sort ============
// R1 lesson: global atomicAdd(&cw[s]) storm cost +30us in bucket_place.
// R5: hist/place blocks 256->512 threads (16 waves/CU resident) -- scattered
// 8B bucket writes need more in-flight misses to fill the memory system
// (place was 43.8us @ occupancy 16.5%, VALUBusy 1.4%).

__global__ __launch_bounds__(512) void bucket_hist(
    const int* __restrict__ src, const int* __restrict__ dst,
    int* __restrict__ cntD, int* __restrict__ cntS, int E, int B, int chunk)
{
    __shared__ int hD[MAXB], hS[MAXB];
    const int tid = threadIdx.x;
    for (int i = tid; i < B; i += 512) { hD[i] = 0; hS[i] = 0; }
    __syncthreads();
    const int lo = blockIdx.x * chunk;
    const int hi = min(E, lo + chunk);
    for (int e = lo + tid; e < hi; e += 512) {
        atomicAdd(&hD[dst[e] >> NPB_SHIFT], 1);
        atomicAdd(&hS[src[e] >> NPB_SHIFT], 1);
    }
    __syncthreads();
    for (int i = tid; i < B; i += 512) {
        cntD[i * PB + blockIdx.x] = hD[i];
        cntS[i * PB + blockIdx.x] = hS[i];
    }
}

__global__ __launch_bounds__(256) void bucket_base(
    const int* __restrict__ cntD, const int* __restrict__ cntS,
    int* __restrict__ baseD, int* __restrict__ baseS, int B, int E)
{
    __shared__ int lD[256], lS[256];
    const int tid = threadIdx.x;
    int sD = 0, sS = 0;
    if (tid < B) {
        const int4* pD = (const int4*)(cntD + tid * PB);
        const int4* pS = (const int4*)(cntS + tid * PB);
        for (int j = 0; j < PB / 4; ++j) {
            const int4 a = pD[j], b = pS[j];
            sD += a.x + a.y + a.z + a.w;
            sS += b.x + b.y + b.z + b.w;
        }
    }
    lD[tid] = sD; lS[tid] = sS;
    __syncthreads();
    for (int st = 1; st < 256; st <<= 1) {
        const int vD = (tid >= st) ? lD[tid - st] : 0;
        const int vS = (tid >= st) ? lS[tid - st] : 0;
        __syncthreads();
        lD[tid] += vD; lS[tid] += vS;
        __syncthreads();
    }
    if (tid < B) { baseD[tid] = lD[tid] - sD; baseS[tid] = lS[tid] - sS; }
    if (tid == 0) { baseD[B] = E; baseS[B] = E; }
}

__global__ __launch_bounds__(256) void bucket_cursor(
    int* __restrict__ cntD, int* __restrict__ cntS,
    const int* __restrict__ baseD, const int* __restrict__ baseS, int B)
{
    int b = blockIdx.x;
    int* cnt; const int* base;
    if (b < B) { cnt = cntD; base = baseD; }
    else       { cnt = cntS; base = baseS; b -= B; }
    __shared__ int ls[256];
    const int tid = threadIdx.x;
    const int c0 = cnt[b * PB + 2 * tid];
    const int c1 = cnt[b * PB + 2 * tid + 1];
    const int s = c0 + c1;
    ls[tid] = s;
    __syncthreads();
    for (int st = 1; st < 256; st <<= 1) {
        const int v = (tid >= st) ? ls[tid - st] : 0;
        __syncthreads();
        ls[tid] += v;
        __syncthreads();
    }
    const int excl = ls[tid] - s + base[b];
    cnt[b * PB + 2 * tid] = excl;
    cnt[b * PB + 2 * tid + 1] = excl + c0;
}

__global__ __launch_bounds__(512) void bucket_place(
    const int* __restrict__ src, const int* __restrict__ dst,
    const float* __restrict__ ew,
    const int* __restrict__ curD, const int* __restrict__ curS,
    uint2* __restrict__ bktD, uint2* __restrict__ bktS, int E, int B, int chunk)
{
    __shared__ int cD[MAXB], cS[MAXB];
    const int tid = threadIdx.x;
    for (int i = tid; i < B; i += 512) {
        cD[i] = curD[i * PB + blockIdx.x];
        cS[i] = curS[i * PB + blockIdx.x];
    }
    __syncthreads();
    const int lo = blockIdx.x * chunk;
    const int hi = min(E, lo + chunk);
    for (int e = lo + tid; e < hi; e += 512) {
        const int s = src[e], d = dst[e];
        const unsigned wb = __float_as_uint(ew[e]);
        const int pd = atomicAdd(&cD[d >> NPB_SHIFT], 1);
        bktD[pd] = make_uint2(((unsigned)s << NPB_SHIFT) | (unsigned)(d & (NPB - 1)), wb);
        const int ps = atomicAdd(&cS[s >> NPB_SHIFT], 1);
        bktS[ps] = make_uint2((unsigned)(s & (NPB - 1)), wb);
    }
}

// merged: blocks [0,B) counting-sort bktD -> rp/packed; blocks [B,2B) cw sums
// packed.x stores src*16 (uint2 index pre-scale: kills a v_mul in the gather)
__global__ __launch_bounds__(256) void bucket_sortcw(
    const uint2* __restrict__ bktD, const int* __restrict__ baseD,
    int* __restrict__ rp, int2* __restrict__ packed,
    const uint2* __restrict__ bktS, const int* __restrict__ baseS,
    float* __restrict__ cw, int N, int B)
{
    const int tid = threadIdx.x;
    if (blockIdx.x >= B) {
        const int b = blockIdx.x - B;
        const int lo = baseS[b], hi = baseS[b + 1];
        __shared__ float sm[NPB];
        sm[2 * tid] = 0.f; sm[2 * tid + 1] = 0.f;
        __syncthreads();
        for (int i = lo + tid; i < hi; i += 256) {
            const uint2 r = bktS[i];
            atomicAdd(&sm[r.x], __uint_as_float(r.y));
        }
        __syncthreads();
        const int n0 = b * NPB + 2 * tid;
        if (n0 < N)     cw[n0]     = sm[2 * tid];
        if (n0 + 1 < N) cw[n0 + 1] = sm[2 * tid + 1];
        return;
    }
    const int b = blockIdx.x;
    const int lo = baseD[b], hi = baseD[b + 1];
    __shared__ int cnt[NPB], cur[NPB];
    __shared__ int ls[256];
    cnt[2 * tid] = 0; cnt[2 * tid + 1] = 0;
    __syncthreads();
    for (int i = lo + tid; i < hi; i += 256)
        atomicAdd(&cnt[bktD[i].x & (NPB - 1)], 1);
    __syncthreads();
    const int c0 = cnt[2 * tid], c1 = cnt[2 * tid + 1];
    const int s = c0 + c1;
    ls[tid] = s;
    __syncthreads();
    for (int st = 1; st < 256; st <<= 1) {
        const int v = (tid >= st) ? ls[tid - st] : 0;
        __syncthreads();
        ls[tid] += v;
        __syncthreads();
    }
    const int excl = ls[tid] - s;
    const int n0 = b * NPB + 2 * tid;
    if (n0 < N)     rp[n0]     = lo + excl + c0;
    if (n0 + 1 < N) rp[n0 + 1] = lo + excl + c0 + c1;
    cur[2 * tid]     = lo + excl;
    cur[2 * tid + 1] = lo + excl + c0;
    __syncthreads();
    for (int i = lo + tid; i < hi; i += 256) {
        const uint2 r = bktD[i];
        const int pos = atomicAdd(&cur[r.x & (NPB - 1)], 1);
        packed[pos] = make_int2((int)(r.x >> NPB_SHIFT) << 4, (int)r.y);
    }
}

// ------- fused aggregate + BN stats (v13: quarter-per-node, branch-free) -----
// Each 16-lane quarter owns node pair (X,Y); lane u = cols 8u..8u+7. No
// cross-lane reduce, parallel writes, pad slots {0,0} -> w=0 kills contrib.

#define ACC_EDGE(V, W, A) do { \
    floatx2 w2_; w2_.x = (W); w2_.y = (W); \
    floatx2 f_; \
    f_ = __builtin_amdgcn_cvt_pk_f32_fp8((int)(V).x, false); \
    A[0] = f_ * w2_ + A[0]; \
    f_ = __builtin_amdgcn_cvt_pk_f32_fp8((int)(V).x, true);  \
    A[1] = f_ * w2_ + A[1]; \
    f_ = __builtin_amdgcn_cvt_pk_f32_fp8((int)(V).y, false); \
    A[2] = f_ * w2_ + A[2]; \
    f_ = __builtin_amdgcn_cvt_pk_f32_fp8((int)(V).y, true);  \
    A[3] = f_ * w2_ + A[3]; \
} while (0)

__global__ __launch_bounds__(256) void aggq(
    const int2* __restrict__ packed, const int* __restrict__ rp,
    const uint2* __restrict__ h2, uint4* __restrict__ aggb4,
    float* __restrict__ sum, float* __restrict__ sq, int N)
{
    __shared__ int2 eb[16][65];           // per-quarter: X slots 0..31, Y 32..63
    __shared__ float lsum[512], lsq[512]; // per-wave col strips

    const int tid = threadIdx.x;
    const int lane = tid & 63, wave = tid >> 6;
    const int sub = lane >> 4;            // quarter within wave
    const int u = lane & 15;              // col group 8u..8u+7
    const int wq = wave * 4 + sub;        // block-quarter 0..15
    const int nb0 = blockIdx.x * 32;
    const int nX = nb0 + wq * 2, nY = nX + 1;
    int2* ebq = eb[wq];

    // coalesced row-pointer block: lane l holds rp[nb0-1+l], l in [0,32]
    int rpv = 0;
    {
        const int idx = nb0 - 1 + lane;
        if (lane <= 32 && idx >= 0 && idx < N) rpv = rp[idx];
    }
    const int sX = __shfl(rpv, 2 * wq, 64);
    const int eX = __shfl(rpv, 2 * wq + 1, 64);
    const int eYr = __shfl(rpv, 2 * wq + 2, 64);
    const int sY = eX;
    const int dXf = max(eX - sX, 0), dYf = max(eYr - sY, 0);
    const int eXe = sX + dXf, eYe = sY + dYf;

    // stage first 32 records per node; pad slots = {0,0} (w=0 kills contrib)
    {
        int2 r;
        r = (u      < dXf) ? packed[sX + u]      : make_int2(0, 0); ebq[u]      = r;
        r = (u + 16 < dXf) ? packed[sX + 16 + u] : make_int2(0, 0); ebq[16 + u] = r;
        r = (u      < dYf) ? packed[sY + u]      : make_int2(0, 0); ebq[32 + u] = r;
        r = (u + 16 < dYf) ? packed[sY + 16 + u] : make_int2(0, 0); ebq[48 + u] = r;
    }

    floatx2 aX[4], aY[4];
#pragma unroll
    for (int k = 0; k < 4; ++k) { aX[k] = 0.f; aY[k] = 0.f; }

    const int cX = min(dXf, 32), cY = min(dYf, 32);
    const int jmax = (cX > cY) ? cX : cY;

    // branch-free main loop; quarter-divergent trip count via exec mask
    for (int j = 0; j < jmax; j += 4) {
        const int2 x0 = ebq[j],      x1 = ebq[j + 1];
        const int2 x2 = ebq[j + 2],  x3 = ebq[j + 3];
        const int2 y0 = ebq[32 + j],     y1 = ebq[32 + j + 1];
        const int2 y2 = ebq[32 + j + 2], y3 = ebq[32 + j + 3];
        const uint2 vx0 = h2[(size_t)(unsigned)(x0.x + u)];
        const uint2 vx1 = h2[(size_t)(unsigned)(x1.x + u)];
        const uint2 vx2 = h2[(size_t)(unsigned)(x2.x + u)];
        const uint2 vx3 = h2[(size_t)(unsigned)(x3.x + u)];
        const uint2 vy0 = h2[(size_t)(unsigned)(y0.x + u)];
        const uint2 vy1 = h2[(size_t)(unsigned)(y1.x + u)];
        const uint2 vy2 = h2[(size_t)(unsigned)(y2.x + u)];
        const uint2 vy3 = h2[(size_t)(unsigned)(y3.x + u)];
        ACC_EDGE(vx0, __int_as_float(x0.y), aX);
        ACC_EDGE(vx1, __int_as_float(x1.y), aX);
        ACC_EDGE(vx2, __int_as_float(x2.y), aX);
        ACC_EDGE(vx3, __int_as_float(x3.y), aX);
        ACC_EDGE(vy0, __int_as_float(y0.y), aY);
        ACC_EDGE(vy1, __int_as_float(y1.y), aY);
        ACC_EDGE(vy2, __int_as_float(y2.y), aY);
        ACC_EDGE(vy3, __int_as_float(y3.y), aY);
    }

    // rare overflow (degree > 32): reload X region in 32-chunks
    for (int base = sX + 32; base < eXe; base += 32) {
        const int rem = eXe - base;
        int2 r;
        r = (u      < rem) ? packed[base + u]      : make_int2(0, 0); ebq[u]      = r;
        r = (u + 16 < rem) ? packed[base + 16 + u] : make_int2(0, 0); ebq[16 + u] = r;
        const int cc = min(rem, 32);
        for (int j = 0; j < cc; j += 4) {
            const int2 x0 = ebq[j], x1 = ebq[j + 1], x2 = ebq[j + 2], x3 = ebq[j + 3];
            const uint2 v0 = h2[(size_t)(unsigned)(x0.x + u)];
            const uint2 v1 = h2[(size_t)(unsigned)(x1.x + u)];
            const uint2 v2 = h2[(size_t)(unsigned)(x2.x + u)];
            const uint2 v3 = h2[(size_t)(unsigned)(x3.x + u)];
            ACC_EDGE(v0, __int_as_float(x0.y), aX);
            ACC_EDGE(v1, __int_as_float(x1.y), aX);
            ACC_EDGE(v2, __int_as_float(x2.y), aX);
            ACC_EDGE(v3, __int_as_float(x3.y), aX);
        }
    }
    for (int base = sY + 32; base < eYe; base += 32) {
        const int rem = eYe - base;
        int2 r;
        r = (u      < rem) ? packed[base + u]      : make_int2(0, 0); ebq[32 + u] = r;
        r = (u + 16 < rem) ? packed[base + 16 + u] : make_int2(0, 0); ebq[48 + u] = r;
        const int cc = min(rem, 32);
        for (int j = 0; j < cc; j += 4) {
            const int2 y0 = ebq[32 + j], y1 = ebq[32 + j + 1];
            const int2 y2 = ebq[32 + j + 2], y3 = ebq[32 + j + 3];
            const uint2 v0 = h2[(size_t)(unsigned)(y0.x + u)];
            const uint2 v1 = h2[(size_t)(unsigned)(y1.x + u)];
            const uint2 v2 = h2[(size_t)(unsigned)(y2.x + u)];
            const uint2 v3 = h2[(size_t)(unsigned)(y3.x + u)];
            ACC_EDGE(v0, __int_as_float(y0.y), aY);
            ACC_EDGE(v1, __int_as_float(y1.y), aY);
            ACC_EDGE(v2, __int_as_float(y2.y), aY);
            ACC_EDGE(v3, __int_as_float(y3.y), aY);
        }
    }

    // parallel writes: every lane stores its own 16B row-slice
    if (nX < N) {
        uint4 o;
        o.x = (unsigned)f2bf(aX[0].x) | ((unsigned)f2bf(aX[0].y) << 16);
        o.y = (unsigned)f2bf(aX[1].x) | ((unsigned)f2bf(aX[1].y) << 16);
        o.z = (unsigned)f2bf(aX[2].x) | ((unsigned)f2bf(aX[2].y) << 16);
        o.w = (unsigned)f2bf(aX[3].x) | ((unsigned)f2bf(aX[3].y) << 16);
        aggb4[(size_t)nX * 16 + u] = o;
    }
    if (nY < N) {
        uint4 o;
        o.x = (unsigned)f2bf(aY[0].x) | ((unsigned)f2bf(aY[0].y) << 16);
        o.y = (unsigned)f2bf(aY[1].x) | ((unsigned)f2bf(aY[1].y) << 16);
        o.z = (unsigned)f2bf(aY[2].x) | ((unsigned)f2bf(aY[2].y) << 16);
        o.w = (unsigned)f2bf(aY[3].x) | ((unsigned)f2bf(aY[3].y) << 16);
        aggb4[(size_t)nY * 16 + u] = o;
    }

    // BN stats: per-lane pair totals, cross-sub shfl reduce (once per block)
    floatx2 cs0 = aX[0] + aY[0], cs1 = aX[1] + aY[1];
    floatx2 cs2 = aX[2] + aY[2], cs3 = aX[3] + aY[3];
    floatx2 cq0 = aX[0] * aX[0] + aY[0] * aY[0];
    floatx2 cq1 = aX[1] * aX[1] + aY[1] * aY[1];
    floatx2 cq2 = aX[2] * aX[2] + aY[2] * aY[2];
    floatx2 cq3 = aX[3] * aX[3] + aY[3] * aY[3];
#define XRED(V) \
    V.x += __shfl_xor(V.x, 16, 64); V.y += __shfl_xor(V.y, 16, 64); \
    V.x += __shfl_xor(V.x, 32, 64); V.y += __shfl_xor(V.y, 32, 64);
    XRED(cs0) XRED(cs1) XRED(cs2) XRED(cs3)
    XRED(cq0) XRED(cq1) XRED(cq2) XRED(cq3)
#undef XRED
    // lane (sub,u) stores col pair u*8+2*sub (2-way bank alias only)
    const floatx2 ws = (sub == 0) ? cs0 : (sub == 1) ? cs1 : (sub == 2) ? cs2 : cs3;
    const floatx2 wwq = (sub == 0) ? cq0 : (sub == 1) ? cq1 : (sub == 2) ? cq2 : cq3;
    const int col = u * 8 + 2 * sub;
    lsum[wave * 128 + col] = ws.x;  lsum[wave * 128 + col + 1] = ws.y;
    lsq[wave * 128 + col]  = wwq.x; lsq[wave * 128 + col + 1]  = wwq.y;
    __syncthreads();
    if (tid < 128) {
        float s = 0.f, q = 0.f;
#pragma unroll
        for (int i = 0; i < 4; ++i) {
            s += lsum[i * 128 + tid];
            q += lsq[i * 128 + tid];
        }
        const int sl = (blockIdx.x & (NSLICE - 1)) * 128;
        atomicAdd(&sum[sl + tid], s);
        atomicAdd(&sq[sl + tid], q);
    }
}

// ---------------- collapsed layer 2 (v14: wide grid + uint2 loads) ----------
// R5 post-mortem: 256-block grid = 1 wave/SIMD, scalar dword loads -> 41us at
// 4.5% HBM for a ~26MB read (~5us ideal). Grid 2048 (8 blk/CU), uint2/lane
// (2 rows/wave/iter), float4 acc, sout sliced by 16 to cap atomic depth.
__global__ __launch_bounds__(256) void wcolsum_bf16(
    const uint2* __restrict__ xb2, const float* __restrict__ cw,
    const float* __restrict__ sum1, const float* __restrict__ sq1,
    const float* __restrict__ g, const float* __restrict__ be,
    float* __restrict__ sout, int N)
{
    __shared__ float Aaf[128], Baf[128];
    __shared__ float4 ls[256];
    const int tid = threadIdx.x;
    if (tid < 128) {
        float s = 0.f, q = 0.f;
#pragma unroll
        for (int k = 0; k < NSLICE; ++k) {
            s += sum1[k * 128 + tid];
            q += sq1[k * 128 + tid];
        }
        const float invN = 1.0f / (float)N;
        const float m = s * invN;
        const float var = q * invN - m * m;
        const float rs = rsqrtf(var + BN_EPS);
        Aaf[tid] = g[tid] * rs;
        Baf[tid] = be[tid] - g[tid] * m * rs;
    }
    __syncthreads();
    const int u2 = tid & 31;            // col quad: cols 4*u2 .. 4*u2+3
    const int half = (tid >> 5) & 1;    // row parity within wave
    const int rr = tid >> 6;            // wave
    const float4 A = *(const float4*)&Aaf[u2 * 4];
    const float4 Bv = *(const float4*)&Baf[u2 * 4];
    float4 s = make_float4(0.f, 0.f, 0.f, 0.f);
    for (int row = blockIdx.x * 8 + rr * 2 + half; row < N; row += gridDim.x * 8) {
        const uint2 v = xb2[(size_t)row * 32 + u2];
        const float c = cw[row];
        s.x = fmaf(c, fmaxf(fmaf(A.x, blo(v.x), Bv.x), 0.f), s.x);
        s.y = fmaf(c, fmaxf(fmaf(A.y, bhi(v.x), Bv.y), 0.f), s.y);
        s.z = fmaf(c, fmaxf(fmaf(A.z, blo(v.y), Bv.z), 0.f), s.z);
        s.w = fmaf(c, fmaxf(fmaf(A.w, bhi(v.y), Bv.w), 0.f), s.w);
    }
    ls[tid] = s;
    __syncthreads();
    if (tid < 32) {
        float4 a = ls[tid];
#pragma unroll
        for (int k = 1; k < 8; ++k) {
            const float4 b = ls[tid + 32 * k];
            a.x += b.x; a.y += b.y; a.z += b.z; a.w += b.w;
        }
        float* so = sout + (blockIdx.x & (NSLICE - 1)) * 128 + tid * 4;
        atomicAdd(&so[0], a.x);
        atomicAdd(&so[1], a.y);
        atomicAdd(&so[2], a.z);
        atomicAdd(&so[3], a.w);
    }
}

__global__ void final_out(
    const float* __restrict__ s, const float* __restrict__ W2,
    const float* __restrict__ b2, float* __restrict__ out, int N, int Dout)
{
    __shared__ float sv[128];
    const int j = threadIdx.x;   // 128 threads
    {
        float a = 0.f;
#pragma unroll
        for (int k = 0; k < NSLICE; ++k) a += s[k * 128 + j];
        sv[j] = a;
    }
    __syncthreads();
    if (j < Dout) {
        float acc = 0.f;
        for (int f = 0; f < 128; ++f) acc = fmaf(sv[f], W2[f * Dout + j], acc);
        out[j] = acc + (float)N * b2[j];
    }
}

extern "C" void kernel_launch(void* const* d_in, const int* in_sizes, int n_in,
                              void* d_out, int out_size, void* d_ws, size_t ws_size,
                              hipStream_t stream)
{
    const float* nf  = (const float*)d_in[0];
    const int*   ei  = (const int*)d_in[1];
    const float* ew  = (const float*)d_in[2];
    const float* W0  = (const float*)d_in[3];
    // b0 = d_in[4], b1 = d_in[6]: cancel inside BatchNorm, unused
    const float* W1  = (const float*)d_in[5];
    const float* W2  = (const float*)d_in[7];
    const float* b2  = (const float*)d_in[8];
    const float* g0  = (const float*)d_in[9];
    const float* be0 = (const float*)d_in[10];
    const float* g1  = (const float*)d_in[11];
    const float* be1 = (const float*)d_in[12];

    const int N = in_sizes[0] / 128;
    const int E = in_sizes[2];
    const int* srcI = ei;       // edge_index[0,:]
    const int* dstI = ei + E;   // edge_index[1,:]

    const int B = (N + NPB - 1) / NPB;        // 196 for N=100k
    const int chunk = (E + PB - 1) / PB;

    const size_t HB = ((size_t)N * 128 * 2 + 255) & ~(size_t)255;  // bf16 buf
    const size_t NA = ((size_t)N * sizeof(int) + 255) & ~(size_t)255;
    const size_t CB = (((size_t)B * PB * 4) + 255) & ~(size_t)255;
    char* ws = (char*)d_ws;
    size_t off = 0;
    float* cw    = (float*)(ws + off); off += NA;
    int*   rp    = (int*)  (ws + off); off += NA;
    float* stats = (float*)(ws + off); off += 40960;   // 4 sliced stats + sliced svec
    int*   cntD  = (int*)  (ws + off); off += CB;
    int*   cntS  = (int*)  (ws + off); off += CB;
    int*   baseD = (int*)  (ws + off); off += 2048;
    int*   baseS = (int*)  (ws + off); off += 2048;
    uint2* hbuf  = (uint2*)(ws + off); off += HB;      // h (fp8, oversized ok)
    unsigned* aggb = (unsigned*)(ws + off); off += HB; // agg (bf16)
    int2*  packed = (int2*)(ws + off); off += (size_t)E * 8;
    uint2* bktD  = (uint2*)(ws + off); off += (size_t)E * 8;
    uint2* bktS  = (uint2*)(ws + off); off += (size_t)E * 8;
    unsigned short* wt0 = (unsigned short*)(ws + off); off += 32768;
    unsigned short* wt1 = (unsigned short*)(ws + off); off += 32768;
    (void)ws_size;  // rounds 1-11 proved ws_size >= 116.5 MB; this needs ~92 MB

    // sliced stats: each array NSLICE*128 floats
    float* sum0 = stats + 0 * NSLICE * 128;
    float* sq0  = stats + 1 * NSLICE * 128;
    float* sum1 = stats + 2 * NSLICE * 128;
    float* sq1  = stats + 3 * NSLICE * 128;
    float* svec = stats + 4 * NSLICE * 128;   // [NSLICE][128]

    const int gemmGrid = (N + 63) / 64;
    const int aggGrid  = (N + 31) / 32;       // 3125

    // ---- atomic-free CSR build + cw (graph identical both layers) ----
    bucket_hist<<<PB, 512, 0, stream>>>(srcI, dstI, cntD, cntS, E, B, chunk);
    bucket_base<<<1, 256, 0, stream>>>(cntD, cntS, baseD, baseS, B, E);
    bucket_cursor<<<2 * B, 256, 0, stream>>>(cntD, cntS, baseD, baseS, B);
    bucket_place<<<PB, 512, 0, stream>>>(srcI, dstI, ew, cntD, cntS, bktD, bktS, E, B, chunk);
    bucket_sortcw<<<2 * B, 256, 0, stream>>>(bktD, baseD, rp, packed,
                                             bktS, baseS, cw, N, B);
    wconv<<<64, 256, 0, stream>>>(W0, W1, wt0, wt1, stats);   // + stats zeroing

    // ---- layer 0 ----
    gemm0<<<gemmGrid, 256, 0, stream>>>(nf, wt0, hbuf, N);
    aggq<<<aggGrid, 256, 0, stream>>>(
        packed, rp, (const uint2*)hbuf, (uint4*)aggb, sum0, sq0, N);

    // ---- layer 1 (BN0+ReLU folded into GEMM staging) ----
    gemm1<<<gemmGrid, 256, 0, stream>>>(aggb, wt1, hbuf, sum0, sq0, g0, be0, N, N);
    aggq<<<aggGrid, 256, 0, stream>>>(
        packed, rp, (const uint2*)hbuf, (uint4*)aggb, sum1, sq1, N);

    // ---- collapsed layer 2: out = (sum_n cw[n]*relu(BN1(x2))[n,:]) @ W2 + N*b2 ----
    wcolsum_bf16<<<2048, 256, 0, stream>>>((const uint2*)aggb, cw, sum1, sq1,
                                           g1, be1, svec, N);
    final_out<<<1, 128, 0, stream>>>(svec, W2, b2, (float*)d_out, N, out_size);
}

// Round 7
// 335.690 us; speedup vs baseline: 1.3065x; 1.0199x over previous
//
#include <hip/hip_runtime.h>

#define BN_EPS 1e-5f

// Bucket-sort parameters: NPB nodes per bucket (pow2), PB placement blocks.
#define NPB 512
#define NPB_SHIFT 9
#define PB 512
#define MAXB 256
// write-combining buffers in bucket_place
#define WCB 200
#define WCCAP 16
// BN-stat accumulator slices (atomic-depth reduction)
#define NSLICE 16

typedef __attribute__((ext_vector_type(8))) short short8;
typedef __attribute__((ext_vector_type(4))) float floatx4;
typedef __attribute__((ext_vector_type(2))) float floatx2;

__device__ __forceinline__ unsigned short f2bf(float f) {
    unsigned u = __float_as_uint(f);
    unsigned r = u + 0x7FFFu + ((u >> 16) & 1u);   // round-to-nearest-even
    return (unsigned short)(r >> 16);
}
__device__ __forceinline__ float blo(unsigned v) { return __uint_as_float(v << 16); }
__device__ __forceinline__ float bhi(unsigned v) { return __uint_as_float(v & 0xffff0000u); }

// pack 8 fp32 -> 8 fp8 e4m3 (2 dwords); byte k of output = value k
__device__ __forceinline__ uint2 pk8_fp8(const float4 v0, const float4 v1) {
    int lo = 0, hi = 0;
    lo = __builtin_amdgcn_cvt_pk_fp8_f32(v0.x, v0.y, lo, false);
    lo = __builtin_amdgcn_cvt_pk_fp8_f32(v0.z, v0.w, lo, true);
    hi = __builtin_amdgcn_cvt_pk_fp8_f32(v1.x, v1.y, hi, false);
    hi = __builtin_amdgcn_cvt_pk_fp8_f32(v1.z, v1.w, hi, true);
    return make_uint2((unsigned)lo, (unsigned)hi);
}

// ------- W pre-transpose (+ stats zeroing folded in, saves a dispatch) -------
__global__ __launch_bounds__(256) void wconv(
    const float* __restrict__ W0, const float* __restrict__ W1,
    unsigned short* __restrict__ wt0, unsigned short* __restrict__ wt1,
    float* __restrict__ stats)
{
    const int idx = blockIdx.x * 256 + threadIdx.x;   // < 16384
    const int n = idx >> 7, k = idx & 127;
    wt0[idx] = f2bf(W0[k * 128 + n]);
    wt1[idx] = f2bf(W1[k * 128 + n]);
    if (blockIdx.x < 10) {  // zero 10240 floats (4 sliced stat arrays + sliced svec)
        const int o = (blockIdx.x * 256 + threadIdx.x) * 4;
        *(float4*)&stats[o] = make_float4(0.f, 0.f, 0.f, 0.f);
    }
}

// ------- layer-0 GEMM: C[M x 128] = A_fp32 @ W, C in fp8 e4m3 -------
__global__ __launch_bounds__(256) void gemm0(
    const float* __restrict__ A, const unsigned short* __restrict__ Wt,
    uint2* __restrict__ C, int M)
{
    __shared__ char lds[53248];
    unsigned short* Al = (unsigned short*)lds;            // [64][136] bf16
    unsigned short* Wl = (unsigned short*)(lds + 17408);  // [128][136] bf16
    float* Cl = (float*)lds;                              // [64][132] f32 (reuse)

    const int tid = threadIdx.x;
    const int r0 = blockIdx.x * 64;

#pragma unroll
    for (int i = 0; i < 16; ++i) {
        const int idx = i * 256 + tid;          // ushort4 units
        const int n = idx >> 5, q = idx & 31;
        const ushort4 v = ((const ushort4*)Wt)[idx];
        *(ushort4*)&Wl[n * 136 + q * 4] = v;
    }
#pragma unroll
    for (int i = 0; i < 8; ++i) {
        const int row = i * 8 + (tid >> 5), q = tid & 31;
        const int gr = r0 + row;
        float4 v = (gr < M) ? ((const float4*)A)[(size_t)gr * 32 + q]
                            : make_float4(0.f, 0.f, 0.f, 0.f);
        ushort4 o;
        o.x = f2bf(v.x); o.y = f2bf(v.y); o.z = f2bf(v.z); o.w = f2bf(v.w);
        *(ushort4*)&Al[row * 136 + q * 4] = o;
    }
    __syncthreads();

    const int wave = tid >> 6, lane = tid & 63;
    const int lrow = lane & 15, quad = lane >> 4;
    const int n0 = wave * 32;

    floatx4 acc[4][2];
#pragma unroll
    for (int mt = 0; mt < 4; ++mt)
#pragma unroll
        for (int t = 0; t < 2; ++t)
#pragma unroll
            for (int j = 0; j < 4; ++j) acc[mt][t][j] = 0.f;

#pragma unroll
    for (int c = 0; c < 4; ++c) {
        const int k0 = c * 32;
        const short8 b0 = *(const short8*)&Wl[(n0 + lrow) * 136 + k0 + quad * 8];
        const short8 b1 = *(const short8*)&Wl[(n0 + 16 + lrow) * 136 + k0 + quad * 8];
#pragma unroll
        for (int mt = 0; mt < 4; ++mt) {
            const short8 a = *(const short8*)&Al[(mt * 16 + lrow) * 136 + k0 + quad * 8];
            acc[mt][0] = __builtin_amdgcn_mfma_f32_16x16x32_bf16(a, b0, acc[mt][0], 0, 0, 0);
            acc[mt][1] = __builtin_amdgcn_mfma_f32_16x16x32_bf16(a, b1, acc[mt][1], 0, 0, 0);
        }
    }
    __syncthreads();

#pragma unroll
    for (int mt = 0; mt < 4; ++mt)
#pragma unroll
        for (int t = 0; t < 2; ++t)
#pragma unroll
            for (int j = 0; j < 4; ++j)
                Cl[(mt * 16 + quad * 4 + j) * 132 + n0 + t * 16 + lrow] = acc[mt][t][j];
    __syncthreads();

#pragma unroll
    for (int i = 0; i < 4; ++i) {
        const int row = i * 16 + (tid >> 4);
        const int c0 = (tid & 15) * 8;
        const int gr = r0 + row;
        if (gr < M) {
            const float4 v0 = *(float4*)&Cl[row * 132 + c0];
            const float4 v1 = *(float4*)&Cl[row * 132 + c0 + 4];
            C[(size_t)gr * 16 + (c0 >> 3)] = pk8_fp8(v0, v1);
        }
    }
}

// ------- layer-1 GEMM: C = relu(BN(A_bf16)) @ W, C in fp8 e4m3 -------
__global__ __launch_bounds__(256) void gemm1(
    const unsigned* __restrict__ Ab, const unsigned short* __restrict__ Wt,
    uint2* __restrict__ C,
    const float* __restrict__ sum, const float* __restrict__ sq,
    const float* __restrict__ g, const float* __restrict__ be,
    int M, int N)
{
    __shared__ char lds[53248];
    unsigned short* Al = (unsigned short*)lds;            // [64][136]
    unsigned short* Wl = (unsigned short*)(lds + 17408);  // [128][136]
    float* AscL = (float*)(lds + 52224);                  // [128]
    float* AshL = AscL + 128;
    float* Cl = (float*)lds;

    const int tid = threadIdx.x;
    const int r0 = blockIdx.x * 64;

    if (tid < 128) {
        float s = 0.f, q = 0.f;
#pragma unroll
        for (int k = 0; k < NSLICE; ++k) {
            s += sum[k * 128 + tid];
            q += sq[k * 128 + tid];
        }
        const float invN = 1.0f / (float)N;
        const float m = s * invN;
        const float var = q * invN - m * m;
        const float rs = rsqrtf(var + BN_EPS);
        AscL[tid] = g[tid] * rs;
        AshL[tid] = be[tid] - g[tid] * m * rs;
    }
    __syncthreads();

#pragma unroll
    for (int i = 0; i < 16; ++i) {
        const int idx = i * 256 + tid;
        const int n = idx >> 5, q = idx & 31;
        const ushort4 v = ((const ushort4*)Wt)[idx];
        *(ushort4*)&Wl[n * 136 + q * 4] = v;
    }
#pragma unroll
    for (int i = 0; i < 4; ++i) {
        const int idx = i * 256 + tid;
        const int row = idx >> 4, qc = idx & 15;
        const int gr = r0 + row;
        uint4 v = (gr < M) ? ((const uint4*)Ab)[(size_t)gr * 16 + qc]
                           : make_uint4(0, 0, 0, 0);
        const float4 a0 = *(const float4*)&AscL[qc * 8];
        const float4 a1 = *(const float4*)&AscL[qc * 8 + 4];
        const float4 b0 = *(const float4*)&AshL[qc * 8];
        const float4 b1 = *(const float4*)&AshL[qc * 8 + 4];
        float x0 = fmaxf(fmaf(a0.x, blo(v.x), b0.x), 0.f);
        float x1 = fmaxf(fmaf(a0.y, bhi(v.x), b0.y), 0.f);
        float x2 = fmaxf(fmaf(a0.z, blo(v.y), b0.z), 0.f);
        float x3 = fmaxf(fmaf(a0.w, bhi(v.y), b0.w), 0.f);
        float x4 = fmaxf(fmaf(a1.x, blo(v.z), b1.x), 0.f);
        float x5 = fmaxf(fmaf(a1.y, bhi(v.z), b1.y), 0.f);
        float x6 = fmaxf(fmaf(a1.z, blo(v.w), b1.z), 0.f);
        float x7 = fmaxf(fmaf(a1.w, bhi(v.w), b1.w), 0.f);
        uint4 o;
        o.x = (unsigned)f2bf(x0) | ((unsigned)f2bf(x1) << 16);
        o.y = (unsigned)f2bf(x2) | ((unsigned)f2bf(x3) << 16);
        o.z = (unsigned)f2bf(x4) | ((unsigned)f2bf(x5) << 16);
        o.w = (unsigned)f2bf(x6) | ((unsigned)f2bf(x7) << 16);
        *(uint4*)&Al[row * 136 + qc * 8] = o;
    }
    __syncthreads();

    const int wave = tid >> 6, lane = tid & 63;
    const int lrow = lane & 15, quad = lane >> 4;
    const int n0 = wave * 32;

    floatx4 acc[4][2];
#pragma unroll
    for (int mt = 0; mt < 4; ++mt)
#pragma unroll
        for (int t = 0; t < 2; ++t)
#pragma unroll
            for (int j = 0; j < 4; ++j) acc[mt][t][j] = 0.f;

#pragma unroll
    for (int c = 0; c < 4; ++c) {
        const int k0 = c * 32;
        const short8 b0 = *(const short8*)&Wl[(n0 + lrow) * 136 + k0 + quad * 8];
        const short8 b1 = *(const short8*)&Wl[(n0 + 16 + lrow) * 136 + k0 + quad * 8];
#pragma unroll
        for (int mt = 0; mt < 4; ++mt) {
            const short8 a = *(const short8*)&Al[(mt * 16 + lrow) * 136 + k0 + quad * 8];
            acc[mt][0] = __builtin_amdgcn_mfma_f32_16x16x32_bf16(a, b0, acc[mt][0], 0, 0, 0);
            acc[mt][1] = __builtin_amdgcn_mfma_f32_16x16x32_bf16(a, b1, acc[mt][1], 0, 0, 0);
        }
    }
    __syncthreads();

#pragma unroll
    for (int mt = 0; mt < 4; ++mt)
#pragma unroll
        for (int t = 0; t < 2; ++t)
#pragma unroll
            for (int j = 0; j < 4; ++j)
                Cl[(mt * 16 + quad * 4 + j) * 132 + n0 + t * 16 + lrow] = acc[mt][t][j];
    __syncthreads();

#pragma unroll
    for (int i = 0; i < 4; ++i) {
        const int row = i * 16 + (tid >> 4);
        const int c0 = (tid & 15) * 8;
        const int gr = r0 + row;
        if (gr < M) {
            const float4 v0 = *(float4*)&Cl[row * 132 + c0];
            const float4 v1 = *(float4*)&Cl[row * 132 + c0 + 4];
            C[(size_t)gr * 16 + (c0 >> 3)] = pk8_fp8(v0, v1);
        }
    }
}

// ============ atomic-free CSR build: two-level bucket counting sort ============
// R1 lesson: global atomicAdd(&cw[s]) storm cost +30us in bucket_place.
// R6 lesson: 512 threads didn't help place (44us, VALUBusy 1.4%) -- the wall is
// scattered 8B partial-line writes (WRITE_SIZE 55MB vs 25.6MB data, 2.15x
// amplification). R7: software write-combining in LDS, flush 64B groups.

__global__ __launch_bounds__(512) void bucket_hist(
    const int* __restrict__ src, const int* __restrict__ dst,
    int* __restrict__ cntD, int* __restrict__ cntS, int E, int B, int chunk)
{
    __shared__ int hD[MAXB], hS[MAXB];
    const int tid = threadIdx.x;
    for (int i = tid; i < B; i += 512) { hD[i] = 0; hS[i] = 0; }
    __syncthreads();
    const int lo = blockIdx.x * chunk;
    const int hi = min(E, lo + chunk);
    for (int e = lo + tid; e < hi; e += 512) {
        atomicAdd(&hD[dst[e] >> NPB_SHIFT], 1);
        atomicAdd(&hS[src[e] >> NPB_SHIFT], 1);
    }
    __syncthreads();
    for (int i = tid; i < B; i += 512) {
        cntD[i * PB + blockIdx.x] = hD[i];
        cntS[i * PB + blockIdx.x] = hS[i];
    }
}

__global__ __launch_bounds__(256) void bucket_base(
    const int* __restrict__ cntD, const int* __restrict__ cntS,
    int* __restrict__ baseD, int* __restrict__ baseS, int B, int E)
{
    __shared__ int lD[256], lS[256];
    const int tid = threadIdx.x;
    int sD = 0, sS = 0;
    if (tid < B) {
        const int4* pD = (const int4*)(cntD + tid * PB);
        const int4* pS = (const int4*)(cntS + tid * PB);
        for (int j = 0; j < PB / 4; ++j) {
            const int4 a = pD[j], b = pS[j];
            sD += a.x + a.y + a.z + a.w;
            sS += b.x + b.y + b.z + b.w;
        }
    }
    lD[tid] = sD; lS[tid] = sS;
    __syncthreads();
    for (int st = 1; st < 256; st <<= 1) {
        const int vD = (tid >= st) ? lD[tid - st] : 0;
        const int vS = (tid >= st) ? lS[tid - st] : 0;
        __syncthreads();
        lD[tid] += vD; lS[tid] += vS;
        __syncthreads();
    }
    if (tid < B) { baseD[tid] = lD[tid] - sD; baseS[tid] = lS[tid] - sS; }
    if (tid == 0) { baseD[B] = E; baseS[B] = E; }
}

__global__ __launch_bounds__(256) void bucket_cursor(
    int* __restrict__ cntD, int* __restrict__ cntS,
    const int* __restrict__ baseD, const int* __restrict__ baseS, int B)
{
    int b = blockIdx.x;
    int* cnt; const int* base;
    if (b < B) { cnt = cntD; base = baseD; }
    else       { cnt = cntS; base = baseS; b -= B; }
    __shared__ int ls[256];
    const int tid = threadIdx.x;
    const int c0 = cnt[b * PB + 2 * tid];
    const int c1 = cnt[b * PB + 2 * tid + 1];
    const int s = c0 + c1;
    ls[tid] = s;
    __syncthreads();
    for (int st = 1; st < 256; st <<= 1) {
        const int v = (tid >= st) ? ls[tid - st] : 0;
        __syncthreads();
        ls[tid] += v;
        __syncthreads();
    }
    const int excl = ls[tid] - s + base[b];
    cnt[b * PB + 2 * tid] = excl;
    cnt[b * PB + 2 * tid + 1] = excl + c0;
}

// v15: software write-combining. Per-bucket LDS staging (16 recs, padded row
// 17 to spread flush reads across banks). Insert: LDS-atomic tail -> buffer
// slot; overflow (>16 in flight, P~1e-6) scatters direct at reserved position.
// Per 512-edge tile: owner thread (tid<B) flushes full groups of 8 records
// (64B) as contiguous stores, carries remainder. Positions exactly match the
// counting-sort contract; only the order within a (bucket,block) region
// changes (arbitrary order is fine -- sortcw re-sorts by node).
__global__ __launch_bounds__(512) void bucket_place(
    const int* __restrict__ src, const int* __restrict__ dst,
    const float* __restrict__ ew,
    const int* __restrict__ curD, const int* __restrict__ curS,
    uint2* __restrict__ bktD, uint2* __restrict__ bktS, int E, int B, int chunk)
{
    __shared__ uint2 bufD[WCB][WCCAP + 1], bufS[WCB][WCCAP + 1];
    __shared__ int tailD[WCB], tailS[WCB], gcurD[WCB], gcurS[WCB];
    const int tid = threadIdx.x;
    for (int i = tid; i < B; i += 512) {
        gcurD[i] = curD[i * PB + blockIdx.x];
        gcurS[i] = curS[i * PB + blockIdx.x];
        tailD[i] = 0; tailS[i] = 0;
    }
    __syncthreads();
    const int lo = blockIdx.x * chunk;
    const int hi = min(E, lo + chunk);
    const int nt = (hi - lo + 511) >> 9;
    for (int t = 0; t < nt; ++t) {
        const int e = lo + t * 512 + tid;
        if (e < hi) {
            const int s = src[e], d = dst[e];
            const unsigned wb = __float_as_uint(ew[e]);
            const int bd = d >> NPB_SHIFT;
            const uint2 rd = make_uint2(((unsigned)s << NPB_SHIFT) | (unsigned)(d & (NPB - 1)), wb);
            const int pd = atomicAdd(&tailD[bd], 1);
            if (pd < WCCAP) bufD[bd][pd] = rd;
            else            bktD[gcurD[bd] + pd] = rd;
            const int bs = s >> NPB_SHIFT;
            const uint2 rs = make_uint2((unsigned)(s & (NPB - 1)), wb);
            const int ps = atomicAdd(&tailS[bs], 1);
            if (ps < WCCAP) bufS[bs][ps] = rs;
            else            bktS[gcurS[bs] + ps] = rs;
        }
        __syncthreads();
        const bool last = (t == nt - 1);
        if (tid < B) {
            {   // D flush
                const int tl = tailD[tid];
                const int nb = min(tl, WCCAP);
                const int k = last ? nb : (nb & ~7);
                const int base = gcurD[tid];
                for (int i = 0; i < k; ++i) bktD[base + i] = bufD[tid][i];
                const int adv = (tl > WCCAP) ? tl : k;
                const int left = (tl > WCCAP) ? 0 : (tl - k);
                for (int i = 0; i < left; ++i) bufD[tid][i] = bufD[tid][k + i];
                gcurD[tid] = base + adv;
                tailD[tid] = left;
            }
            {   // S flush
                const int tl = tailS[tid];
                const int nb = min(tl, WCCAP);
                const int k = last ? nb : (nb & ~7);
                const int base = gcurS[tid];
                for (int i = 0; i < k; ++i) bktS[base + i] = bufS[tid][i];
                const int adv = (tl > WCCAP) ? tl : k;
                const int left = (tl > WCCAP) ? 0 : (tl - k);
                for (int i = 0; i < left; ++i) bufS[tid][i] = bufS[tid][k + i];
                gcurS[tid] = base + adv;
                tailS[tid] = left;
            }
        }
        __syncthreads();
    }
}

// merged: blocks [0,B) counting-sort bktD -> rp/packed; blocks [B,2B) cw sums
// packed.x stores src*16 (uint2 index pre-scale: kills a v_mul in the gather)
__global__ __launch_bounds__(256) void bucket_sortcw(
    const uint2* __restrict__ bktD, const int* __restrict__ baseD,
    int* __restrict__ rp, int2* __restrict__ packed,
    const uint2* __restrict__ bktS, const int* __restrict__ baseS,
    float* __restrict__ cw, int N, int B)
{
    const int tid = threadIdx.x;
    if (blockIdx.x >= B) {
        const int b = blockIdx.x - B;
        const int lo = baseS[b], hi = baseS[b + 1];
        __shared__ float sm[NPB];
        sm[2 * tid] = 0.f; sm[2 * tid + 1] = 0.f;
        __syncthreads();
        for (int i = lo + tid; i < hi; i += 256) {
            const uint2 r = bktS[i];
            atomicAdd(&sm[r.x], __uint_as_float(r.y));
        }
        __syncthreads();
        const int n0 = b * NPB + 2 * tid;
        if (n0 < N)     cw[n0]     = sm[2 * tid];
        if (n0 + 1 < N) cw[n0 + 1] = sm[2 * tid + 1];
        return;
    }
    const int b = blockIdx.x;
    const int lo = baseD[b], hi = baseD[b + 1];
    __shared__ int cnt[NPB], cur[NPB];
    __shared__ int ls[256];
    cnt[2 * tid] = 0; cnt[2 * tid + 1] = 0;
    __syncthreads();
    for (int i = lo + tid; i < hi; i += 256)
        atomicAdd(&cnt[bktD[i].x & (NPB - 1)], 1);
    __syncthreads();
    const int c0 = cnt[2 * tid], c1 = cnt[2 * tid + 1];
    const int s = c0 + c1;
    ls[tid] = s;
    __syncthreads();
    for (int st = 1; st < 256; st <<= 1) {
        const int v = (tid >= st) ? ls[tid - st] : 0;
        __syncthreads();
        ls[tid] += v;
        __syncthreads();
    }
    const int excl = ls[tid] - s;
    const int n0 = b * NPB + 2 * tid;
    if (n0 < N)     rp[n0]     = lo + excl + c0;
    if (n0 + 1 < N) rp[n0 + 1] = lo + excl + c0 + c1;
    cur[2 * tid]     = lo + excl;
    cur[2 * tid + 1] = lo + excl + c0;
    __syncthreads();
    for (int i = lo + tid; i < hi; i += 256) {
        const uint2 r = bktD[i];
        const int pos = atomicAdd(&cur[r.x & (NPB - 1)], 1);
        packed[pos] = make_int2((int)(r.x >> NPB_SHIFT) << 4, (int)r.y);
    }
}

// ------- fused aggregate + BN stats (v13: quarter-per-node, branch-free) -----
// Each 16-lane quarter owns node pair (X,Y); lane u = cols 8u..8u+7. No
// cross-lane reduce, parallel writes, pad slots {0,0} -> w=0 kills contrib.

#define ACC_EDGE(V, W, A) do { \
    floatx2 w2_; w2_.x = (W); w2_.y = (W); \
    floatx2 f_; \
    f_ = __builtin_amdgcn_cvt_pk_f32_fp8((int)(V).x, false); \
    A[0] = f_ * w2_ + A[0]; \
    f_ = __builtin_amdgcn_cvt_pk_f32_fp8((int)(V).x, true);  \
    A[1] = f_ * w2_ + A[1]; \
    f_ = __builtin_amdgcn_cvt_pk_f32_fp8((int)(V).y, false); \
    A[2] = f_ * w2_ + A[2]; \
    f_ = __builtin_amdgcn_cvt_pk_f32_fp8((int)(V).y, true);  \
    A[3] = f_ * w2_ + A[3]; \
} while (0)

__global__ __launch_bounds__(256) void aggq(
    const int2* __restrict__ packed, const int* __restrict__ rp,
    const uint2* __restrict__ h2, uint4* __restrict__ aggb4,
    float* __restrict__ sum, float* __restrict__ sq, int N)
{
    __shared__ int2 eb[16][65];           // per-quarter: X slots 0..31, Y 32..63
    __shared__ float lsum[512], lsq[512]; // per-wave col strips

    const int tid = threadIdx.x;
    const int lane = tid & 63, wave = tid >> 6;
    const int sub = lane >> 4;            // quarter within wave
    const int u = lane & 15;              // col group 8u..8u+7
    const int wq = wave * 4 + sub;        // block-quarter 0..15
    const int nb0 = blockIdx.x * 32;
    const int nX = nb0 + wq * 2, nY = nX + 1;
    int2* ebq = eb[wq];

    // coalesced row-pointer block: lane l holds rp[nb0-1+l], l in [0,32]
    int rpv = 0;
    {
        const int idx = nb0 - 1 + lane;
        if (lane <= 32 && idx >= 0 && idx < N) rpv = rp[idx];
    }
    const int sX = __shfl(rpv, 2 * wq, 64);
    const int eX = __shfl(rpv, 2 * wq + 1, 64);
    const int eYr = __shfl(rpv, 2 * wq + 2, 64);
    const int sY = eX;
    const int dXf = max(eX - sX, 0), dYf = max(eYr - sY, 0);
    const int eXe = sX + dXf, eYe = sY + dYf;

    // stage first 32 records per node; pad slots = {0,0} (w=0 kills contrib)
    {
        int2 r;
        r = (u      < dXf) ? packed[sX + u]      : make_int2(0, 0); ebq[u]      = r;
        r = (u + 16 < dXf) ? packed[sX + 16 + u] : make_int2(0, 0); ebq[16 + u] = r;
        r = (u      < dYf) ? packed[sY + u]      : make_int2(0, 0); ebq[32 + u] = r;
        r = (u + 16 < dYf) ? packed[sY + 16 + u] : make_int2(0, 0); ebq[48 + u] = r;
    }

    floatx2 aX[4], aY[4];
#pragma unroll
    for (int k = 0; k < 4; ++k) { aX[k] = 0.f; aY[k] = 0.f; }

    const int cX = min(dXf, 32), cY = min(dYf, 32);
    const int jmax = (cX > cY) ? cX : cY;

    // branch-free main loop; quarter-divergent trip count via exec mask
    for (int j = 0; j < jmax; j += 4) {
        const int2 x0 = ebq[j],      x1 = ebq[j + 1];
        const int2 x2 = ebq[j + 2],  x3 = ebq[j + 3];
        const int2 y0 = ebq[32 + j],     y1 = ebq[32 + j + 1];
        const int2 y2 = ebq[32 + j + 2], y3 = ebq[32 + j + 3];
        const uint2 vx0 = h2[(size_t)(unsigned)(x0.x + u)];
        const uint2 vx1 = h2[(size_t)(unsigned)(x1.x + u)];
        const uint2 vx2 = h2[(size_t)(unsigned)(x2.x + u)];
        const uint2 vx3 = h2[(size_t)(unsigned)(x3.x + u)];
        const uint2 vy0 = h2[(size_t)(unsigned)(y0.x + u)];
        const uint2 vy1 = h2[(size_t)(unsigned)(y1.x + u)];
        const uint2 vy2 = h2[(size_t)(unsigned)(y2.x + u)];
        const uint2 vy3 = h2[(size_t)(unsigned)(y3.x + u)];
        ACC_EDGE(vx0, __int_as_float(x0.y), aX);
        ACC_EDGE(vx1, __int_as_float(x1.y), aX);
        ACC_EDGE(vx2, __int_as_float(x2.y), aX);
        ACC_EDGE(vx3, __int_as_float(x3.y), aX);
        ACC_EDGE(vy0, __int_as_float(y0.y), aY);
        ACC_EDGE(vy1, __int_as_float(y1.y), aY);
        ACC_EDGE(vy2, __int_as_float(y2.y), aY);
        ACC_EDGE(vy3, __int_as_float(y3.y), aY);
    }

    // rare overflow (degree > 32): reload X region in 32-chunks
    for (int base = sX + 32; base < eXe; base += 32) {
        const int rem = eXe - base;
        int2 r;
        r = (u      < rem) ? packed[base + u]      : make_int2(0, 0); ebq[u]      = r;
        r = (u + 16 < rem) ? packed[base + 16 + u] : make_int2(0, 0); ebq[16 + u] = r;
        const int cc = min(rem, 32);
        for (int j = 0; j < cc; j += 4) {
            const int2 x0 = ebq[j], x1 = ebq[j + 1], x2 = ebq[j + 2], x3 = ebq[j + 3];
            const uint2 v0 = h2[(size_t)(unsigned)(x0.x + u)];
            const uint2 v1 = h2[(size_t)(unsigned)(x1.x + u)];
            const uint2 v2 = h2[(size_t)(unsigned)(x2.x + u)];
            const uint2 v3 = h2[(size_t)(unsigned)(x3.x + u)];
            ACC_EDGE(v0, __int_as_float(x0.y), aX);
            ACC_EDGE(v1, __int_as_float(x1.y), aX);
            ACC_EDGE(v2, __int_as_float(x2.y), aX);
            ACC_EDGE(v3, __int_as_float(x3.y), aX);
        }
    }
    for (int base = sY + 32; base < eYe; base += 32) {
        const int rem = eYe - base;
        int2 r;
        r = (u      < rem) ? packed[base + u]      : make_int2(0, 0); ebq[32 + u] = r;
        r = (u + 16 < rem) ? packed[base + 16 + u] : make_int2(0, 0); ebq[48 + u] = r;
        const int cc = min(rem, 32);
        for (int j = 0; j < cc; j += 4) {
            const int2 y0 = ebq[32 + j], y1 = ebq[32 + j + 1];
            const int2 y2 = ebq[32 + j + 2], y3 = ebq[32 + j + 3];
            const uint2 v0 = h2[(size_t)(unsigned)(y0.x + u)];
            const uint2 v1 = h2[(size_t)(unsigned)(y1.x + u)];
            const uint2 v2 = h2[(size_t)(unsigned)(y2.x + u)];
            const uint2 v3 = h2[(size_t)(unsigned)(y3.x + u)];
            ACC_EDGE(v0, __int_as_float(y0.y), aY);
            ACC_EDGE(v1, __int_as_float(y1.y), aY);
            ACC_EDGE(v2, __int_as_float(y2.y), aY);
            ACC_EDGE(v3, __int_as_float(y3.y), aY);
        }
    }

    // parallel writes: every lane stores its own 16B row-slice
    if (nX < N) {
        uint4 o;
        o.x = (unsigned)f2bf(aX[0].x) | ((unsigned)f2bf(aX[0].y) << 16);
        o.y = (unsigned)f2bf(aX[1].x) | ((unsigned)f2bf(aX[1].y) << 16);
        o.z = (unsigned)f2bf(aX[2].x) | ((unsigned)f2bf(aX[2].y) << 16);
        o.w = (unsigned)f2bf(aX[3].x) | ((unsigned)f2bf(aX[3].y) << 16);
        aggb4[(size_t)nX * 16 + u] = o;
    }
    if (nY < N) {
        uint4 o;
        o.x = (unsigned)f2bf(aY[0].x) | ((unsigned)f2bf(aY[0].y) << 16);
        o.y = (unsigned)f2bf(aY[1].x) | ((unsigned)f2bf(aY[1].y) << 16);
        o.z = (unsigned)f2bf(aY[2].x) | ((unsigned)f2bf(aY[2].y) << 16);
        o.w = (unsigned)f2bf(aY[3].x) | ((unsigned)f2bf(aY[3].y) << 16);
        aggb4[(size_t)nY * 16 + u] = o;
    }

    // BN stats: per-lane pair totals, cross-sub shfl reduce (once per block)
    floatx2 cs0 = aX[0] + aY[0], cs1 = aX[1] + aY[1];
    floatx2 cs2 = aX[2] + aY[2], cs3 = aX[3] + aY[3];
    floatx2 cq0 = aX[0] * aX[0] + aY[0] * aY[0];
    floatx2 cq1 = aX[1] * aX[1] + aY[1] * aY[1];
    floatx2 cq2 = aX[2] * aX[2] + aY[2] * aY[2];
    floatx2 cq3 = aX[3] * aX[3] + aY[3] * aY[3];
#define XRED(V) \
    V.x += __shfl_xor(V.x, 16, 64); V.y += __shfl_xor(V.y, 16, 64); \
    V.x += __shfl_xor(V.x, 32, 64); V.y += __shfl_xor(V.y, 32, 64);
    XRED(cs0) XRED(cs1) XRED(cs2) XRED(cs3)
    XRED(cq0) XRED(cq1) XRED(cq2) XRED(cq3)
#undef XRED
    // lane (sub,u) stores col pair u*8+2*sub (2-way bank alias only)
    const floatx2 ws = (sub == 0) ? cs0 : (sub == 1) ? cs1 : (sub == 2) ? cs2 : cs3;
    const floatx2 wwq = (sub == 0) ? cq0 : (sub == 1) ? cq1 : (sub == 2) ? cq2 : cq3;
    const int col = u * 8 + 2 * sub;
    lsum[wave * 128 + col] = ws.x;  lsum[wave * 128 + col + 1] = ws.y;
    lsq[wave * 128 + col]  = wwq.x; lsq[wave * 128 + col + 1]  = wwq.y;
    __syncthreads();
    if (tid < 128) {
        float s = 0.f, q = 0.f;
#pragma unroll
        for (int i = 0; i < 4; ++i) {
            s += lsum[i * 128 + tid];
            q += lsq[i * 128 + tid];
        }
        const int sl = (blockIdx.x & (NSLICE - 1)) * 128;
        atomicAdd(&sum[sl + tid], s);
        atomicAdd(&sq[sl + tid], q);
    }
}

// ---------------- collapsed layer 2 (v14: wide grid + uint2 loads) ----------
__global__ __launch_bounds__(256) void wcolsum_bf16(
    const uint2* __restrict__ xb2, const float* __restrict__ cw,
    const float* __restrict__ sum1, const float* __restrict__ sq1,
    const float* __restrict__ g, const float* __restrict__ be,
    float* __restrict__ sout, int N)
{
    __shared__ float Aaf[128], Baf[128];
    __shared__ float4 ls[256];
    const int tid = threadIdx.x;
    if (tid < 128) {
        float s = 0.f, q = 0.f;
#pragma unroll
        for (int k = 0; k < NSLICE; ++k) {
            s += sum1[k * 128 + tid];
            q += sq1[k * 128 + tid];
        }
        const float invN = 1.0f / (float)N;
        const float m = s * invN;
        const float var = q * invN - m * m;
        const float rs = rsqrtf(var + BN_EPS);
        Aaf[tid] = g[tid] * rs;
        Baf[tid] = be[tid] - g[tid] * m * rs;
    }
    __syncthreads();
    const int u2 = tid & 31;            // col quad: cols 4*u2 .. 4*u2+3
    const int half = (tid >> 5) & 1;    // row parity within wave
    const int rr = tid >> 6;            // wave
    const float4 A = *(const float4*)&Aaf[u2 * 4];
    const float4 Bv = *(const float4*)&Baf[u2 * 4];
    float4 s = make_float4(0.f, 0.f, 0.f, 0.f);
    for (int row = blockIdx.x * 8 + rr * 2 + half; row < N; row += gridDim.x * 8) {
        const uint2 v = xb2[(size_t)row * 32 + u2];
        const float c = cw[row];
        s.x = fmaf(c, fmaxf(fmaf(A.x, blo(v.x), Bv.x), 0.f), s.x);
        s.y = fmaf(c, fmaxf(fmaf(A.y, bhi(v.x), Bv.y), 0.f), s.y);
        s.z = fmaf(c, fmaxf(fmaf(A.z, blo(v.y), Bv.z), 0.f), s.z);
        s.w = fmaf(c, fmaxf(fmaf(A.w, bhi(v.y), Bv.w), 0.f), s.w);
    }
    ls[tid] = s;
    __syncthreads();
    if (tid < 32) {
        float4 a = ls[tid];
#pragma unroll
        for (int k = 1; k < 8; ++k) {
            const float4 b = ls[tid + 32 * k];
            a.x += b.x; a.y += b.y; a.z += b.z; a.w += b.w;
        }
        float* so = sout + (blockIdx.x & (NSLICE - 1)) * 128 + tid * 4;
        atomicAdd(&so[0], a.x);
        atomicAdd(&so[1], a.y);
        atomicAdd(&so[2], a.z);
        atomicAdd(&so[3], a.w);
    }
}

__global__ void final_out(
    const float* __restrict__ s, const float* __restrict__ W2,
    const float* __restrict__ b2, float* __restrict__ out, int N, int Dout)
{
    __shared__ float sv[128];
    const int j = threadIdx.x;   // 128 threads
    {
        float a = 0.f;
#pragma unroll
        for (int k = 0; k < NSLICE; ++k) a += s[k * 128 + j];
        sv[j] = a;
    }
    __syncthreads();
    if (j < Dout) {
        float acc = 0.f;
        for (int f = 0; f < 128; ++f) acc = fmaf(sv[f], W2[f * Dout + j], acc);
        out[j] = acc + (float)N * b2[j];
    }
}

extern "C" void kernel_launch(void* const* d_in, const int* in_sizes, int n_in,
                              void* d_out, int out_size, void* d_ws, size_t ws_size,
                              hipStream_t stream)
{
    const float* nf  = (const float*)d_in[0];
    const int*   ei  = (const int*)d_in[1];
    const float* ew  = (const float*)d_in[2];
    const float* W0  = (const float*)d_in[3];
    // b0 = d_in[4], b1 = d_in[6]: cancel inside BatchNorm, unused
    const float* W1  = (const float*)d_in[5];
    const float* W2  = (const float*)d_in[7];
    const float* b2  = (const float*)d_in[8];
    const float* g0  = (const float*)d_in[9];
    const float* be0 = (const float*)d_in[10];
    const float* g1  = (const float*)d_in[11];
    const float* be1 = (const float*)d_in[12];

    const int N = in_sizes[0] / 128;
    const int E = in_sizes[2];
    const int* srcI = ei;       // edge_index[0,:]
    const int* dstI = ei + E;   // edge_index[1,:]

    const int B = (N + NPB - 1) / NPB;        // 196 for N=100k (must be <= WCB)
    const int chunk = (E + PB - 1) / PB;

    const size_t HB = ((size_t)N * 128 * 2 + 255) & ~(size_t)255;  // bf16 buf
    const size_t NA = ((size_t)N * sizeof(int) + 255) & ~(size_t)255;
    const size_t CB = (((size_t)B * PB * 4) + 255) & ~(size_t)255;
    char* ws = (char*)d_ws;
    size_t off = 0;
    float* cw    = (float*)(ws + off); off += NA;
    int*   rp    = (int*)  (ws + off); off += NA;
    float* stats = (float*)(ws + off); off += 40960;   // 4 sliced stats + sliced svec
    int*   cntD  = (int*)  (ws + off); off += CB;
    int*   cntS  = (int*)  (ws + off); off += CB;
    int*   baseD = (int*)  (ws + off); off += 2048;
    int*   baseS = (int*)  (ws + off); off += 2048;
    uint2* hbuf  = (uint2*)(ws + off); off += HB;      // h (fp8, oversized ok)
    unsigned* aggb = (unsigned*)(ws + off); off += HB; // agg (bf16)
    int2*  packed = (int2*)(ws + off); off += (size_t)E * 8;
    uint2* bktD  = (uint2*)(ws + off); off += (size_t)E * 8;
    uint2* bktS  = (uint2*)(ws + off); off += (size_t)E * 8;
    unsigned short* wt0 = (unsigned short*)(ws + off); off += 32768;
    unsigned short* wt1 = (unsigned short*)(ws + off); off += 32768;
    (void)ws_size;  // rounds 1-11 proved ws_size >= 116.5 MB; this needs ~92 MB

    // sliced stats: each array NSLICE*128 floats
    float* sum0 = stats + 0 * NSLICE * 128;
    float* sq0  = stats + 1 * NSLICE * 128;
    float* sum1 = stats + 2 * NSLICE * 128;
    float* sq1  = stats + 3 * NSLICE * 128;
    float* svec = stats + 4 * NSLICE * 128;   // [NSLICE][128]

    const int gemmGrid = (N + 63) / 64;
    const int aggGrid  = (N + 31) / 32;       // 3125

    // ---- atomic-free CSR build + cw (graph identical both layers) ----
    bucket_hist<<<PB, 512, 0, stream>>>(srcI, dstI, cntD, cntS, E, B, chunk);
    bucket_base<<<1, 256, 0, stream>>>(cntD, cntS, baseD, baseS, B, E);
    bucket_cursor<<<2 * B, 256, 0, stream>>>(cntD, cntS, baseD, baseS, B);
    bucket_place<<<PB, 512, 0, stream>>>(srcI, dstI, ew, cntD, cntS, bktD, bktS, E, B, chunk);
    bucket_sortcw<<<2 * B, 256, 0, stream>>>(bktD, baseD, rp, packed,
                                             bktS, baseS, cw, N, B);
    wconv<<<64, 256, 0, stream>>>(W0, W1, wt0, wt1, stats);   // + stats zeroing

    // ---- layer 0 ----
    gemm0<<<gemmGrid, 256, 0, stream>>>(nf, wt0, hbuf, N);
    aggq<<<aggGrid, 256, 0, stream>>>(
        packed, rp, (const uint2*)hbuf, (uint4*)aggb, sum0, sq0, N);

    // ---- layer 1 (BN0+ReLU folded into GEMM staging) ----
    gemm1<<<gemmGrid, 256, 0, stream>>>(aggb, wt1, hbuf, sum0, sq0, g0, be0, N, N);
    aggq<<<aggGrid, 256, 0, stream>>>(
        packed, rp, (const uint2*)hbuf, (uint4*)aggb, sum1, sq1, N);

    // ---- collapsed layer 2: out = (sum_n cw[n]*relu(BN1(x2))[n,:]) @ W2 + N*b2 ----
    wcolsum_bf16<<<2048, 256, 0, stream>>>((const uint2*)aggb, cw, sum1, sq1,
                                           g1, be1, svec, N);
    final_out<<<1, 128, 0, stream>>>(svec, W2, b2, (float*)d_out, N, out_size);
}